// Round 12
// baseline (157.540 us; speedup 1.0000x reference)
//
#include <hip/hip_runtime.h>
#include <hip/hip_bf16.h>
#include <math.h>

#define L_SEQ 4096
#define CDIM 96
#define DIN 192
#define NST 16
#define NCHUNK 64
#define CHLEN 64
#define MROWS 8192
#define XPW2 960   // combined xp width: 2 branches x 480 (416 used + pad)
#define SCAN_GRID 3072

typedef __attribute__((ext_vector_type(8))) short bf16x8;
typedef __attribute__((ext_vector_type(4))) float f32x4;
typedef __attribute__((ext_vector_type(4))) short s16x4;
typedef __attribute__((ext_vector_type(4))) unsigned short u16x4;

__device__ __forceinline__ float gelu_exact(float x) {
    return 0.5f * x * (1.0f + erff(x * 0.70710678118654752f));
}

__device__ __forceinline__ float fast_exp2(float x) {
#if __has_builtin(__builtin_amdgcn_exp2f)
    return __builtin_amdgcn_exp2f(x);
#else
    return exp2f(x);
#endif
}

__device__ __forceinline__ float b2f(unsigned short u) {
    return __uint_as_float((unsigned int)u << 16);
}

// 16-lane DPP row reduction via explicit v_add_f32_dpp (guaranteed fused form;
// row_ror rotates within each 16-lane row, all lanes valid). Leaves the row
// sum in all 16 lanes.
__device__ __forceinline__ float rowsum16(float s) {
    asm("v_add_f32_dpp %0, %0, %0 row_ror:8 row_mask:0xf bank_mask:0xf" : "+v"(s));
    asm("v_add_f32_dpp %0, %0, %0 row_ror:4 row_mask:0xf bank_mask:0xf" : "+v"(s));
    asm("v_add_f32_dpp %0, %0, %0 row_ror:2 row_mask:0xf bank_mask:0xf" : "+v"(s));
    asm("v_add_f32_dpp %0, %0, %0 row_ror:1 row_mask:0xf bank_mask:0xf" : "+v"(s));
    return s;
}

__device__ __forceinline__ unsigned short f2bf_bits(float f) {
    __hip_bfloat16 h = __float2bfloat16(f);
    return *reinterpret_cast<unsigned short*>(&h);
}

// ---------------- prep: weight convert/transpose + input LayerNorm (one launch) ----------------
#define CVT_BLOCKS 1440
__global__ __launch_bounds__(256) void prep_kernel(
    const float* __restrict__ Wp0, const float* __restrict__ Wp1,
    const float* __restrict__ Wo0, const float* __restrict__ Wo1,
    const float* __restrict__ Wf, const float* __restrict__ W1, const float* __restrict__ W2,
    __hip_bfloat16* __restrict__ wpT, __hip_bfloat16* __restrict__ wo0T,
    __hip_bfloat16* __restrict__ wo1T, __hip_bfloat16* __restrict__ wfT,
    __hip_bfloat16* __restrict__ w1T, __hip_bfloat16* __restrict__ w2T,
    const float* __restrict__ x, const float* __restrict__ g, const float* __restrict__ b,
    __hip_bfloat16* __restrict__ xn) {
    if (blockIdx.x >= CVT_BLOCKS) {
        int wave = threadIdx.x >> 6;
        int lane = threadIdx.x & 63;
        int row = (blockIdx.x - CVT_BLOCKS) * 4 + wave;
        if (row >= MROWS) return;
        const float* p = x + (size_t)row * CDIM;
        float x0 = p[lane];
        float x1 = (lane < 32) ? p[64 + lane] : 0.f;
        float s = x0 + x1, sq = x0 * x0 + x1 * x1;
#pragma unroll
        for (int o = 32; o >= 1; o >>= 1) { s += __shfl_xor(s, o); sq += __shfl_xor(sq, o); }
        float mean = s * (1.f / 96.f);
        float var = sq * (1.f / 96.f) - mean * mean;
        float w = rsqrtf(var + 1e-5f);
        __hip_bfloat16* q = xn + (size_t)row * CDIM;
        q[lane] = __float2bfloat16((x0 - mean) * w * g[lane] + b[lane]);
        if (lane < 32) q[64 + lane] = __float2bfloat16((x1 - mean) * w * g[64 + lane] + b[64 + lane]);
        return;
    }
    int i = blockIdx.x * 256 + threadIdx.x;
    const int S_WPALL = XPW2 * 96;
    const int S_WO = 96 * 192;
    const int S_WF = 96 * 1728;
    const int S_W1 = 384 * 96;
    const int S_W2 = 96 * 384;
    if (i < S_WPALL) {
        int j = i / 96, r = i % 96;
        int br = j / 480, cc = j % 480;
        const float* W = br ? Wp1 : Wp0;
        wpT[i] = __float2bfloat16(cc < 416 ? W[r * 576 + cc] : 0.f);
        return;
    }
    i -= S_WPALL;
    if (i < S_WO) { int c = i / 192, r = i % 192; wo0T[i] = __float2bfloat16(Wo0[r * 96 + c]); return; }
    i -= S_WO;
    if (i < S_WO) { int c = i / 192, r = i % 192; wo1T[i] = __float2bfloat16(Wo1[r * 96 + c]); return; }
    i -= S_WO;
    if (i < S_WF) { int c = i / 1728, k = i % 1728; wfT[i] = __float2bfloat16(Wf[k * 96 + c]); return; }
    i -= S_WF;
    if (i < S_W1) { int c = i / 96, r = i % 96; w1T[i] = __float2bfloat16(W1[r * 384 + c]); return; }
    i -= S_W1;
    if (i < S_W2) { int c = i / 384, r = i % 384; w2T[i] = __float2bfloat16(W2[r * 96 + c]); return; }
}

// ---------------- LDS-free direct-fragment MFMA GEMM (optional 2-way K-split) ----------------
template <int MI, int NI, int WR, int WC, int K, int KS, int EPI, typename CT>
__global__ __launch_bounds__(WR * WC * KS * 64) void gemm_direct(
    const __hip_bfloat16* __restrict__ A, int lda,
    const __hip_bfloat16* __restrict__ BT,
    CT* __restrict__ C, int ldc, int N,
    const float* __restrict__ bias, const float* __restrict__ res) {
    __shared__ float part[KS > 1 ? (WR * MI * 16) * (WC * NI * 16) : 1];
    int tid = threadIdx.x;
    int lane = tid & 63, wid = tid >> 6;
    int wk = wid / (WR * WC);
    int wrem = wid % (WR * WC);
    int wm = wrem % WR, wn = wrem / WR;
    int m0 = blockIdx.y * (WR * MI * 16) + wm * MI * 16;
    int n0 = blockIdx.x * (WC * NI * 16) + wn * NI * 16;
    int lr = lane & 15, kh = (lane >> 4) * 8;
    constexpr int KC = K / KS;
    f32x4 acc[MI][NI] = {};
    const __hip_bfloat16* Ap = A + (size_t)(m0 + lr) * lda + kh + wk * KC;
    const __hip_bfloat16* Bp = BT + (size_t)(n0 + lr) * K + kh + wk * KC;
#pragma unroll
    for (int k0 = 0; k0 < KC; k0 += 32) {
        bf16x8 af[MI], bf[NI];
#pragma unroll
        for (int i = 0; i < MI; ++i)
            af[i] = *reinterpret_cast<const bf16x8*>(Ap + (size_t)i * 16 * lda + k0);
#pragma unroll
        for (int j = 0; j < NI; ++j)
            bf[j] = *reinterpret_cast<const bf16x8*>(Bp + (size_t)j * 16 * K + k0);
#pragma unroll
        for (int i = 0; i < MI; ++i)
#pragma unroll
            for (int j = 0; j < NI; ++j)
                acc[i][j] = __builtin_amdgcn_mfma_f32_16x16x32_bf16(af[i], bf[j], acc[i][j], 0, 0, 0);
    }
    int cr = (lane >> 4) << 2;
    if (KS > 1) {
        constexpr int BN = WC * NI * 16;
        if (wk == 1) {
#pragma unroll
            for (int i = 0; i < MI; ++i)
#pragma unroll
                for (int j = 0; j < NI; ++j)
#pragma unroll
                    for (int q = 0; q < 4; ++q)
                        part[(wm * MI * 16 + i * 16 + cr + q) * BN + wn * NI * 16 + j * 16 + lr] =
                            acc[i][j][q];
        }
        __syncthreads();
        if (wk != 0) return;
#pragma unroll
        for (int i = 0; i < MI; ++i)
#pragma unroll
            for (int j = 0; j < NI; ++j)
#pragma unroll
                for (int q = 0; q < 4; ++q)
                    acc[i][j][q] +=
                        part[(wm * MI * 16 + i * 16 + cr + q) * BN + wn * NI * 16 + j * 16 + lr];
    }
#pragma unroll
    for (int i = 0; i < MI; ++i) {
        int row = m0 + i * 16 + cr;
#pragma unroll
        for (int j = 0; j < NI; ++j) {
            int col = n0 + j * 16 + lr;
            if (col < N) {
#pragma unroll
                for (int q = 0; q < 4; ++q) {
                    float v = acc[i][j][q];
                    if (EPI == 1) v = gelu_exact(v + bias[col]);
                    else if (EPI == 2) v = v + bias[col] + res[(size_t)(row + q) * ldc + col];
                    C[(size_t)(row + q) * ldc + col] = (CT)v;
                }
            }
        }
    }
}

// ---------------- Wo GEMM both branches + LN + cosine fuse -> cat (bf16) ----------------
__global__ __launch_bounds__(256) void gemm_wo_ln_fuse(
    const __hip_bfloat16* __restrict__ A,      // yb [2*8192][192]
    const __hip_bfloat16* __restrict__ BT0, const __hip_bfloat16* __restrict__ BT1,
    const float* __restrict__ g0, const float* __restrict__ b0,
    const float* __restrict__ g1, const float* __restrict__ b1,
    __hip_bfloat16* __restrict__ cat) {        // [8192][192]
    int tid = threadIdx.x;
    int lane = tid & 63, wid = tid >> 6;
    int wm = wid & 1, wn = wid >> 1;
    int m0 = blockIdx.x * 32 + wm * 16;
    int n0 = wn * 48;
    int lr = lane & 15, kh = (lane >> 4) * 8;
    f32x4 acc0[3] = {}, acc1[3] = {};
    const __hip_bfloat16* A0 = A + (size_t)(m0 + lr) * 192 + kh;
    const __hip_bfloat16* A1 = A + (size_t)(MROWS + m0 + lr) * 192 + kh;
    const __hip_bfloat16* Bp0 = BT0 + (size_t)(n0 + lr) * 192 + kh;
    const __hip_bfloat16* Bp1 = BT1 + (size_t)(n0 + lr) * 192 + kh;
#pragma unroll
    for (int k0 = 0; k0 < 192; k0 += 32) {
        bf16x8 af0 = *reinterpret_cast<const bf16x8*>(A0 + k0);
        bf16x8 af1 = *reinterpret_cast<const bf16x8*>(A1 + k0);
#pragma unroll
        for (int j = 0; j < 3; ++j) {
            bf16x8 b0v = *reinterpret_cast<const bf16x8*>(Bp0 + (size_t)j * 16 * 192 + k0);
            bf16x8 b1v = *reinterpret_cast<const bf16x8*>(Bp1 + (size_t)j * 16 * 192 + k0);
            acc0[j] = __builtin_amdgcn_mfma_f32_16x16x32_bf16(af0, b0v, acc0[j], 0, 0, 0);
            acc1[j] = __builtin_amdgcn_mfma_f32_16x16x32_bf16(af1, b1v, acc1[j], 0, 0, 0);
        }
    }
    __shared__ float ct0[32][100], ct1[32][100];
    int cr = (lane >> 4) << 2;
#pragma unroll
    for (int j = 0; j < 3; ++j)
#pragma unroll
        for (int q = 0; q < 4; ++q) {
            ct0[wm * 16 + cr + q][n0 + j * 16 + lr] = acc0[j][q];
            ct1[wm * 16 + cr + q][n0 + j * 16 + lr] = acc1[j][q];
        }
    __syncthreads();
#pragma unroll
    for (int rr = 0; rr < 8; ++rr) {
        int row = wid * 8 + rr;
        float a0 = ct0[row][lane];
        float a1 = (lane < 32) ? ct0[row][64 + lane] : 0.f;
        float c0 = ct1[row][lane];
        float c1 = (lane < 32) ? ct1[row][64 + lane] : 0.f;
        float s0 = a0 + a1, q0 = a0 * a0 + a1 * a1;
        float s1 = c0 + c1, q1 = c0 * c0 + c1 * c1;
#pragma unroll
        for (int o = 32; o >= 1; o >>= 1) {
            s0 += __shfl_xor(s0, o); q0 += __shfl_xor(q0, o);
            s1 += __shfl_xor(s1, o); q1 += __shfl_xor(q1, o);
        }
        float mu0 = s0 * (1.f / 96.f), w0 = rsqrtf(q0 * (1.f / 96.f) - mu0 * mu0 + 1e-5f);
        float mu1 = s1 * (1.f / 96.f), w1 = rsqrtf(q1 * (1.f / 96.f) - mu1 * mu1 + 1e-5f);
        float f1a = (a0 - mu0) * w0 * g0[lane] + b0[lane];
        float f2a = (c0 - mu1) * w1 * g1[lane] + b1[lane];
        float f1b = 0.f, f2b = 0.f;
        if (lane < 32) {
            f1b = (a1 - mu0) * w0 * g0[64 + lane] + b0[64 + lane];
            f2b = (c1 - mu1) * w1 * g1[64 + lane] + b1[64 + lane];
        }
        float s11 = f1a * f1a + f1b * f1b;
        float s22 = f2a * f2a + f2b * f2b;
        float s12 = f1a * f2a + f1b * f2b;
#pragma unroll
        for (int o = 32; o >= 1; o >>= 1) {
            s11 += __shfl_xor(s11, o);
            s22 += __shfl_xor(s22, o);
            s12 += __shfl_xor(s12, o);
        }
        float nr1 = fmaxf(sqrtf(s11), 1e-12f);
        float nr2 = fmaxf(sqrtf(s22), 1e-12f);
        float sim = s12 / (nr1 * nr2);
        size_t grow = (size_t)blockIdx.x * 32 + row;
        __hip_bfloat16* q = cat + grow * 192;
        q[lane] = __float2bfloat16(f1a);
        q[96 + lane] = __float2bfloat16(sim * f1a + (1.f - sim) * f2a);
        if (lane < 32) {
            q[64 + lane] = __float2bfloat16(f1b);
            q[96 + 64 + lane] = __float2bfloat16(sim * f1b + (1.f - sim) * f2b);
        }
    }
}

// ---------------- 3x3 SAME conv, K-split implicit MFMA GEMM (8 waves) ----------------
__global__ __launch_bounds__(512) void conv3x3_direct(const __hip_bfloat16* __restrict__ cat,
                                                      const __hip_bfloat16* __restrict__ WfT,
                                                      const float* __restrict__ bfv,
                                                      __hip_bfloat16* __restrict__ out) {
    __shared__ float part[32][96];
    int tid = threadIdx.x;
    int lane = tid & 63, wid = tid >> 6;
    int wm = wid & 1, wn = (wid >> 1) & 1, wk = wid >> 2;
    int m0 = blockIdx.x * 32 + wm * 16;
    int n0 = wn * 48;
    int lr = lane & 15, kh = (lane >> 4) * 8;
    int m = m0 + lr;
    int bb = m >> 12, l = m & 4095, yy = l >> 6, xx = l & 63;
    f32x4 acc[3] = {};
    const __hip_bfloat16* Bp = WfT + (size_t)(n0 + lr) * 1728 + kh;
#pragma unroll
    for (int tap = 0; tap < 9; ++tap) {
        if ((tap & 1) != wk) continue;   // wave-uniform K split (5 even / 4 odd taps)
        int ky = tap / 3, kx = tap % 3;
        int iy = yy + ky - 1, ix = xx + kx - 1;
        bool ok = ((unsigned)iy < 64u) && ((unsigned)ix < 64u);
        const __hip_bfloat16* Ap = cat + ((size_t)bb * 4096 + (size_t)(iy * 64 + ix)) * 192 + kh;
        int kbase = tap * 192;
#pragma unroll
        for (int kc = 0; kc < 192; kc += 32) {
            bf16x8 af = {};
            if (ok) af = *reinterpret_cast<const bf16x8*>(Ap + kc);
#pragma unroll
            for (int j = 0; j < 3; ++j) {
                bf16x8 bf = *reinterpret_cast<const bf16x8*>(Bp + (size_t)j * 16 * 1728 + kbase + kc);
                acc[j] = __builtin_amdgcn_mfma_f32_16x16x32_bf16(af, bf, acc[j], 0, 0, 0);
            }
        }
    }
    int cr = (lane >> 4) << 2;
    if (wk == 1) {
#pragma unroll
        for (int j = 0; j < 3; ++j)
#pragma unroll
            for (int q = 0; q < 4; ++q)
                part[wm * 16 + cr + q][n0 + j * 16 + lr] = acc[j][q];
    }
    __syncthreads();
    if (wk != 0) return;
    int crow = m0 + cr;
#pragma unroll
    for (int j = 0; j < 3; ++j) {
        int ccol = n0 + j * 16 + lr;
#pragma unroll
        for (int q = 0; q < 4; ++q) {
            float v = acc[j][q] + part[wm * 16 + cr + q][ccol];
            v = gelu_exact(v + bfv[ccol]);
            out[(size_t)(crow + q) * 96 + ccol] = __float2bfloat16(v);
        }
    }
}

// ---------------- scan pass1 (fused conv+sigmoid), direction-split (4 fwd + 4 bwd waves) ----
__global__ __launch_bounds__(512) void scan_pass1f(
    const __hip_bfloat16* __restrict__ xpw,
    const float* __restrict__ cw0, const float* __restrict__ cw1,
    const float* __restrict__ cb0, const float* __restrict__ cb1,
    const float* __restrict__ A0, const float* __restrict__ A1,
    float* __restrict__ Pc, float* __restrict__ Hf, float* __restrict__ Gb) {
    __shared__ unsigned short rawxu[67][16];
    __shared__ float2 sdx[CHLEN][16];
    __shared__ float sb[CHLEN][16];
    __shared__ float asumv[16];
    int bid = (blockIdx.x & 7) * (SCAN_GRID / 8) + (blockIdx.x >> 3);  // XCD swizzle
    int dg = bid % 12;
    int c = (bid / 12) % NCHUNK;
    int b = (bid / (12 * NCHUNK)) & 1;
    int p = bid / (12 * NCHUNK * 2);
    const float* cw = p ? cw1 : cw0;
    const float* cbp = p ? cb1 : cb0;
    const float* Am = p ? A1 : A0;
    int tid = threadIdx.x;
    if (tid < 16) {
        const float4* Ap4 = (const float4*)(Am + tid * 16);
        float4 a0 = Ap4[0], a1 = Ap4[1], a2 = Ap4[2], a3 = Ap4[3];
        float s = (a0.x + a0.y + a0.z + a0.w) + (a1.x + a1.y + a1.z + a1.w) +
                  (a2.x + a2.y + a2.z + a2.w) + (a3.x + a3.y + a3.z + a3.w);
        asumv[tid] = s * 1.44269504f;
    }
    const unsigned short* xu = (const unsigned short*)xpw;
    int xb = p * 480;
    int t0 = c * CHLEN;
    int r = tid >> 2, q = (tid & 3) * 4;
    u16x4 dvu = {0, 0, 0, 0};
    if (tid < 256) {
        size_t grow = (size_t)b * L_SEQ + t0 + r;
        const unsigned short* rowp = xu + grow * XPW2 + xb;
        *(u16x4*)&rawxu[r + 3][q] = *(const u16x4*)(rowp + dg * 16 + q);
        dvu = *(const u16x4*)(rowp + 192 + dg * 16 + q);
        u16x4 bvu = *(const u16x4*)(rowp + 384 + q);
        float4 bf4 = {b2f(bvu.x), b2f(bvu.y), b2f(bvu.z), b2f(bvu.w)};
        *(float4*)&sb[r][q] = bf4;
        if (tid < 12) {
            int rr = tid >> 2, qq = (tid & 3) * 4;
            int src = t0 - 3 + rr;
            u16x4 v = {0, 0, 0, 0};
            if (src >= 0)
                v = *(const u16x4*)(xu + ((size_t)b * L_SEQ + src) * XPW2 + xb + dg * 16 + qq);
            *(u16x4*)&rawxu[rr][qq] = v;
        }
    }
    __syncthreads();
    if (tid < 256) {
        float dd[4] = {b2f(dvu.x), b2f(dvu.y), b2f(dvu.z), b2f(dvu.w)};
#pragma unroll
        for (int i = 0; i < 4; ++i) {
            int d = dg * 16 + q + i;
            float4 w = *(const float4*)(cw + (size_t)d * 4);
            float xc = cbp[d] + w.w * b2f(rawxu[r + 3][q + i]) + w.z * b2f(rawxu[r + 2][q + i]) +
                       w.y * b2f(rawxu[r + 1][q + i]) + w.x * b2f(rawxu[r][q + i]);
            float ds = 1.f / (1.f + __expf(-dd[i]));
            sdx[r][q + i] = make_float2(ds, ds * xc);
        }
    }
    __syncthreads();
    int lane = tid & 63, wave = tid >> 6;
    int dir = wave >> 2, wl = wave & 3;
    int n = lane & 15;
    int drow = wl * 4 + (lane >> 4);
    float asum2 = asumv[n];
    size_t cidx = ((((size_t)p * 2 + b) * NST + n) * DIN + dg * 16 + drow) * NCHUNK + c;
    if (dir == 0) {
        // forward local scan: h_t = a_t h_{t-1} + bu_t
        float h = 0.f;
#pragma unroll 4
        for (int t = 0; t < CHLEN; ++t) {
            float2 dx = sdx[t][drow];
            float bm = sb[t][n];
            float a = fast_exp2(dx.x * asum2);
            h = a * h + dx.y * bm;
        }
        Hf[cidx] = h;
    } else {
        // Gb = sum_t (prod_{s<t} a_s) bu_t  via backward recurrence G = a_t G + bu_t;
        // P = prod a (order-independent)
        float G = 0.f, Q = 1.f;
#pragma unroll 4
        for (int t = CHLEN - 1; t >= 0; --t) {
            float2 dx = sdx[t][drow];
            float bm = sb[t][n];
            float a = fast_exp2(dx.x * asum2);
            G = a * G + dx.y * bm;
            Q *= a;
        }
        Gb[cidx] = G;
        Pc[cidx] = Q;
    }
}

// ---------------- scan pass2: combine chunk carries (contiguous float4 loads) ----------------
__global__ __launch_bounds__(256) void scan_pass2(const float* __restrict__ Pc,
                                                  const float* __restrict__ Hf,
                                                  const float* __restrict__ Gb,
                                                  float* __restrict__ Hinf,
                                                  float* __restrict__ Hinb) {
    int t = blockIdx.x * 256 + threadIdx.x;
    if (t >= 2 * 2 * NST * DIN) return;
    size_t base = (size_t)t * NCHUNK;
    {
        float4 P4[16], H4[16];
        const float4* Pp = (const float4*)(Pc + base);
        const float4* Hp = (const float4*)(Hf + base);
#pragma unroll
        for (int i = 0; i < 16; ++i) { P4[i] = Pp[i]; H4[i] = Hp[i]; }
        float hin = 0.f;
        float4* Op = (float4*)(Hinf + base);
#pragma unroll
        for (int i = 0; i < 16; ++i) {
            float4 o;
            o.x = hin; hin = H4[i].x + P4[i].x * hin;
            o.y = hin; hin = H4[i].y + P4[i].y * hin;
            o.z = hin; hin = H4[i].z + P4[i].z * hin;
            o.w = hin; hin = H4[i].w + P4[i].w * hin;
            Op[i] = o;
        }
    }
    {
        float4 P4[16], G4[16];
        const float4* Pp = (const float4*)(Pc + base);
        const float4* Gp = (const float4*)(Gb + base);
#pragma unroll
        for (int i = 0; i < 16; ++i) { P4[i] = Pp[i]; G4[i] = Gp[i]; }
        float gin = 0.f;
        float4* Op = (float4*)(Hinb + base);
#pragma unroll
        for (int i = 15; i >= 0; --i) {
            float4 o;
            o.w = gin; gin = G4[i].w + P4[i].w * gin;
            o.z = gin; gin = G4[i].z + P4[i].z * gin;
            o.y = gin; gin = G4[i].y + P4[i].y * gin;
            o.x = gin; gin = G4[i].x + P4[i].x * gin;
            Op[i] = o;
        }
    }
}

// ---------------- scan pass3 (fused conv): direction-split waves (4 fwd + 4 bwd) ----------------
__global__ __launch_bounds__(512) void scan_pass3f(
    const __hip_bfloat16* __restrict__ xpw,
    const float* __restrict__ cw0, const float* __restrict__ cw1,
    const float* __restrict__ cb0, const float* __restrict__ cb1,
    const float* __restrict__ A0, const float* __restrict__ A1,
    const float* __restrict__ Hinf, const float* __restrict__ Hinb,
    const float* __restrict__ Dp0, const float* __restrict__ Dp1,
    __hip_bfloat16* __restrict__ y) {
    __shared__ unsigned short rawxu[67][16];
    __shared__ float2 sdx[CHLEN][16];        // (ds, ds*xc)
    __shared__ float2 sbc[CHLEN][16];        // (Bm, Cm)
    __shared__ unsigned short sxcu[CHLEN][16];  // xc as bf16 (epilogue Dp*xc)
    __shared__ float ysf[CHLEN][16], ysb[CHLEN][16];
    __shared__ float asumv[16];
    int bid = (blockIdx.x & 7) * (SCAN_GRID / 8) + (blockIdx.x >> 3);  // XCD swizzle
    int dg = bid % 12;
    int c = (bid / 12) % NCHUNK;
    int b = (bid / (12 * NCHUNK)) & 1;
    int p = bid / (12 * NCHUNK * 2);
    const float* cw = p ? cw1 : cw0;
    const float* cbp = p ? cb1 : cb0;
    const float* Am = p ? A1 : A0;
    const float* Dp = p ? Dp1 : Dp0;
    int tid = threadIdx.x;
    if (tid < 16) {
        const float4* Ap4 = (const float4*)(Am + tid * 16);
        float4 a0 = Ap4[0], a1 = Ap4[1], a2 = Ap4[2], a3 = Ap4[3];
        float s = (a0.x + a0.y + a0.z + a0.w) + (a1.x + a1.y + a1.z + a1.w) +
                  (a2.x + a2.y + a2.z + a2.w) + (a3.x + a3.y + a3.z + a3.w);
        asumv[tid] = s * 1.44269504f;
    }
    const unsigned short* xu = (const unsigned short*)xpw;
    int xb = p * 480;
    int t0 = c * CHLEN;
    int r = tid >> 2, q = (tid & 3) * 4;
    u16x4 dvu = {0, 0, 0, 0};
    if (tid < 256) {
        size_t grow = (size_t)b * L_SEQ + t0 + r;
        const unsigned short* rowp = xu + grow * XPW2 + xb;
        *(u16x4*)&rawxu[r + 3][q] = *(const u16x4*)(rowp + dg * 16 + q);
        dvu = *(const u16x4*)(rowp + 192 + dg * 16 + q);
        u16x4 bvu = *(const u16x4*)(rowp + 384 + q);
        u16x4 cvu = *(const u16x4*)(rowp + 400 + q);
        sbc[r][q + 0] = make_float2(b2f(bvu.x), b2f(cvu.x));
        sbc[r][q + 1] = make_float2(b2f(bvu.y), b2f(cvu.y));
        sbc[r][q + 2] = make_float2(b2f(bvu.z), b2f(cvu.z));
        sbc[r][q + 3] = make_float2(b2f(bvu.w), b2f(cvu.w));
        if (tid < 12) {
            int rr = tid >> 2, qq = (tid & 3) * 4;
            int src = t0 - 3 + rr;
            u16x4 v = {0, 0, 0, 0};
            if (src >= 0)
                v = *(const u16x4*)(xu + ((size_t)b * L_SEQ + src) * XPW2 + xb + dg * 16 + qq);
            *(u16x4*)&rawxu[rr][qq] = v;
        }
    }
    __syncthreads();
    if (tid < 256) {
        float dd[4] = {b2f(dvu.x), b2f(dvu.y), b2f(dvu.z), b2f(dvu.w)};
#pragma unroll
        for (int i = 0; i < 4; ++i) {
            int d = dg * 16 + q + i;
            float4 w = *(const float4*)(cw + (size_t)d * 4);
            float xc = cbp[d] + w.w * b2f(rawxu[r + 3][q + i]) + w.z * b2f(rawxu[r + 2][q + i]) +
                       w.y * b2f(rawxu[r + 1][q + i]) + w.x * b2f(rawxu[r][q + i]);
            float ds = 1.f / (1.f + __expf(-dd[i]));
            sdx[r][q + i] = make_float2(ds, ds * xc);
            sxcu[r][q + i] = f2bf_bits(xc);
        }
    }
    __syncthreads();
    int lane = tid & 63, wave = tid >> 6;   // 8 waves
    int dir = wave >> 2;                    // 0 = fwd (waves 0-3), 1 = bwd (waves 4-7)
    int wl = wave & 3;
    int n = lane & 15;
    int dloc = wl * 4 + (lane >> 4);
    int d = dg * 16 + dloc;
    float asum2 = asumv[n];
    size_t cidx = ((((size_t)p * 2 + b) * NST + n) * DIN + d) * NCHUNK + c;
    if (dir == 0) {
        float h = Hinf[cidx];
#pragma unroll 4
        for (int t = 0; t < CHLEN; ++t) {
            float2 dx = sdx[t][dloc];
            float2 bc = sbc[t][n];
            float a = fast_exp2(dx.x * asum2);
            h = a * h + dx.y * bc.x;
            float pf = rowsum16(bc.y * h);
            if (n == 0) ysf[t][dloc] = pf;
        }
    } else {
        float gv = Hinb[cidx];
#pragma unroll 4
        for (int t = CHLEN - 1; t >= 0; --t) {
            float2 dx = sdx[t][dloc];
            float2 bc = sbc[t][n];
            float a = fast_exp2(dx.x * asum2);
            gv = a * gv + dx.y * bc.x;
            float pb = rowsum16(bc.y * gv);
            if (n == 0) ysb[t][dloc] = pb;
        }
    }
    __syncthreads();
    if (tid < 256) {
        int tl = tid >> 2, qq = (tid & 3) * 4;
        int d2 = dg * 16 + qq;
        float4 Dv = *(const float4*)(Dp + d2);
        float vs[4];
#pragma unroll
        for (int i = 0; i < 4; ++i)
            vs[i] = ysf[tl][qq + i] + ysb[tl][qq + i] +
                    ((const float*)&Dv)[i] * b2f(sxcu[tl][qq + i]);
        s16x4 pk = {(short)f2bf_bits(vs[0]), (short)f2bf_bits(vs[1]),
                    (short)f2bf_bits(vs[2]), (short)f2bf_bits(vs[3])};
        size_t row = (size_t)b * L_SEQ + t0 + tl;
        *(s16x4*)((unsigned short*)y + ((size_t)p * MROWS + row) * DIN + d2) = pk;
    }
}

extern "C" void kernel_launch(void* const* d_in, const int* in_sizes, int n_in,
                              void* d_out, int out_size, void* d_ws, size_t ws_size,
                              hipStream_t stream) {
    const float* x = (const float*)d_in[0];
    const float* norm_g = (const float*)d_in[1];
    const float* norm_b = (const float*)d_in[2];
    const float* Wp[2] = {(const float*)d_in[3], (const float*)d_in[11]};
    const float* cw[2] = {(const float*)d_in[4], (const float*)d_in[12]};
    const float* cb[2] = {(const float*)d_in[5], (const float*)d_in[13]};
    const float* Ab[2] = {(const float*)d_in[6], (const float*)d_in[14]};
    const float* Dpb[2] = {(const float*)d_in[7], (const float*)d_in[15]};
    const float* Wo[2] = {(const float*)d_in[8], (const float*)d_in[16]};
    const float* lng[2] = {(const float*)d_in[9], (const float*)d_in[17]};
    const float* lnb[2] = {(const float*)d_in[10], (const float*)d_in[18]};
    const float* Wf = (const float*)d_in[19];
    const float* bfv = (const float*)d_in[20];
    const float* W1 = (const float*)d_in[21];
    const float* b1 = (const float*)d_in[22];
    const float* W2 = (const float*)d_in[23];
    const float* b2 = (const float*)d_in[24];
    float* out = (float*)d_out;

    char* base = (char*)d_ws;
    size_t off = 0;
    auto alloc = [&](size_t bytes) { void* p = base + off; off += (bytes + 255) & ~(size_t)255; return p; };
    __hip_bfloat16* xpw = (__hip_bfloat16*)alloc((size_t)MROWS * XPW2 * 2);
    const size_t csz = (size_t)2 * 2 * NST * DIN * NCHUNK;
    float* Pc = (float*)alloc(csz * 4);
    float* Hfc = (float*)alloc(csz * 4);
    float* Gbc = (float*)alloc(csz * 4);
    float* Hinf = (float*)alloc(csz * 4);
    float* Hinb = (float*)alloc(csz * 4);
    __hip_bfloat16* xn_bf = (__hip_bfloat16*)alloc((size_t)MROWS * 96 * 2);
    __hip_bfloat16* yb_bf = (__hip_bfloat16*)alloc((size_t)2 * MROWS * DIN * 2);
    __hip_bfloat16* cat_bf = (__hip_bfloat16*)alloc((size_t)MROWS * DIN * 2);
    __hip_bfloat16* fc_bf = (__hip_bfloat16*)alloc((size_t)MROWS * 96 * 2);
    __hip_bfloat16* h1_bf = (__hip_bfloat16*)alloc((size_t)MROWS * 384 * 2);
    __hip_bfloat16* wpT = (__hip_bfloat16*)alloc((size_t)XPW2 * 96 * 2);
    __hip_bfloat16* woT[2] = {(__hip_bfloat16*)alloc(96 * 192 * 2),
                              (__hip_bfloat16*)alloc(96 * 192 * 2)};
    __hip_bfloat16* wfT = (__hip_bfloat16*)alloc(96 * 1728 * 2);
    __hip_bfloat16* w1T = (__hip_bfloat16*)alloc(384 * 96 * 2);
    __hip_bfloat16* w2T = (__hip_bfloat16*)alloc(96 * 384 * 2);
    (void)ws_size; (void)in_sizes; (void)n_in; (void)out_size;

    // 1. weights convert/transpose + input LN (one launch)
    prep_kernel<<<dim3(CVT_BLOCKS + 2048), dim3(256), 0, stream>>>(
        Wp[0], Wp[1], Wo[0], Wo[1], Wf, W1, W2,
        wpT, woT[0], woT[1], wfT, w1T, w2T, x, norm_g, norm_b, xn_bf);
    // 2. xp(both branches, bf16) = xn @ [Wp1|Wp2]
    gemm_direct<2, 3, 2, 2, 96, 1, 0, __hip_bfloat16><<<dim3(10, 128), dim3(256), 0, stream>>>(
        xn_bf, 96, wpT, xpw, XPW2, XPW2, nullptr, nullptr);
    // 3-5. bidirectional selective scan, both branches (direction-split waves)
    scan_pass1f<<<dim3(SCAN_GRID), dim3(512), 0, stream>>>(
        xpw, cw[0], cw[1], cb[0], cb[1], Ab[0], Ab[1], Pc, Hfc, Gbc);
    scan_pass2<<<dim3(48), dim3(256), 0, stream>>>(Pc, Hfc, Gbc, Hinf, Hinb);
    scan_pass3f<<<dim3(SCAN_GRID), dim3(512), 0, stream>>>(
        xpw, cw[0], cw[1], cb[0], cb[1], Ab[0], Ab[1], Hinf, Hinb, Dpb[0], Dpb[1], yb_bf);
    // 6. f1/f2 = LN(y@Wo), cosine fuse -> cat
    gemm_wo_ln_fuse<<<dim3(256), dim3(256), 0, stream>>>(
        yb_bf, woT[0], woT[1], lng[0], lnb[0], lng[1], lnb[1], cat_bf);
    // 7. fc = gelu(conv3x3(cat) + bf)  (K-split, 8 waves)
    conv3x3_direct<<<dim3(256), dim3(512), 0, stream>>>(cat_bf, wfT, bfv, fc_bf);
    // 8. h1 = gelu(fc @ W1 + b1)
    gemm_direct<2, 3, 2, 2, 96, 1, 1, __hip_bfloat16><<<dim3(4, 128), dim3(256), 0, stream>>>(
        fc_bf, 96, w1T, h1_bf, 384, 384, b1, nullptr);
    // 9. out = h1 @ W2 + b2 + res  (K-split, 8 waves)
    gemm_direct<1, 3, 2, 2, 384, 2, 2, float><<<dim3(1, 256), dim3(512), 0, stream>>>(
        h1_bf, 384, w2T, out, 96, 96, b2, x);
}

// Round 13
// 152.927 us; speedup vs baseline: 1.0302x; 1.0302x over previous
//
#include <hip/hip_runtime.h>
#include <hip/hip_bf16.h>
#include <math.h>

#define L_SEQ 4096
#define CDIM 96
#define DIN 192
#define NST 16
#define NCHUNK 64
#define CHLEN 64
#define MROWS 8192
#define XPW2 960   // combined xp width: 2 branches x 480 (416 used + pad)
#define SCAN_GRID 3072

typedef __attribute__((ext_vector_type(8))) short bf16x8;
typedef __attribute__((ext_vector_type(4))) float f32x4;
typedef __attribute__((ext_vector_type(4))) short s16x4;
typedef __attribute__((ext_vector_type(4))) unsigned short u16x4;

__device__ __forceinline__ float gelu_exact(float x) {
    return 0.5f * x * (1.0f + erff(x * 0.70710678118654752f));
}

__device__ __forceinline__ float fast_exp2(float x) {
#if __has_builtin(__builtin_amdgcn_exp2f)
    return __builtin_amdgcn_exp2f(x);
#else
    return exp2f(x);
#endif
}

__device__ __forceinline__ float b2f(unsigned short u) {
    return __uint_as_float((unsigned int)u << 16);
}

// 16-lane DPP row reduction via explicit v_add_f32_dpp (guaranteed fused form;
// row_ror rotates within each 16-lane row, all lanes valid). Leaves the row
// sum in all 16 lanes.
__device__ __forceinline__ float rowsum16(float s) {
    asm("v_add_f32_dpp %0, %0, %0 row_ror:8 row_mask:0xf bank_mask:0xf" : "+v"(s));
    asm("v_add_f32_dpp %0, %0, %0 row_ror:4 row_mask:0xf bank_mask:0xf" : "+v"(s));
    asm("v_add_f32_dpp %0, %0, %0 row_ror:2 row_mask:0xf bank_mask:0xf" : "+v"(s));
    asm("v_add_f32_dpp %0, %0, %0 row_ror:1 row_mask:0xf bank_mask:0xf" : "+v"(s));
    return s;
}

__device__ __forceinline__ unsigned short f2bf_bits(float f) {
    __hip_bfloat16 h = __float2bfloat16(f);
    return *reinterpret_cast<unsigned short*>(&h);
}

// ---------------- prep: weight convert/transpose + input LayerNorm (one launch) ----------------
#define CVT_BLOCKS 1440
__global__ __launch_bounds__(256) void prep_kernel(
    const float* __restrict__ Wp0, const float* __restrict__ Wp1,
    const float* __restrict__ Wo0, const float* __restrict__ Wo1,
    const float* __restrict__ Wf, const float* __restrict__ W1, const float* __restrict__ W2,
    __hip_bfloat16* __restrict__ wpT, __hip_bfloat16* __restrict__ wo0T,
    __hip_bfloat16* __restrict__ wo1T, __hip_bfloat16* __restrict__ wfT,
    __hip_bfloat16* __restrict__ w1T, __hip_bfloat16* __restrict__ w2T,
    const float* __restrict__ x, const float* __restrict__ g, const float* __restrict__ b,
    __hip_bfloat16* __restrict__ xn) {
    if (blockIdx.x >= CVT_BLOCKS) {
        int wave = threadIdx.x >> 6;
        int lane = threadIdx.x & 63;
        int row = (blockIdx.x - CVT_BLOCKS) * 4 + wave;
        if (row >= MROWS) return;
        const float* p = x + (size_t)row * CDIM;
        float x0 = p[lane];
        float x1 = (lane < 32) ? p[64 + lane] : 0.f;
        float s = x0 + x1, sq = x0 * x0 + x1 * x1;
#pragma unroll
        for (int o = 32; o >= 1; o >>= 1) { s += __shfl_xor(s, o); sq += __shfl_xor(sq, o); }
        float mean = s * (1.f / 96.f);
        float var = sq * (1.f / 96.f) - mean * mean;
        float w = rsqrtf(var + 1e-5f);
        __hip_bfloat16* q = xn + (size_t)row * CDIM;
        q[lane] = __float2bfloat16((x0 - mean) * w * g[lane] + b[lane]);
        if (lane < 32) q[64 + lane] = __float2bfloat16((x1 - mean) * w * g[64 + lane] + b[64 + lane]);
        return;
    }
    int i = blockIdx.x * 256 + threadIdx.x;
    const int S_WPALL = XPW2 * 96;
    const int S_WO = 96 * 192;
    const int S_WF = 96 * 1728;
    const int S_W1 = 384 * 96;
    const int S_W2 = 96 * 384;
    if (i < S_WPALL) {
        int j = i / 96, r = i % 96;
        int br = j / 480, cc = j % 480;
        const float* W = br ? Wp1 : Wp0;
        wpT[i] = __float2bfloat16(cc < 416 ? W[r * 576 + cc] : 0.f);
        return;
    }
    i -= S_WPALL;
    if (i < S_WO) { int c = i / 192, r = i % 192; wo0T[i] = __float2bfloat16(Wo0[r * 96 + c]); return; }
    i -= S_WO;
    if (i < S_WO) { int c = i / 192, r = i % 192; wo1T[i] = __float2bfloat16(Wo1[r * 96 + c]); return; }
    i -= S_WO;
    if (i < S_WF) { int c = i / 1728, k = i % 1728; wfT[i] = __float2bfloat16(Wf[k * 96 + c]); return; }
    i -= S_WF;
    if (i < S_W1) { int c = i / 96, r = i % 96; w1T[i] = __float2bfloat16(W1[r * 384 + c]); return; }
    i -= S_W1;
    if (i < S_W2) { int c = i / 384, r = i % 384; w2T[i] = __float2bfloat16(W2[r * 96 + c]); return; }
}

// ---------------- LDS-free direct-fragment MFMA GEMM (optional 2-way K-split) ----------------
template <int MI, int NI, int WR, int WC, int K, int KS, int EPI, typename CT>
__global__ __launch_bounds__(WR * WC * KS * 64) void gemm_direct(
    const __hip_bfloat16* __restrict__ A, int lda,
    const __hip_bfloat16* __restrict__ BT,
    CT* __restrict__ C, int ldc, int N,
    const float* __restrict__ bias, const float* __restrict__ res) {
    __shared__ float part[KS > 1 ? (WR * MI * 16) * (WC * NI * 16) : 1];
    int tid = threadIdx.x;
    int lane = tid & 63, wid = tid >> 6;
    int wk = wid / (WR * WC);
    int wrem = wid % (WR * WC);
    int wm = wrem % WR, wn = wrem / WR;
    int m0 = blockIdx.y * (WR * MI * 16) + wm * MI * 16;
    int n0 = blockIdx.x * (WC * NI * 16) + wn * NI * 16;
    int lr = lane & 15, kh = (lane >> 4) * 8;
    constexpr int KC = K / KS;
    f32x4 acc[MI][NI] = {};
    const __hip_bfloat16* Ap = A + (size_t)(m0 + lr) * lda + kh + wk * KC;
    const __hip_bfloat16* Bp = BT + (size_t)(n0 + lr) * K + kh + wk * KC;
#pragma unroll
    for (int k0 = 0; k0 < KC; k0 += 32) {
        bf16x8 af[MI], bf[NI];
#pragma unroll
        for (int i = 0; i < MI; ++i)
            af[i] = *reinterpret_cast<const bf16x8*>(Ap + (size_t)i * 16 * lda + k0);
#pragma unroll
        for (int j = 0; j < NI; ++j)
            bf[j] = *reinterpret_cast<const bf16x8*>(Bp + (size_t)j * 16 * K + k0);
#pragma unroll
        for (int i = 0; i < MI; ++i)
#pragma unroll
            for (int j = 0; j < NI; ++j)
                acc[i][j] = __builtin_amdgcn_mfma_f32_16x16x32_bf16(af[i], bf[j], acc[i][j], 0, 0, 0);
    }
    int cr = (lane >> 4) << 2;
    if (KS > 1) {
        constexpr int BN = WC * NI * 16;
        if (wk == 1) {
#pragma unroll
            for (int i = 0; i < MI; ++i)
#pragma unroll
                for (int j = 0; j < NI; ++j)
#pragma unroll
                    for (int q = 0; q < 4; ++q)
                        part[(wm * MI * 16 + i * 16 + cr + q) * BN + wn * NI * 16 + j * 16 + lr] =
                            acc[i][j][q];
        }
        __syncthreads();
        if (wk != 0) return;
#pragma unroll
        for (int i = 0; i < MI; ++i)
#pragma unroll
            for (int j = 0; j < NI; ++j)
#pragma unroll
                for (int q = 0; q < 4; ++q)
                    acc[i][j][q] +=
                        part[(wm * MI * 16 + i * 16 + cr + q) * BN + wn * NI * 16 + j * 16 + lr];
    }
#pragma unroll
    for (int i = 0; i < MI; ++i) {
        int row = m0 + i * 16 + cr;
#pragma unroll
        for (int j = 0; j < NI; ++j) {
            int col = n0 + j * 16 + lr;
            if (col < N) {
#pragma unroll
                for (int q = 0; q < 4; ++q) {
                    float v = acc[i][j][q];
                    if (EPI == 1) v = gelu_exact(v + bias[col]);
                    else if (EPI == 2) v = v + bias[col] + res[(size_t)(row + q) * ldc + col];
                    C[(size_t)(row + q) * ldc + col] = (CT)v;
                }
            }
        }
    }
}

// ---------------- Wo GEMM both branches + LN + cosine fuse -> cat (bf16) ----------------
__global__ __launch_bounds__(256) void gemm_wo_ln_fuse(
    const __hip_bfloat16* __restrict__ A,      // yb [2*8192][192]
    const __hip_bfloat16* __restrict__ BT0, const __hip_bfloat16* __restrict__ BT1,
    const float* __restrict__ g0, const float* __restrict__ b0,
    const float* __restrict__ g1, const float* __restrict__ b1,
    __hip_bfloat16* __restrict__ cat) {        // [8192][192]
    int tid = threadIdx.x;
    int lane = tid & 63, wid = tid >> 6;
    int wm = wid & 1, wn = wid >> 1;
    int m0 = blockIdx.x * 32 + wm * 16;
    int n0 = wn * 48;
    int lr = lane & 15, kh = (lane >> 4) * 8;
    f32x4 acc0[3] = {}, acc1[3] = {};
    const __hip_bfloat16* A0 = A + (size_t)(m0 + lr) * 192 + kh;
    const __hip_bfloat16* A1 = A + (size_t)(MROWS + m0 + lr) * 192 + kh;
    const __hip_bfloat16* Bp0 = BT0 + (size_t)(n0 + lr) * 192 + kh;
    const __hip_bfloat16* Bp1 = BT1 + (size_t)(n0 + lr) * 192 + kh;
#pragma unroll
    for (int k0 = 0; k0 < 192; k0 += 32) {
        bf16x8 af0 = *reinterpret_cast<const bf16x8*>(A0 + k0);
        bf16x8 af1 = *reinterpret_cast<const bf16x8*>(A1 + k0);
#pragma unroll
        for (int j = 0; j < 3; ++j) {
            bf16x8 b0v = *reinterpret_cast<const bf16x8*>(Bp0 + (size_t)j * 16 * 192 + k0);
            bf16x8 b1v = *reinterpret_cast<const bf16x8*>(Bp1 + (size_t)j * 16 * 192 + k0);
            acc0[j] = __builtin_amdgcn_mfma_f32_16x16x32_bf16(af0, b0v, acc0[j], 0, 0, 0);
            acc1[j] = __builtin_amdgcn_mfma_f32_16x16x32_bf16(af1, b1v, acc1[j], 0, 0, 0);
        }
    }
    __shared__ float ct0[32][100], ct1[32][100];
    int cr = (lane >> 4) << 2;
#pragma unroll
    for (int j = 0; j < 3; ++j)
#pragma unroll
        for (int q = 0; q < 4; ++q) {
            ct0[wm * 16 + cr + q][n0 + j * 16 + lr] = acc0[j][q];
            ct1[wm * 16 + cr + q][n0 + j * 16 + lr] = acc1[j][q];
        }
    __syncthreads();
#pragma unroll
    for (int rr = 0; rr < 8; ++rr) {
        int row = wid * 8 + rr;
        float a0 = ct0[row][lane];
        float a1 = (lane < 32) ? ct0[row][64 + lane] : 0.f;
        float c0 = ct1[row][lane];
        float c1 = (lane < 32) ? ct1[row][64 + lane] : 0.f;
        float s0 = a0 + a1, q0 = a0 * a0 + a1 * a1;
        float s1 = c0 + c1, q1 = c0 * c0 + c1 * c1;
#pragma unroll
        for (int o = 32; o >= 1; o >>= 1) {
            s0 += __shfl_xor(s0, o); q0 += __shfl_xor(q0, o);
            s1 += __shfl_xor(s1, o); q1 += __shfl_xor(q1, o);
        }
        float mu0 = s0 * (1.f / 96.f), w0 = rsqrtf(q0 * (1.f / 96.f) - mu0 * mu0 + 1e-5f);
        float mu1 = s1 * (1.f / 96.f), w1 = rsqrtf(q1 * (1.f / 96.f) - mu1 * mu1 + 1e-5f);
        float f1a = (a0 - mu0) * w0 * g0[lane] + b0[lane];
        float f2a = (c0 - mu1) * w1 * g1[lane] + b1[lane];
        float f1b = 0.f, f2b = 0.f;
        if (lane < 32) {
            f1b = (a1 - mu0) * w0 * g0[64 + lane] + b0[64 + lane];
            f2b = (c1 - mu1) * w1 * g1[64 + lane] + b1[64 + lane];
        }
        float s11 = f1a * f1a + f1b * f1b;
        float s22 = f2a * f2a + f2b * f2b;
        float s12 = f1a * f2a + f1b * f2b;
#pragma unroll
        for (int o = 32; o >= 1; o >>= 1) {
            s11 += __shfl_xor(s11, o);
            s22 += __shfl_xor(s22, o);
            s12 += __shfl_xor(s12, o);
        }
        float nr1 = fmaxf(sqrtf(s11), 1e-12f);
        float nr2 = fmaxf(sqrtf(s22), 1e-12f);
        float sim = s12 / (nr1 * nr2);
        size_t grow = (size_t)blockIdx.x * 32 + row;
        __hip_bfloat16* q = cat + grow * 192;
        q[lane] = __float2bfloat16(f1a);
        q[96 + lane] = __float2bfloat16(sim * f1a + (1.f - sim) * f2a);
        if (lane < 32) {
            q[64 + lane] = __float2bfloat16(f1b);
            q[96 + 64 + lane] = __float2bfloat16(sim * f1b + (1.f - sim) * f2b);
        }
    }
}

// ---------------- 3x3 SAME conv, K-split implicit MFMA GEMM (8 waves) ----------------
__global__ __launch_bounds__(512) void conv3x3_direct(const __hip_bfloat16* __restrict__ cat,
                                                      const __hip_bfloat16* __restrict__ WfT,
                                                      const float* __restrict__ bfv,
                                                      __hip_bfloat16* __restrict__ out) {
    __shared__ float part[32][96];
    int tid = threadIdx.x;
    int lane = tid & 63, wid = tid >> 6;
    int wm = wid & 1, wn = (wid >> 1) & 1, wk = wid >> 2;
    int m0 = blockIdx.x * 32 + wm * 16;
    int n0 = wn * 48;
    int lr = lane & 15, kh = (lane >> 4) * 8;
    int m = m0 + lr;
    int bb = m >> 12, l = m & 4095, yy = l >> 6, xx = l & 63;
    f32x4 acc[3] = {};
    const __hip_bfloat16* Bp = WfT + (size_t)(n0 + lr) * 1728 + kh;
#pragma unroll
    for (int tap = 0; tap < 9; ++tap) {
        if ((tap & 1) != wk) continue;   // wave-uniform K split (5 even / 4 odd taps)
        int ky = tap / 3, kx = tap % 3;
        int iy = yy + ky - 1, ix = xx + kx - 1;
        bool ok = ((unsigned)iy < 64u) && ((unsigned)ix < 64u);
        const __hip_bfloat16* Ap = cat + ((size_t)bb * 4096 + (size_t)(iy * 64 + ix)) * 192 + kh;
        int kbase = tap * 192;
#pragma unroll
        for (int kc = 0; kc < 192; kc += 32) {
            bf16x8 af = {};
            if (ok) af = *reinterpret_cast<const bf16x8*>(Ap + kc);
#pragma unroll
            for (int j = 0; j < 3; ++j) {
                bf16x8 bf = *reinterpret_cast<const bf16x8*>(Bp + (size_t)j * 16 * 1728 + kbase + kc);
                acc[j] = __builtin_amdgcn_mfma_f32_16x16x32_bf16(af, bf, acc[j], 0, 0, 0);
            }
        }
    }
    int cr = (lane >> 4) << 2;
    if (wk == 1) {
#pragma unroll
        for (int j = 0; j < 3; ++j)
#pragma unroll
            for (int q = 0; q < 4; ++q)
                part[wm * 16 + cr + q][n0 + j * 16 + lr] = acc[j][q];
    }
    __syncthreads();
    if (wk != 0) return;
    int crow = m0 + cr;
#pragma unroll
    for (int j = 0; j < 3; ++j) {
        int ccol = n0 + j * 16 + lr;
#pragma unroll
        for (int q = 0; q < 4; ++q) {
            float v = acc[j][q] + part[wm * 16 + cr + q][ccol];
            v = gelu_exact(v + bfv[ccol]);
            out[(size_t)(crow + q) * 96 + ccol] = __float2bfloat16(v);
        }
    }
}

// ---------------- scan pass1 (fused conv+sigmoid), 256 thr, 3-chain forward ----------------
__global__ __launch_bounds__(256) void scan_pass1f(
    const __hip_bfloat16* __restrict__ xpw,
    const float* __restrict__ cw0, const float* __restrict__ cw1,
    const float* __restrict__ cb0, const float* __restrict__ cb1,
    const float* __restrict__ A0, const float* __restrict__ A1,
    float* __restrict__ Pc, float* __restrict__ Hf, float* __restrict__ Gb) {
    __shared__ unsigned short rawxu[67][16];
    __shared__ float2 sdx[CHLEN][16];
    __shared__ float sb[CHLEN][16];
    __shared__ float asumv[16];
    int bid = (blockIdx.x & 7) * (SCAN_GRID / 8) + (blockIdx.x >> 3);  // XCD swizzle
    int dg = bid % 12;
    int c = (bid / 12) % NCHUNK;
    int b = (bid / (12 * NCHUNK)) & 1;
    int p = bid / (12 * NCHUNK * 2);
    const float* cw = p ? cw1 : cw0;
    const float* cbp = p ? cb1 : cb0;
    const float* Am = p ? A1 : A0;
    int tid = threadIdx.x;
    if (tid < 16) {
        const float4* Ap4 = (const float4*)(Am + tid * 16);
        float4 a0 = Ap4[0], a1 = Ap4[1], a2 = Ap4[2], a3 = Ap4[3];
        float s = (a0.x + a0.y + a0.z + a0.w) + (a1.x + a1.y + a1.z + a1.w) +
                  (a2.x + a2.y + a2.z + a2.w) + (a3.x + a3.y + a3.z + a3.w);
        asumv[tid] = s * 1.44269504f;
    }
    const unsigned short* xu = (const unsigned short*)xpw;
    int xb = p * 480;
    int t0 = c * CHLEN;
    int r = tid >> 2, q = (tid & 3) * 4;
    size_t grow = (size_t)b * L_SEQ + t0 + r;
    const unsigned short* rowp = xu + grow * XPW2 + xb;
    *(u16x4*)&rawxu[r + 3][q] = *(const u16x4*)(rowp + dg * 16 + q);
    u16x4 dvu = *(const u16x4*)(rowp + 192 + dg * 16 + q);
    u16x4 bvu = *(const u16x4*)(rowp + 384 + q);
    float4 bf4 = {b2f(bvu.x), b2f(bvu.y), b2f(bvu.z), b2f(bvu.w)};
    *(float4*)&sb[r][q] = bf4;
    if (tid < 12) {
        int rr = tid >> 2, qq = (tid & 3) * 4;
        int src = t0 - 3 + rr;
        u16x4 v = {0, 0, 0, 0};
        if (src >= 0)
            v = *(const u16x4*)(xu + ((size_t)b * L_SEQ + src) * XPW2 + xb + dg * 16 + qq);
        *(u16x4*)&rawxu[rr][qq] = v;
    }
    __syncthreads();
    float dd[4] = {b2f(dvu.x), b2f(dvu.y), b2f(dvu.z), b2f(dvu.w)};
#pragma unroll
    for (int i = 0; i < 4; ++i) {
        int d = dg * 16 + q + i;
        float4 w = *(const float4*)(cw + (size_t)d * 4);
        float xc = cbp[d] + w.w * b2f(rawxu[r + 3][q + i]) + w.z * b2f(rawxu[r + 2][q + i]) +
                   w.y * b2f(rawxu[r + 1][q + i]) + w.x * b2f(rawxu[r][q + i]);
        float ds = 1.f / (1.f + __expf(-dd[i]));
        sdx[r][q + i] = make_float2(ds, ds * xc);
    }
    __syncthreads();
    int n = tid & 15, drow = tid >> 4;
    float asum2 = asumv[n];
    float h = 0.f, gb = 0.f, Q = 1.f;
#pragma unroll 4
    for (int t = 0; t < CHLEN; ++t) {
        float2 dx = sdx[t][drow];
        float bm = sb[t][n];
        float a = fast_exp2(dx.x * asum2);
        float bu = dx.y * bm;
        h = a * h + bu;
        gb += Q * bu;
        Q *= a;
    }
    size_t cidx = ((((size_t)p * 2 + b) * NST + n) * DIN + dg * 16 + drow) * NCHUNK + c;
    Pc[cidx] = Q;
    Hf[cidx] = h;
    Gb[cidx] = gb;
}

// ---------------- scan pass2: combine chunk carries (contiguous float4 loads) ----------------
__global__ __launch_bounds__(256) void scan_pass2(const float* __restrict__ Pc,
                                                  const float* __restrict__ Hf,
                                                  const float* __restrict__ Gb,
                                                  float* __restrict__ Hinf,
                                                  float* __restrict__ Hinb) {
    int t = blockIdx.x * 256 + threadIdx.x;
    if (t >= 2 * 2 * NST * DIN) return;
    size_t base = (size_t)t * NCHUNK;
    {
        float4 P4[16], H4[16];
        const float4* Pp = (const float4*)(Pc + base);
        const float4* Hp = (const float4*)(Hf + base);
#pragma unroll
        for (int i = 0; i < 16; ++i) { P4[i] = Pp[i]; H4[i] = Hp[i]; }
        float hin = 0.f;
        float4* Op = (float4*)(Hinf + base);
#pragma unroll
        for (int i = 0; i < 16; ++i) {
            float4 o;
            o.x = hin; hin = H4[i].x + P4[i].x * hin;
            o.y = hin; hin = H4[i].y + P4[i].y * hin;
            o.z = hin; hin = H4[i].z + P4[i].z * hin;
            o.w = hin; hin = H4[i].w + P4[i].w * hin;
            Op[i] = o;
        }
    }
    {
        float4 P4[16], G4[16];
        const float4* Pp = (const float4*)(Pc + base);
        const float4* Gp = (const float4*)(Gb + base);
#pragma unroll
        for (int i = 0; i < 16; ++i) { P4[i] = Pp[i]; G4[i] = Gp[i]; }
        float gin = 0.f;
        float4* Op = (float4*)(Hinb + base);
#pragma unroll
        for (int i = 15; i >= 0; --i) {
            float4 o;
            o.w = gin; gin = G4[i].w + P4[i].w * gin;
            o.z = gin; gin = G4[i].z + P4[i].z * gin;
            o.y = gin; gin = G4[i].y + P4[i].y * gin;
            o.x = gin; gin = G4[i].x + P4[i].x * gin;
            Op[i] = o;
        }
    }
}

// ---------------- scan pass3 (fused conv): direction-split waves (4 fwd + 4 bwd) ----------------
__global__ __launch_bounds__(512) void scan_pass3f(
    const __hip_bfloat16* __restrict__ xpw,
    const float* __restrict__ cw0, const float* __restrict__ cw1,
    const float* __restrict__ cb0, const float* __restrict__ cb1,
    const float* __restrict__ A0, const float* __restrict__ A1,
    const float* __restrict__ Hinf, const float* __restrict__ Hinb,
    const float* __restrict__ Dp0, const float* __restrict__ Dp1,
    __hip_bfloat16* __restrict__ y) {
    __shared__ unsigned short rawxu[67][16];
    __shared__ float2 sdx[CHLEN][16];        // (ds, ds*xc)
    __shared__ float2 sbc[CHLEN][16];        // (Bm, Cm)
    __shared__ unsigned short sxcu[CHLEN][16];  // xc as bf16 (epilogue Dp*xc)
    __shared__ float ysf[CHLEN][16], ysb[CHLEN][16];
    __shared__ float asumv[16];
    int bid = (blockIdx.x & 7) * (SCAN_GRID / 8) + (blockIdx.x >> 3);  // XCD swizzle
    int dg = bid % 12;
    int c = (bid / 12) % NCHUNK;
    int b = (bid / (12 * NCHUNK)) & 1;
    int p = bid / (12 * NCHUNK * 2);
    const float* cw = p ? cw1 : cw0;
    const float* cbp = p ? cb1 : cb0;
    const float* Am = p ? A1 : A0;
    const float* Dp = p ? Dp1 : Dp0;
    int tid = threadIdx.x;
    if (tid < 16) {
        const float4* Ap4 = (const float4*)(Am + tid * 16);
        float4 a0 = Ap4[0], a1 = Ap4[1], a2 = Ap4[2], a3 = Ap4[3];
        float s = (a0.x + a0.y + a0.z + a0.w) + (a1.x + a1.y + a1.z + a1.w) +
                  (a2.x + a2.y + a2.z + a2.w) + (a3.x + a3.y + a3.z + a3.w);
        asumv[tid] = s * 1.44269504f;
    }
    const unsigned short* xu = (const unsigned short*)xpw;
    int xb = p * 480;
    int t0 = c * CHLEN;
    int r = tid >> 2, q = (tid & 3) * 4;
    u16x4 dvu = {0, 0, 0, 0};
    if (tid < 256) {
        size_t grow = (size_t)b * L_SEQ + t0 + r;
        const unsigned short* rowp = xu + grow * XPW2 + xb;
        *(u16x4*)&rawxu[r + 3][q] = *(const u16x4*)(rowp + dg * 16 + q);
        dvu = *(const u16x4*)(rowp + 192 + dg * 16 + q);
        u16x4 bvu = *(const u16x4*)(rowp + 384 + q);
        u16x4 cvu = *(const u16x4*)(rowp + 400 + q);
        sbc[r][q + 0] = make_float2(b2f(bvu.x), b2f(cvu.x));
        sbc[r][q + 1] = make_float2(b2f(bvu.y), b2f(cvu.y));
        sbc[r][q + 2] = make_float2(b2f(bvu.z), b2f(cvu.z));
        sbc[r][q + 3] = make_float2(b2f(bvu.w), b2f(cvu.w));
        if (tid < 12) {
            int rr = tid >> 2, qq = (tid & 3) * 4;
            int src = t0 - 3 + rr;
            u16x4 v = {0, 0, 0, 0};
            if (src >= 0)
                v = *(const u16x4*)(xu + ((size_t)b * L_SEQ + src) * XPW2 + xb + dg * 16 + qq);
            *(u16x4*)&rawxu[rr][qq] = v;
        }
    }
    __syncthreads();
    if (tid < 256) {
        float dd[4] = {b2f(dvu.x), b2f(dvu.y), b2f(dvu.z), b2f(dvu.w)};
#pragma unroll
        for (int i = 0; i < 4; ++i) {
            int d = dg * 16 + q + i;
            float4 w = *(const float4*)(cw + (size_t)d * 4);
            float xc = cbp[d] + w.w * b2f(rawxu[r + 3][q + i]) + w.z * b2f(rawxu[r + 2][q + i]) +
                       w.y * b2f(rawxu[r + 1][q + i]) + w.x * b2f(rawxu[r][q + i]);
            float ds = 1.f / (1.f + __expf(-dd[i]));
            sdx[r][q + i] = make_float2(ds, ds * xc);
            sxcu[r][q + i] = f2bf_bits(xc);
        }
    }
    __syncthreads();
    int lane = tid & 63, wave = tid >> 6;   // 8 waves
    int dir = wave >> 2;                    // 0 = fwd (waves 0-3), 1 = bwd (waves 4-7)
    int wl = wave & 3;
    int n = lane & 15;
    int dloc = wl * 4 + (lane >> 4);
    int d = dg * 16 + dloc;
    float asum2 = asumv[n];
    size_t cidx = ((((size_t)p * 2 + b) * NST + n) * DIN + d) * NCHUNK + c;
    if (dir == 0) {
        float h = Hinf[cidx];
#pragma unroll 4
        for (int t = 0; t < CHLEN; ++t) {
            float2 dx = sdx[t][dloc];
            float2 bc = sbc[t][n];
            float a = fast_exp2(dx.x * asum2);
            h = a * h + dx.y * bc.x;
            float pf = rowsum16(bc.y * h);
            if (n == 0) ysf[t][dloc] = pf;
        }
    } else {
        float gv = Hinb[cidx];
#pragma unroll 4
        for (int t = CHLEN - 1; t >= 0; --t) {
            float2 dx = sdx[t][dloc];
            float2 bc = sbc[t][n];
            float a = fast_exp2(dx.x * asum2);
            gv = a * gv + dx.y * bc.x;
            float pb = rowsum16(bc.y * gv);
            if (n == 0) ysb[t][dloc] = pb;
        }
    }
    __syncthreads();
    if (tid < 256) {
        int tl = tid >> 2, qq = (tid & 3) * 4;
        int d2 = dg * 16 + qq;
        float4 Dv = *(const float4*)(Dp + d2);
        float vs[4];
#pragma unroll
        for (int i = 0; i < 4; ++i)
            vs[i] = ysf[tl][qq + i] + ysb[tl][qq + i] +
                    ((const float*)&Dv)[i] * b2f(sxcu[tl][qq + i]);
        s16x4 pk = {(short)f2bf_bits(vs[0]), (short)f2bf_bits(vs[1]),
                    (short)f2bf_bits(vs[2]), (short)f2bf_bits(vs[3])};
        size_t row = (size_t)b * L_SEQ + t0 + tl;
        *(s16x4*)((unsigned short*)y + ((size_t)p * MROWS + row) * DIN + d2) = pk;
    }
}

extern "C" void kernel_launch(void* const* d_in, const int* in_sizes, int n_in,
                              void* d_out, int out_size, void* d_ws, size_t ws_size,
                              hipStream_t stream) {
    const float* x = (const float*)d_in[0];
    const float* norm_g = (const float*)d_in[1];
    const float* norm_b = (const float*)d_in[2];
    const float* Wp[2] = {(const float*)d_in[3], (const float*)d_in[11]};
    const float* cw[2] = {(const float*)d_in[4], (const float*)d_in[12]};
    const float* cb[2] = {(const float*)d_in[5], (const float*)d_in[13]};
    const float* Ab[2] = {(const float*)d_in[6], (const float*)d_in[14]};
    const float* Dpb[2] = {(const float*)d_in[7], (const float*)d_in[15]};
    const float* Wo[2] = {(const float*)d_in[8], (const float*)d_in[16]};
    const float* lng[2] = {(const float*)d_in[9], (const float*)d_in[17]};
    const float* lnb[2] = {(const float*)d_in[10], (const float*)d_in[18]};
    const float* Wf = (const float*)d_in[19];
    const float* bfv = (const float*)d_in[20];
    const float* W1 = (const float*)d_in[21];
    const float* b1 = (const float*)d_in[22];
    const float* W2 = (const float*)d_in[23];
    const float* b2 = (const float*)d_in[24];
    float* out = (float*)d_out;

    char* base = (char*)d_ws;
    size_t off = 0;
    auto alloc = [&](size_t bytes) { void* p = base + off; off += (bytes + 255) & ~(size_t)255; return p; };
    __hip_bfloat16* xpw = (__hip_bfloat16*)alloc((size_t)MROWS * XPW2 * 2);
    const size_t csz = (size_t)2 * 2 * NST * DIN * NCHUNK;
    float* Pc = (float*)alloc(csz * 4);
    float* Hfc = (float*)alloc(csz * 4);
    float* Gbc = (float*)alloc(csz * 4);
    float* Hinf = (float*)alloc(csz * 4);
    float* Hinb = (float*)alloc(csz * 4);
    __hip_bfloat16* xn_bf = (__hip_bfloat16*)alloc((size_t)MROWS * 96 * 2);
    __hip_bfloat16* yb_bf = (__hip_bfloat16*)alloc((size_t)2 * MROWS * DIN * 2);
    __hip_bfloat16* cat_bf = (__hip_bfloat16*)alloc((size_t)MROWS * DIN * 2);
    __hip_bfloat16* fc_bf = (__hip_bfloat16*)alloc((size_t)MROWS * 96 * 2);
    __hip_bfloat16* h1_bf = (__hip_bfloat16*)alloc((size_t)MROWS * 384 * 2);
    __hip_bfloat16* wpT = (__hip_bfloat16*)alloc((size_t)XPW2 * 96 * 2);
    __hip_bfloat16* woT[2] = {(__hip_bfloat16*)alloc(96 * 192 * 2),
                              (__hip_bfloat16*)alloc(96 * 192 * 2)};
    __hip_bfloat16* wfT = (__hip_bfloat16*)alloc(96 * 1728 * 2);
    __hip_bfloat16* w1T = (__hip_bfloat16*)alloc(384 * 96 * 2);
    __hip_bfloat16* w2T = (__hip_bfloat16*)alloc(96 * 384 * 2);
    (void)ws_size; (void)in_sizes; (void)n_in; (void)out_size;

    // 1. weights convert/transpose + input LN (one launch)
    prep_kernel<<<dim3(CVT_BLOCKS + 2048), dim3(256), 0, stream>>>(
        Wp[0], Wp[1], Wo[0], Wo[1], Wf, W1, W2,
        wpT, woT[0], woT[1], wfT, w1T, w2T, x, norm_g, norm_b, xn_bf);
    // 2. xp(both branches, bf16) = xn @ [Wp1|Wp2]
    gemm_direct<2, 3, 2, 2, 96, 1, 0, __hip_bfloat16><<<dim3(10, 128), dim3(256), 0, stream>>>(
        xn_bf, 96, wpT, xpw, XPW2, XPW2, nullptr, nullptr);
    // 3-5. bidirectional selective scan, both branches
    scan_pass1f<<<dim3(SCAN_GRID), dim3(256), 0, stream>>>(
        xpw, cw[0], cw[1], cb[0], cb[1], Ab[0], Ab[1], Pc, Hfc, Gbc);
    scan_pass2<<<dim3(48), dim3(256), 0, stream>>>(Pc, Hfc, Gbc, Hinf, Hinb);
    scan_pass3f<<<dim3(SCAN_GRID), dim3(512), 0, stream>>>(
        xpw, cw[0], cw[1], cb[0], cb[1], Ab[0], Ab[1], Hinf, Hinb, Dpb[0], Dpb[1], yb_bf);
    // 6. f1/f2 = LN(y@Wo), cosine fuse -> cat
    gemm_wo_ln_fuse<<<dim3(256), dim3(256), 0, stream>>>(
        yb_bf, woT[0], woT[1], lng[0], lnb[0], lng[1], lnb[1], cat_bf);
    // 7. fc = gelu(conv3x3(cat) + bf)  (K-split, 8 waves)
    conv3x3_direct<<<dim3(256), dim3(512), 0, stream>>>(cat_bf, wfT, bfv, fc_bf);
    // 8. h1 = gelu(fc @ W1 + b1)
    gemm_direct<2, 3, 2, 2, 96, 1, 1, __hip_bfloat16><<<dim3(4, 128), dim3(256), 0, stream>>>(
        fc_bf, 96, w1T, h1_bf, 384, 384, b1, nullptr);
    // 9. out = h1 @ W2 + b2 + res  (K-split, 8 waves)
    gemm_direct<1, 3, 2, 2, 384, 2, 2, float><<<dim3(1, 256), dim3(512), 0, stream>>>(
        h1_bf, 384, w2T, out, 96, 96, b2, x);
}

// Round 14
// 149.301 us; speedup vs baseline: 1.0552x; 1.0243x over previous
//
#include <hip/hip_runtime.h>
#include <hip/hip_bf16.h>
#include <math.h>

#define L_SEQ 4096
#define CDIM 96
#define DIN 192
#define NST 16
#define NCHUNK 64
#define CHLEN 64
#define MROWS 8192
#define XPW2 960   // combined xp width: 2 branches x 480 (416 used + pad)
#define SCAN_GRID 3072

typedef __attribute__((ext_vector_type(8))) short bf16x8;
typedef __attribute__((ext_vector_type(4))) float f32x4;
typedef __attribute__((ext_vector_type(4))) short s16x4;
typedef __attribute__((ext_vector_type(4))) unsigned short u16x4;

__device__ __forceinline__ float gelu_exact(float x) {
    return 0.5f * x * (1.0f + erff(x * 0.70710678118654752f));
}

__device__ __forceinline__ float fast_exp2(float x) {
#if __has_builtin(__builtin_amdgcn_exp2f)
    return __builtin_amdgcn_exp2f(x);
#else
    return exp2f(x);
#endif
}

__device__ __forceinline__ float b2f(unsigned short u) {
    return __uint_as_float((unsigned int)u << 16);
}

// 16-lane DPP row reduction via explicit v_add_f32_dpp; leaves the row sum in all 16 lanes.
__device__ __forceinline__ float rowsum16(float s) {
    asm("v_add_f32_dpp %0, %0, %0 row_ror:8 row_mask:0xf bank_mask:0xf" : "+v"(s));
    asm("v_add_f32_dpp %0, %0, %0 row_ror:4 row_mask:0xf bank_mask:0xf" : "+v"(s));
    asm("v_add_f32_dpp %0, %0, %0 row_ror:2 row_mask:0xf bank_mask:0xf" : "+v"(s));
    asm("v_add_f32_dpp %0, %0, %0 row_ror:1 row_mask:0xf bank_mask:0xf" : "+v"(s));
    return s;
}

__device__ __forceinline__ unsigned short f2bf_bits(float f) {
    __hip_bfloat16 h = __float2bfloat16(f);
    return *reinterpret_cast<unsigned short*>(&h);
}

// ---------------- prep: tiled weight transposes (coalesced) + input LayerNorm ----------------
#define TP_BLOCKS 360
__global__ __launch_bounds__(256) void prep_kernel(
    const float* __restrict__ Wp0, const float* __restrict__ Wp1,
    const float* __restrict__ Wo0, const float* __restrict__ Wo1,
    const float* __restrict__ Wf, const float* __restrict__ W1, const float* __restrict__ W2,
    __hip_bfloat16* __restrict__ wpT, __hip_bfloat16* __restrict__ wo0T,
    __hip_bfloat16* __restrict__ wo1T, __hip_bfloat16* __restrict__ wfT,
    __hip_bfloat16* __restrict__ w1T, __hip_bfloat16* __restrict__ w2T,
    const float* __restrict__ x, const float* __restrict__ g, const float* __restrict__ b,
    __hip_bfloat16* __restrict__ xn) {
    int tid = threadIdx.x;
    if (blockIdx.x < TP_BLOCKS) {
        // 32x32 LDS tile transpose: D[c][r] = (c < Cv) ? S[r][c] : 0   (D dims [Cd][Rs])
        int t = blockIdx.x;
        const float* S;
        __hip_bfloat16* D;
        int ldS, Cv, Rs;
        if (t < 45) { S = Wp0; D = wpT; ldS = 576; Cv = 416; Rs = 96; }
        else if (t < 90) { t -= 45; S = Wp1; D = wpT + 480 * 96; ldS = 576; Cv = 416; Rs = 96; }
        else if (t < 108) { t -= 90; S = Wo0; D = wo0T; ldS = 96; Cv = 96; Rs = 192; }
        else if (t < 126) { t -= 108; S = Wo1; D = wo1T; ldS = 96; Cv = 96; Rs = 192; }
        else if (t < 288) { t -= 126; S = Wf; D = wfT; ldS = 96; Cv = 96; Rs = 1728; }
        else if (t < 324) { t -= 288; S = W1; D = w1T; ldS = 384; Cv = 384; Rs = 96; }
        else { t -= 324; S = W2; D = w2T; ldS = 96; Cv = 96; Rs = 384; }
        int tilesJ = Rs >> 5;
        int ti = t / tilesJ, tj = t - ti * tilesJ;
        int c0 = ti * 32, r0 = tj * 32;
        __shared__ __hip_bfloat16 lt[32][33];
        int cl = tid & 31, rl = tid >> 5;
#pragma unroll
        for (int e = 0; e < 4; ++e) {
            int row = r0 + rl + e * 8;
            int col = c0 + cl;
            float v = (col < Cv) ? S[(size_t)row * ldS + col] : 0.f;
            lt[cl][rl + e * 8] = __float2bfloat16(v);
        }
        __syncthreads();
#pragma unroll
        for (int e = 0; e < 4; ++e) {
            int drow = c0 + rl + e * 8;
            int dcol = r0 + cl;
            D[(size_t)drow * Rs + dcol] = lt[rl + e * 8][cl];
        }
        return;
    }
    // ---- input LayerNorm ----
    int wave = tid >> 6;
    int lane = tid & 63;
    int row = (blockIdx.x - TP_BLOCKS) * 4 + wave;
    if (row >= MROWS) return;
    const float* p = x + (size_t)row * CDIM;
    float x0 = p[lane];
    float x1 = (lane < 32) ? p[64 + lane] : 0.f;
    float s = x0 + x1, sq = x0 * x0 + x1 * x1;
#pragma unroll
    for (int o = 32; o >= 1; o >>= 1) { s += __shfl_xor(s, o); sq += __shfl_xor(sq, o); }
    float mean = s * (1.f / 96.f);
    float var = sq * (1.f / 96.f) - mean * mean;
    float w = rsqrtf(var + 1e-5f);
    __hip_bfloat16* q = xn + (size_t)row * CDIM;
    q[lane] = __float2bfloat16((x0 - mean) * w * g[lane] + b[lane]);
    if (lane < 32) q[64 + lane] = __float2bfloat16((x1 - mean) * w * g[64 + lane] + b[64 + lane]);
}

// ---------------- LDS-free direct-fragment MFMA GEMM (optional 2-way K-split) ----------------
template <int MI, int NI, int WR, int WC, int K, int KS, int EPI, typename CT>
__global__ __launch_bounds__(WR * WC * KS * 64) void gemm_direct(
    const __hip_bfloat16* __restrict__ A, int lda,
    const __hip_bfloat16* __restrict__ BT,
    CT* __restrict__ C, int ldc, int N,
    const float* __restrict__ bias, const float* __restrict__ res) {
    __shared__ float part[KS > 1 ? (WR * MI * 16) * (WC * NI * 16) : 1];
    int tid = threadIdx.x;
    int lane = tid & 63, wid = tid >> 6;
    int wk = wid / (WR * WC);
    int wrem = wid % (WR * WC);
    int wm = wrem % WR, wn = wrem / WR;
    int m0 = blockIdx.y * (WR * MI * 16) + wm * MI * 16;
    int n0 = blockIdx.x * (WC * NI * 16) + wn * NI * 16;
    int lr = lane & 15, kh = (lane >> 4) * 8;
    constexpr int KC = K / KS;
    f32x4 acc[MI][NI] = {};
    const __hip_bfloat16* Ap = A + (size_t)(m0 + lr) * lda + kh + wk * KC;
    const __hip_bfloat16* Bp = BT + (size_t)(n0 + lr) * K + kh + wk * KC;
#pragma unroll
    for (int k0 = 0; k0 < KC; k0 += 32) {
        bf16x8 af[MI], bf[NI];
#pragma unroll
        for (int i = 0; i < MI; ++i)
            af[i] = *reinterpret_cast<const bf16x8*>(Ap + (size_t)i * 16 * lda + k0);
#pragma unroll
        for (int j = 0; j < NI; ++j)
            bf[j] = *reinterpret_cast<const bf16x8*>(Bp + (size_t)j * 16 * K + k0);
#pragma unroll
        for (int i = 0; i < MI; ++i)
#pragma unroll
            for (int j = 0; j < NI; ++j)
                acc[i][j] = __builtin_amdgcn_mfma_f32_16x16x32_bf16(af[i], bf[j], acc[i][j], 0, 0, 0);
    }
    int cr = (lane >> 4) << 2;
    if (KS > 1) {
        constexpr int BN = WC * NI * 16;
        if (wk == 1) {
#pragma unroll
            for (int i = 0; i < MI; ++i)
#pragma unroll
                for (int j = 0; j < NI; ++j)
#pragma unroll
                    for (int q = 0; q < 4; ++q)
                        part[(wm * MI * 16 + i * 16 + cr + q) * BN + wn * NI * 16 + j * 16 + lr] =
                            acc[i][j][q];
        }
        __syncthreads();
        if (wk != 0) return;
#pragma unroll
        for (int i = 0; i < MI; ++i)
#pragma unroll
            for (int j = 0; j < NI; ++j)
#pragma unroll
                for (int q = 0; q < 4; ++q)
                    acc[i][j][q] +=
                        part[(wm * MI * 16 + i * 16 + cr + q) * BN + wn * NI * 16 + j * 16 + lr];
    }
#pragma unroll
    for (int i = 0; i < MI; ++i) {
        int row = m0 + i * 16 + cr;
#pragma unroll
        for (int j = 0; j < NI; ++j) {
            int col = n0 + j * 16 + lr;
            if (col < N) {
#pragma unroll
                for (int q = 0; q < 4; ++q) {
                    float v = acc[i][j][q];
                    if (EPI == 1) v = gelu_exact(v + bias[col]);
                    else if (EPI == 2) v = v + bias[col] + res[(size_t)(row + q) * ldc + col];
                    C[(size_t)(row + q) * ldc + col] = (CT)v;
                }
            }
        }
    }
}

// ---------------- Wo GEMM both branches + LN + cosine fuse -> cat (16-row tiles) ----------------
__global__ __launch_bounds__(256) void gemm_wo_ln_fuse(
    const __hip_bfloat16* __restrict__ A,      // yb [2*8192][192]
    const __hip_bfloat16* __restrict__ BT0, const __hip_bfloat16* __restrict__ BT1,
    const float* __restrict__ g0, const float* __restrict__ b0,
    const float* __restrict__ g1, const float* __restrict__ b1,
    __hip_bfloat16* __restrict__ cat) {        // [8192][192]
    int tid = threadIdx.x;
    int lane = tid & 63, wid = tid >> 6;       // 4 waves: wn x branch
    int wn = wid & 1, wb = wid >> 1;
    int m0 = blockIdx.x * 16;
    int n0 = wn * 48;
    int lr = lane & 15, kh = (lane >> 4) * 8;
    f32x4 acc[3] = {};
    const __hip_bfloat16* Ap = A + (size_t)((wb ? MROWS : 0) + m0 + lr) * 192 + kh;
    const __hip_bfloat16* BT = wb ? BT1 : BT0;
    const __hip_bfloat16* Bp = BT + (size_t)(n0 + lr) * 192 + kh;
#pragma unroll
    for (int k0 = 0; k0 < 192; k0 += 32) {
        bf16x8 af = *reinterpret_cast<const bf16x8*>(Ap + k0);
#pragma unroll
        for (int j = 0; j < 3; ++j) {
            bf16x8 bv = *reinterpret_cast<const bf16x8*>(Bp + (size_t)j * 16 * 192 + k0);
            acc[j] = __builtin_amdgcn_mfma_f32_16x16x32_bf16(af, bv, acc[j], 0, 0, 0);
        }
    }
    __shared__ float ct[2][16][100];
    int cr = (lane >> 4) << 2;
#pragma unroll
    for (int j = 0; j < 3; ++j)
#pragma unroll
        for (int q = 0; q < 4; ++q)
            ct[wb][cr + q][n0 + j * 16 + lr] = acc[j][q];
    __syncthreads();
#pragma unroll
    for (int rr = 0; rr < 4; ++rr) {
        int row = wid * 4 + rr;
        float a0 = ct[0][row][lane];
        float a1 = (lane < 32) ? ct[0][row][64 + lane] : 0.f;
        float c0 = ct[1][row][lane];
        float c1 = (lane < 32) ? ct[1][row][64 + lane] : 0.f;
        float s0 = a0 + a1, q0 = a0 * a0 + a1 * a1;
        float s1 = c0 + c1, q1 = c0 * c0 + c1 * c1;
#pragma unroll
        for (int o = 32; o >= 1; o >>= 1) {
            s0 += __shfl_xor(s0, o); q0 += __shfl_xor(q0, o);
            s1 += __shfl_xor(s1, o); q1 += __shfl_xor(q1, o);
        }
        float mu0 = s0 * (1.f / 96.f), w0 = rsqrtf(q0 * (1.f / 96.f) - mu0 * mu0 + 1e-5f);
        float mu1 = s1 * (1.f / 96.f), w1 = rsqrtf(q1 * (1.f / 96.f) - mu1 * mu1 + 1e-5f);
        float f1a = (a0 - mu0) * w0 * g0[lane] + b0[lane];
        float f2a = (c0 - mu1) * w1 * g1[lane] + b1[lane];
        float f1b = 0.f, f2b = 0.f;
        if (lane < 32) {
            f1b = (a1 - mu0) * w0 * g0[64 + lane] + b0[64 + lane];
            f2b = (c1 - mu1) * w1 * g1[64 + lane] + b1[64 + lane];
        }
        float s11 = f1a * f1a + f1b * f1b;
        float s22 = f2a * f2a + f2b * f2b;
        float s12 = f1a * f2a + f1b * f2b;
#pragma unroll
        for (int o = 32; o >= 1; o >>= 1) {
            s11 += __shfl_xor(s11, o);
            s22 += __shfl_xor(s22, o);
            s12 += __shfl_xor(s12, o);
        }
        float nr1 = fmaxf(sqrtf(s11), 1e-12f);
        float nr2 = fmaxf(sqrtf(s22), 1e-12f);
        float sim = s12 / (nr1 * nr2);
        size_t grow = (size_t)blockIdx.x * 16 + row;
        __hip_bfloat16* q = cat + grow * 192;
        q[lane] = __float2bfloat16(f1a);
        q[96 + lane] = __float2bfloat16(sim * f1a + (1.f - sim) * f2a);
        if (lane < 32) {
            q[64 + lane] = __float2bfloat16(f1b);
            q[96 + 64 + lane] = __float2bfloat16(sim * f1b + (1.f - sim) * f2b);
        }
    }
}

// ---------------- 3x3 SAME conv: 16-row tiles, balanced 4-way K-split (8 waves) ----------------
__global__ __launch_bounds__(512) void conv3x3_direct(const __hip_bfloat16* __restrict__ cat,
                                                      const __hip_bfloat16* __restrict__ WfT,
                                                      const float* __restrict__ bfv,
                                                      __hip_bfloat16* __restrict__ out) {
    __shared__ float part[3][16][100];
    int tid = threadIdx.x;
    int lane = tid & 63, wid = tid >> 6;   // 8 waves: wn(2) x wk(4)
    int wn = wid & 1, wk = wid >> 1;
    int m0 = blockIdx.x * 16;
    int n0 = wn * 48;
    int lr = lane & 15, kh = (lane >> 4) * 8;
    int m = m0 + lr;
    int bb = m >> 12, l = m & 4095, yy = l >> 6, xx = l & 63;
    f32x4 acc[3] = {};
    const __hip_bfloat16* Bp = WfT + (size_t)(n0 + lr) * 1728 + kh;
    // 54 (tap, k-chunk) pairs split 14/14/13/13 across wk
    for (int u = wk; u < 54; u += 4) {
        int tap = u / 6;
        int kc = (u - tap * 6) * 32;
        int ky = tap / 3, kx = tap - ky * 3;
        int iy = yy + ky - 1, ix = xx + kx - 1;
        bool ok = ((unsigned)iy < 64u) && ((unsigned)ix < 64u);
        bf16x8 af = {};
        if (ok)
            af = *reinterpret_cast<const bf16x8*>(
                cat + ((size_t)bb * 4096 + (size_t)(iy * 64 + ix)) * 192 + kh + kc);
        int kbase = tap * 192 + kc;
#pragma unroll
        for (int j = 0; j < 3; ++j) {
            bf16x8 bfr = *reinterpret_cast<const bf16x8*>(Bp + (size_t)j * 16 * 1728 + kbase);
            acc[j] = __builtin_amdgcn_mfma_f32_16x16x32_bf16(af, bfr, acc[j], 0, 0, 0);
        }
    }
    int cr = (lane >> 4) << 2;
    if (wk != 0) {
#pragma unroll
        for (int j = 0; j < 3; ++j)
#pragma unroll
            for (int q = 0; q < 4; ++q)
                part[wk - 1][cr + q][n0 + j * 16 + lr] = acc[j][q];
    }
    __syncthreads();
    if (wk != 0) return;
#pragma unroll
    for (int j = 0; j < 3; ++j) {
        int ccol = n0 + j * 16 + lr;
#pragma unroll
        for (int q = 0; q < 4; ++q) {
            float v = acc[j][q] + part[0][cr + q][ccol] + part[1][cr + q][ccol] +
                      part[2][cr + q][ccol];
            v = gelu_exact(v + bfv[ccol]);
            out[(size_t)(m0 + cr + q) * 96 + ccol] = __float2bfloat16(v);
        }
    }
}

// ---------------- scan pass1 (fused conv+sigmoid), 256 thr, 3-chain forward ----------------
__global__ __launch_bounds__(256) void scan_pass1f(
    const __hip_bfloat16* __restrict__ xpw,
    const float* __restrict__ cw0, const float* __restrict__ cw1,
    const float* __restrict__ cb0, const float* __restrict__ cb1,
    const float* __restrict__ A0, const float* __restrict__ A1,
    float* __restrict__ Pc, float* __restrict__ Hf, float* __restrict__ Gb) {
    __shared__ unsigned short rawxu[67][16];
    __shared__ float2 sdx[CHLEN][16];
    __shared__ float sb[CHLEN][16];
    __shared__ float asumv[16];
    int bid = (blockIdx.x & 7) * (SCAN_GRID / 8) + (blockIdx.x >> 3);  // XCD swizzle
    int dg = bid % 12;
    int c = (bid / 12) % NCHUNK;
    int b = (bid / (12 * NCHUNK)) & 1;
    int p = bid / (12 * NCHUNK * 2);
    const float* cw = p ? cw1 : cw0;
    const float* cbp = p ? cb1 : cb0;
    const float* Am = p ? A1 : A0;
    int tid = threadIdx.x;
    if (tid < 16) {
        const float4* Ap4 = (const float4*)(Am + tid * 16);
        float4 a0 = Ap4[0], a1 = Ap4[1], a2 = Ap4[2], a3 = Ap4[3];
        float s = (a0.x + a0.y + a0.z + a0.w) + (a1.x + a1.y + a1.z + a1.w) +
                  (a2.x + a2.y + a2.z + a2.w) + (a3.x + a3.y + a3.z + a3.w);
        asumv[tid] = s * 1.44269504f;
    }
    const unsigned short* xu = (const unsigned short*)xpw;
    int xb = p * 480;
    int t0 = c * CHLEN;
    int r = tid >> 2, q = (tid & 3) * 4;
    size_t grow = (size_t)b * L_SEQ + t0 + r;
    const unsigned short* rowp = xu + grow * XPW2 + xb;
    *(u16x4*)&rawxu[r + 3][q] = *(const u16x4*)(rowp + dg * 16 + q);
    u16x4 dvu = *(const u16x4*)(rowp + 192 + dg * 16 + q);
    u16x4 bvu = *(const u16x4*)(rowp + 384 + q);
    float4 bf4 = {b2f(bvu.x), b2f(bvu.y), b2f(bvu.z), b2f(bvu.w)};
    *(float4*)&sb[r][q] = bf4;
    if (tid < 12) {
        int rr = tid >> 2, qq = (tid & 3) * 4;
        int src = t0 - 3 + rr;
        u16x4 v = {0, 0, 0, 0};
        if (src >= 0)
            v = *(const u16x4*)(xu + ((size_t)b * L_SEQ + src) * XPW2 + xb + dg * 16 + qq);
        *(u16x4*)&rawxu[rr][qq] = v;
    }
    __syncthreads();
    float dd[4] = {b2f(dvu.x), b2f(dvu.y), b2f(dvu.z), b2f(dvu.w)};
#pragma unroll
    for (int i = 0; i < 4; ++i) {
        int d = dg * 16 + q + i;
        float4 w = *(const float4*)(cw + (size_t)d * 4);
        float xc = cbp[d] + w.w * b2f(rawxu[r + 3][q + i]) + w.z * b2f(rawxu[r + 2][q + i]) +
                   w.y * b2f(rawxu[r + 1][q + i]) + w.x * b2f(rawxu[r][q + i]);
        float ds = 1.f / (1.f + __expf(-dd[i]));
        sdx[r][q + i] = make_float2(ds, ds * xc);
    }
    __syncthreads();
    int n = tid & 15, drow = tid >> 4;
    float asum2 = asumv[n];
    float h = 0.f, gb = 0.f, Q = 1.f;
#pragma unroll 4
    for (int t = 0; t < CHLEN; ++t) {
        float2 dx = sdx[t][drow];
        float bm = sb[t][n];
        float a = fast_exp2(dx.x * asum2);
        float bu = dx.y * bm;
        h = a * h + bu;
        gb += Q * bu;
        Q *= a;
    }
    size_t cidx = ((((size_t)p * 2 + b) * NST + n) * DIN + dg * 16 + drow) * NCHUNK + c;
    Pc[cidx] = Q;
    Hf[cidx] = h;
    Gb[cidx] = gb;
}

// ---------------- scan pass2: combine chunk carries (contiguous float4 loads) ----------------
__global__ __launch_bounds__(256) void scan_pass2(const float* __restrict__ Pc,
                                                  const float* __restrict__ Hf,
                                                  const float* __restrict__ Gb,
                                                  float* __restrict__ Hinf,
                                                  float* __restrict__ Hinb) {
    int t = blockIdx.x * 256 + threadIdx.x;
    if (t >= 2 * 2 * NST * DIN) return;
    size_t base = (size_t)t * NCHUNK;
    {
        float4 P4[16], H4[16];
        const float4* Pp = (const float4*)(Pc + base);
        const float4* Hp = (const float4*)(Hf + base);
#pragma unroll
        for (int i = 0; i < 16; ++i) { P4[i] = Pp[i]; H4[i] = Hp[i]; }
        float hin = 0.f;
        float4* Op = (float4*)(Hinf + base);
#pragma unroll
        for (int i = 0; i < 16; ++i) {
            float4 o;
            o.x = hin; hin = H4[i].x + P4[i].x * hin;
            o.y = hin; hin = H4[i].y + P4[i].y * hin;
            o.z = hin; hin = H4[i].z + P4[i].z * hin;
            o.w = hin; hin = H4[i].w + P4[i].w * hin;
            Op[i] = o;
        }
    }
    {
        float4 P4[16], G4[16];
        const float4* Pp = (const float4*)(Pc + base);
        const float4* Gp = (const float4*)(Gb + base);
#pragma unroll
        for (int i = 0; i < 16; ++i) { P4[i] = Pp[i]; G4[i] = Gp[i]; }
        float gin = 0.f;
        float4* Op = (float4*)(Hinb + base);
#pragma unroll
        for (int i = 15; i >= 0; --i) {
            float4 o;
            o.w = gin; gin = G4[i].w + P4[i].w * gin;
            o.z = gin; gin = G4[i].z + P4[i].z * gin;
            o.y = gin; gin = G4[i].y + P4[i].y * gin;
            o.x = gin; gin = G4[i].x + P4[i].x * gin;
            Op[i] = o;
        }
    }
}

// ---------------- scan pass3 (fused conv): direction-split waves (4 fwd + 4 bwd) ----------------
__global__ __launch_bounds__(512) void scan_pass3f(
    const __hip_bfloat16* __restrict__ xpw,
    const float* __restrict__ cw0, const float* __restrict__ cw1,
    const float* __restrict__ cb0, const float* __restrict__ cb1,
    const float* __restrict__ A0, const float* __restrict__ A1,
    const float* __restrict__ Hinf, const float* __restrict__ Hinb,
    const float* __restrict__ Dp0, const float* __restrict__ Dp1,
    __hip_bfloat16* __restrict__ y) {
    __shared__ unsigned short rawxu[67][16];
    __shared__ float2 sdx[CHLEN][16];        // (ds, ds*xc)
    __shared__ float2 sbc[CHLEN][16];        // (Bm, Cm)
    __shared__ unsigned short sxcu[CHLEN][16];  // xc as bf16 (epilogue Dp*xc)
    __shared__ float ysf[CHLEN][16], ysb[CHLEN][16];
    __shared__ float asumv[16];
    int bid = (blockIdx.x & 7) * (SCAN_GRID / 8) + (blockIdx.x >> 3);  // XCD swizzle
    int dg = bid % 12;
    int c = (bid / 12) % NCHUNK;
    int b = (bid / (12 * NCHUNK)) & 1;
    int p = bid / (12 * NCHUNK * 2);
    const float* cw = p ? cw1 : cw0;
    const float* cbp = p ? cb1 : cb0;
    const float* Am = p ? A1 : A0;
    const float* Dp = p ? Dp1 : Dp0;
    int tid = threadIdx.x;
    if (tid < 16) {
        const float4* Ap4 = (const float4*)(Am + tid * 16);
        float4 a0 = Ap4[0], a1 = Ap4[1], a2 = Ap4[2], a3 = Ap4[3];
        float s = (a0.x + a0.y + a0.z + a0.w) + (a1.x + a1.y + a1.z + a1.w) +
                  (a2.x + a2.y + a2.z + a2.w) + (a3.x + a3.y + a3.z + a3.w);
        asumv[tid] = s * 1.44269504f;
    }
    const unsigned short* xu = (const unsigned short*)xpw;
    int xb = p * 480;
    int t0 = c * CHLEN;
    int r = tid >> 2, q = (tid & 3) * 4;
    u16x4 dvu = {0, 0, 0, 0};
    if (tid < 256) {
        size_t grow = (size_t)b * L_SEQ + t0 + r;
        const unsigned short* rowp = xu + grow * XPW2 + xb;
        *(u16x4*)&rawxu[r + 3][q] = *(const u16x4*)(rowp + dg * 16 + q);
        dvu = *(const u16x4*)(rowp + 192 + dg * 16 + q);
        u16x4 bvu = *(const u16x4*)(rowp + 384 + q);
        u16x4 cvu = *(const u16x4*)(rowp + 400 + q);
        sbc[r][q + 0] = make_float2(b2f(bvu.x), b2f(cvu.x));
        sbc[r][q + 1] = make_float2(b2f(bvu.y), b2f(cvu.y));
        sbc[r][q + 2] = make_float2(b2f(bvu.z), b2f(cvu.z));
        sbc[r][q + 3] = make_float2(b2f(bvu.w), b2f(cvu.w));
        if (tid < 12) {
            int rr = tid >> 2, qq = (tid & 3) * 4;
            int src = t0 - 3 + rr;
            u16x4 v = {0, 0, 0, 0};
            if (src >= 0)
                v = *(const u16x4*)(xu + ((size_t)b * L_SEQ + src) * XPW2 + xb + dg * 16 + qq);
            *(u16x4*)&rawxu[rr][qq] = v;
        }
    }
    __syncthreads();
    if (tid < 256) {
        float dd[4] = {b2f(dvu.x), b2f(dvu.y), b2f(dvu.z), b2f(dvu.w)};
#pragma unroll
        for (int i = 0; i < 4; ++i) {
            int d = dg * 16 + q + i;
            float4 w = *(const float4*)(cw + (size_t)d * 4);
            float xc = cbp[d] + w.w * b2f(rawxu[r + 3][q + i]) + w.z * b2f(rawxu[r + 2][q + i]) +
                       w.y * b2f(rawxu[r + 1][q + i]) + w.x * b2f(rawxu[r][q + i]);
            float ds = 1.f / (1.f + __expf(-dd[i]));
            sdx[r][q + i] = make_float2(ds, ds * xc);
            sxcu[r][q + i] = f2bf_bits(xc);
        }
    }
    __syncthreads();
    int lane = tid & 63, wave = tid >> 6;   // 8 waves
    int dir = wave >> 2;                    // 0 = fwd (waves 0-3), 1 = bwd (waves 4-7)
    int wl = wave & 3;
    int n = lane & 15;
    int dloc = wl * 4 + (lane >> 4);
    int d = dg * 16 + dloc;
    float asum2 = asumv[n];
    size_t cidx = ((((size_t)p * 2 + b) * NST + n) * DIN + d) * NCHUNK + c;
    if (dir == 0) {
        float h = Hinf[cidx];
#pragma unroll 4
        for (int t = 0; t < CHLEN; ++t) {
            float2 dx = sdx[t][dloc];
            float2 bc = sbc[t][n];
            float a = fast_exp2(dx.x * asum2);
            h = a * h + dx.y * bc.x;
            float pf = rowsum16(bc.y * h);
            if (n == 0) ysf[t][dloc] = pf;
        }
    } else {
        float gv = Hinb[cidx];
#pragma unroll 4
        for (int t = CHLEN - 1; t >= 0; --t) {
            float2 dx = sdx[t][dloc];
            float2 bc = sbc[t][n];
            float a = fast_exp2(dx.x * asum2);
            gv = a * gv + dx.y * bc.x;
            float pb = rowsum16(bc.y * gv);
            if (n == 0) ysb[t][dloc] = pb;
        }
    }
    __syncthreads();
    if (tid < 256) {
        int tl = tid >> 2, qq = (tid & 3) * 4;
        int d2 = dg * 16 + qq;
        float4 Dv = *(const float4*)(Dp + d2);
        float vs[4];
#pragma unroll
        for (int i = 0; i < 4; ++i)
            vs[i] = ysf[tl][qq + i] + ysb[tl][qq + i] +
                    ((const float*)&Dv)[i] * b2f(sxcu[tl][qq + i]);
        s16x4 pk = {(short)f2bf_bits(vs[0]), (short)f2bf_bits(vs[1]),
                    (short)f2bf_bits(vs[2]), (short)f2bf_bits(vs[3])};
        size_t row = (size_t)b * L_SEQ + t0 + tl;
        *(s16x4*)((unsigned short*)y + ((size_t)p * MROWS + row) * DIN + d2) = pk;
    }
}

extern "C" void kernel_launch(void* const* d_in, const int* in_sizes, int n_in,
                              void* d_out, int out_size, void* d_ws, size_t ws_size,
                              hipStream_t stream) {
    const float* x = (const float*)d_in[0];
    const float* norm_g = (const float*)d_in[1];
    const float* norm_b = (const float*)d_in[2];
    const float* Wp[2] = {(const float*)d_in[3], (const float*)d_in[11]};
    const float* cw[2] = {(const float*)d_in[4], (const float*)d_in[12]};
    const float* cb[2] = {(const float*)d_in[5], (const float*)d_in[13]};
    const float* Ab[2] = {(const float*)d_in[6], (const float*)d_in[14]};
    const float* Dpb[2] = {(const float*)d_in[7], (const float*)d_in[15]};
    const float* Wo[2] = {(const float*)d_in[8], (const float*)d_in[16]};
    const float* lng[2] = {(const float*)d_in[9], (const float*)d_in[17]};
    const float* lnb[2] = {(const float*)d_in[10], (const float*)d_in[18]};
    const float* Wf = (const float*)d_in[19];
    const float* bfv = (const float*)d_in[20];
    const float* W1 = (const float*)d_in[21];
    const float* b1 = (const float*)d_in[22];
    const float* W2 = (const float*)d_in[23];
    const float* b2 = (const float*)d_in[24];
    float* out = (float*)d_out;

    char* base = (char*)d_ws;
    size_t off = 0;
    auto alloc = [&](size_t bytes) { void* p = base + off; off += (bytes + 255) & ~(size_t)255; return p; };
    __hip_bfloat16* xpw = (__hip_bfloat16*)alloc((size_t)MROWS * XPW2 * 2);
    const size_t csz = (size_t)2 * 2 * NST * DIN * NCHUNK;
    float* Pc = (float*)alloc(csz * 4);
    float* Hfc = (float*)alloc(csz * 4);
    float* Gbc = (float*)alloc(csz * 4);
    float* Hinf = (float*)alloc(csz * 4);
    float* Hinb = (float*)alloc(csz * 4);
    __hip_bfloat16* xn_bf = (__hip_bfloat16*)alloc((size_t)MROWS * 96 * 2);
    __hip_bfloat16* yb_bf = (__hip_bfloat16*)alloc((size_t)2 * MROWS * DIN * 2);
    __hip_bfloat16* cat_bf = (__hip_bfloat16*)alloc((size_t)MROWS * DIN * 2);
    __hip_bfloat16* fc_bf = (__hip_bfloat16*)alloc((size_t)MROWS * 96 * 2);
    __hip_bfloat16* h1_bf = (__hip_bfloat16*)alloc((size_t)MROWS * 384 * 2);
    __hip_bfloat16* wpT = (__hip_bfloat16*)alloc((size_t)XPW2 * 96 * 2);
    __hip_bfloat16* woT[2] = {(__hip_bfloat16*)alloc(96 * 192 * 2),
                              (__hip_bfloat16*)alloc(96 * 192 * 2)};
    __hip_bfloat16* wfT = (__hip_bfloat16*)alloc(96 * 1728 * 2);
    __hip_bfloat16* w1T = (__hip_bfloat16*)alloc(384 * 96 * 2);
    __hip_bfloat16* w2T = (__hip_bfloat16*)alloc(96 * 384 * 2);
    (void)ws_size; (void)in_sizes; (void)n_in; (void)out_size;

    // 1. tiled weight transposes + input LN (one launch)
    prep_kernel<<<dim3(TP_BLOCKS + 2048), dim3(256), 0, stream>>>(
        Wp[0], Wp[1], Wo[0], Wo[1], Wf, W1, W2,
        wpT, woT[0], woT[1], wfT, w1T, w2T, x, norm_g, norm_b, xn_bf);
    // 2. xp(both branches, bf16) = xn @ [Wp1|Wp2]
    gemm_direct<2, 3, 2, 2, 96, 1, 0, __hip_bfloat16><<<dim3(10, 128), dim3(256), 0, stream>>>(
        xn_bf, 96, wpT, xpw, XPW2, XPW2, nullptr, nullptr);
    // 3-5. bidirectional selective scan, both branches
    scan_pass1f<<<dim3(SCAN_GRID), dim3(256), 0, stream>>>(
        xpw, cw[0], cw[1], cb[0], cb[1], Ab[0], Ab[1], Pc, Hfc, Gbc);
    scan_pass2<<<dim3(48), dim3(256), 0, stream>>>(Pc, Hfc, Gbc, Hinf, Hinb);
    scan_pass3f<<<dim3(SCAN_GRID), dim3(512), 0, stream>>>(
        xpw, cw[0], cw[1], cb[0], cb[1], Ab[0], Ab[1], Hinf, Hinb, Dpb[0], Dpb[1], yb_bf);
    // 6. f1/f2 = LN(y@Wo), cosine fuse -> cat (16-row tiles, 512 blocks)
    gemm_wo_ln_fuse<<<dim3(512), dim3(256), 0, stream>>>(
        yb_bf, woT[0], woT[1], lng[0], lnb[0], lng[1], lnb[1], cat_bf);
    // 7. fc = gelu(conv3x3(cat) + bf)  (16-row tiles, 512 blocks, 8 waves)
    conv3x3_direct<<<dim3(512), dim3(512), 0, stream>>>(cat_bf, wfT, bfv, fc_bf);
    // 8. h1 = gelu(fc @ W1 + b1)
    gemm_direct<2, 3, 2, 2, 96, 1, 1, __hip_bfloat16><<<dim3(4, 128), dim3(256), 0, stream>>>(
        fc_bf, 96, w1T, h1_bf, 384, 384, b1, nullptr);
    // 9. out = h1 @ W2 + b2 + res  (K-split, 8 waves)
    gemm_direct<1, 3, 2, 2, 384, 2, 2, float><<<dim3(1, 256), dim3(512), 0, stream>>>(
        h1_bf, 384, w2T, out, 96, 96, b2, x);
}

// Round 15
// 148.364 us; speedup vs baseline: 1.0618x; 1.0063x over previous
//
#include <hip/hip_runtime.h>
#include <hip/hip_bf16.h>
#include <math.h>

#define L_SEQ 4096
#define CDIM 96
#define DIN 192
#define NST 16
#define NCHUNK 64
#define CHLEN 64
#define MROWS 8192
#define XPW2 960   // combined xp width: 2 branches x 480 (416 used + pad)
#define SCAN_GRID 3072

typedef __attribute__((ext_vector_type(8))) short bf16x8;
typedef __attribute__((ext_vector_type(4))) float f32x4;
typedef __attribute__((ext_vector_type(4))) short s16x4;
typedef __attribute__((ext_vector_type(4))) unsigned short u16x4;

__device__ __forceinline__ float gelu_exact(float x) {
    return 0.5f * x * (1.0f + erff(x * 0.70710678118654752f));
}

__device__ __forceinline__ float fast_exp2(float x) {
#if __has_builtin(__builtin_amdgcn_exp2f)
    return __builtin_amdgcn_exp2f(x);
#else
    return exp2f(x);
#endif
}

__device__ __forceinline__ float b2f(unsigned short u) {
    return __uint_as_float((unsigned int)u << 16);
}

// 16-lane DPP row reduction via explicit v_add_f32_dpp; leaves the row sum in all 16 lanes.
__device__ __forceinline__ float rowsum16(float s) {
    asm("v_add_f32_dpp %0, %0, %0 row_ror:8 row_mask:0xf bank_mask:0xf" : "+v"(s));
    asm("v_add_f32_dpp %0, %0, %0 row_ror:4 row_mask:0xf bank_mask:0xf" : "+v"(s));
    asm("v_add_f32_dpp %0, %0, %0 row_ror:2 row_mask:0xf bank_mask:0xf" : "+v"(s));
    asm("v_add_f32_dpp %0, %0, %0 row_ror:1 row_mask:0xf bank_mask:0xf" : "+v"(s));
    return s;
}

__device__ __forceinline__ unsigned short f2bf_bits(float f) {
    __hip_bfloat16 h = __float2bfloat16(f);
    return *reinterpret_cast<unsigned short*>(&h);
}

// ---------------- prep: tiled weight transposes (coalesced) + input LayerNorm ----------------
#define TP_BLOCKS 360
__global__ __launch_bounds__(256) void prep_kernel(
    const float* __restrict__ Wp0, const float* __restrict__ Wp1,
    const float* __restrict__ Wo0, const float* __restrict__ Wo1,
    const float* __restrict__ Wf, const float* __restrict__ W1, const float* __restrict__ W2,
    __hip_bfloat16* __restrict__ wpT, __hip_bfloat16* __restrict__ wo0T,
    __hip_bfloat16* __restrict__ wo1T, __hip_bfloat16* __restrict__ wfT,
    __hip_bfloat16* __restrict__ w1T, __hip_bfloat16* __restrict__ w2T,
    const float* __restrict__ x, const float* __restrict__ g, const float* __restrict__ b,
    __hip_bfloat16* __restrict__ xn) {
    int tid = threadIdx.x;
    if (blockIdx.x < TP_BLOCKS) {
        int t = blockIdx.x;
        const float* S;
        __hip_bfloat16* D;
        int ldS, Cv, Rs;
        if (t < 45) { S = Wp0; D = wpT; ldS = 576; Cv = 416; Rs = 96; }
        else if (t < 90) { t -= 45; S = Wp1; D = wpT + 480 * 96; ldS = 576; Cv = 416; Rs = 96; }
        else if (t < 108) { t -= 90; S = Wo0; D = wo0T; ldS = 96; Cv = 96; Rs = 192; }
        else if (t < 126) { t -= 108; S = Wo1; D = wo1T; ldS = 96; Cv = 96; Rs = 192; }
        else if (t < 288) { t -= 126; S = Wf; D = wfT; ldS = 96; Cv = 96; Rs = 1728; }
        else if (t < 324) { t -= 288; S = W1; D = w1T; ldS = 384; Cv = 384; Rs = 96; }
        else { t -= 324; S = W2; D = w2T; ldS = 96; Cv = 96; Rs = 384; }
        int tilesJ = Rs >> 5;
        int ti = t / tilesJ, tj = t - ti * tilesJ;
        int c0 = ti * 32, r0 = tj * 32;
        __shared__ __hip_bfloat16 lt[32][33];
        int cl = tid & 31, rl = tid >> 5;
#pragma unroll
        for (int e = 0; e < 4; ++e) {
            int row = r0 + rl + e * 8;
            int col = c0 + cl;
            float v = (col < Cv) ? S[(size_t)row * ldS + col] : 0.f;
            lt[cl][rl + e * 8] = __float2bfloat16(v);
        }
        __syncthreads();
#pragma unroll
        for (int e = 0; e < 4; ++e) {
            int drow = c0 + rl + e * 8;
            int dcol = r0 + cl;
            D[(size_t)drow * Rs + dcol] = lt[rl + e * 8][cl];
        }
        return;
    }
    int wave = tid >> 6;
    int lane = tid & 63;
    int row = (blockIdx.x - TP_BLOCKS) * 4 + wave;
    if (row >= MROWS) return;
    const float* p = x + (size_t)row * CDIM;
    float x0 = p[lane];
    float x1 = (lane < 32) ? p[64 + lane] : 0.f;
    float s = x0 + x1, sq = x0 * x0 + x1 * x1;
#pragma unroll
    for (int o = 32; o >= 1; o >>= 1) { s += __shfl_xor(s, o); sq += __shfl_xor(sq, o); }
    float mean = s * (1.f / 96.f);
    float var = sq * (1.f / 96.f) - mean * mean;
    float w = rsqrtf(var + 1e-5f);
    __hip_bfloat16* q = xn + (size_t)row * CDIM;
    q[lane] = __float2bfloat16((x0 - mean) * w * g[lane] + b[lane]);
    if (lane < 32) q[64 + lane] = __float2bfloat16((x1 - mean) * w * g[64 + lane] + b[64 + lane]);
}

// ---------------- LDS-free direct-fragment MFMA GEMM (generic KS-way K-split) ----------------
template <int MI, int NI, int WR, int WC, int K, int KS, int EPI, typename CT>
__global__ __launch_bounds__(WR * WC * KS * 64) void gemm_direct(
    const __hip_bfloat16* __restrict__ A, int lda,
    const __hip_bfloat16* __restrict__ BT,
    CT* __restrict__ C, int ldc, int N,
    const float* __restrict__ bias, const float* __restrict__ res) {
    constexpr int BN = WC * NI * 16;
    constexpr int TILE = (WR * MI * 16) * BN;
    __shared__ float part[KS > 1 ? (KS - 1) * TILE : 1];
    int tid = threadIdx.x;
    int lane = tid & 63, wid = tid >> 6;
    int wk = wid / (WR * WC);
    int wrem = wid % (WR * WC);
    int wm = wrem % WR, wn = wrem / WR;
    int m0 = blockIdx.y * (WR * MI * 16) + wm * MI * 16;
    int n0 = blockIdx.x * (WC * NI * 16) + wn * NI * 16;
    int lr = lane & 15, kh = (lane >> 4) * 8;
    constexpr int KC = K / KS;
    f32x4 acc[MI][NI] = {};
    const __hip_bfloat16* Ap = A + (size_t)(m0 + lr) * lda + kh + wk * KC;
    const __hip_bfloat16* Bp = BT + (size_t)(n0 + lr) * K + kh + wk * KC;
#pragma unroll
    for (int k0 = 0; k0 < KC; k0 += 32) {
        bf16x8 af[MI], bf[NI];
#pragma unroll
        for (int i = 0; i < MI; ++i)
            af[i] = *reinterpret_cast<const bf16x8*>(Ap + (size_t)i * 16 * lda + k0);
#pragma unroll
        for (int j = 0; j < NI; ++j)
            bf[j] = *reinterpret_cast<const bf16x8*>(Bp + (size_t)j * 16 * K + k0);
#pragma unroll
        for (int i = 0; i < MI; ++i)
#pragma unroll
            for (int j = 0; j < NI; ++j)
                acc[i][j] = __builtin_amdgcn_mfma_f32_16x16x32_bf16(af[i], bf[j], acc[i][j], 0, 0, 0);
    }
    int cr = (lane >> 4) << 2;
    if (KS > 1) {
        if (wk != 0) {
#pragma unroll
            for (int i = 0; i < MI; ++i)
#pragma unroll
                for (int j = 0; j < NI; ++j)
#pragma unroll
                    for (int q = 0; q < 4; ++q)
                        part[(wk - 1) * TILE +
                             (wm * MI * 16 + i * 16 + cr + q) * BN + wn * NI * 16 + j * 16 + lr] =
                            acc[i][j][q];
        }
        __syncthreads();
        if (wk != 0) return;
#pragma unroll
        for (int i = 0; i < MI; ++i)
#pragma unroll
            for (int j = 0; j < NI; ++j)
#pragma unroll
                for (int q = 0; q < 4; ++q)
#pragma unroll
                    for (int s = 0; s < KS - 1; ++s)
                        acc[i][j][q] +=
                            part[s * TILE +
                                 (wm * MI * 16 + i * 16 + cr + q) * BN + wn * NI * 16 + j * 16 + lr];
    }
#pragma unroll
    for (int i = 0; i < MI; ++i) {
        int row = m0 + i * 16 + cr;
#pragma unroll
        for (int j = 0; j < NI; ++j) {
            int col = n0 + j * 16 + lr;
            if (col < N) {
#pragma unroll
                for (int q = 0; q < 4; ++q) {
                    float v = acc[i][j][q];
                    if (EPI == 1) v = gelu_exact(v + bias[col]);
                    else if (EPI == 2) v = v + bias[col] + res[(size_t)(row + q) * ldc + col];
                    C[(size_t)(row + q) * ldc + col] = (CT)v;
                }
            }
        }
    }
}

// ---------------- Wo GEMM both branches + LN + cosine fuse (16-row tiles, K-split, 8 waves) ----
__global__ __launch_bounds__(512) void gemm_wo_ln_fuse(
    const __hip_bfloat16* __restrict__ A,      // yb [2*8192][192]
    const __hip_bfloat16* __restrict__ BT0, const __hip_bfloat16* __restrict__ BT1,
    const float* __restrict__ g0, const float* __restrict__ b0,
    const float* __restrict__ g1, const float* __restrict__ b1,
    __hip_bfloat16* __restrict__ cat) {        // [8192][192]
    int tid = threadIdx.x;
    int lane = tid & 63, wid = tid >> 6;       // 8 waves: wk x wn x branch
    int wk = wid & 1, wn = (wid >> 1) & 1, wb = wid >> 2;
    int m0 = blockIdx.x * 16;
    int n0 = wn * 48;
    int lr = lane & 15, kh = (lane >> 4) * 8;
    f32x4 acc[3] = {};
    const __hip_bfloat16* Ap = A + (size_t)((wb ? MROWS : 0) + m0 + lr) * 192 + kh + wk * 96;
    const __hip_bfloat16* BT = wb ? BT1 : BT0;
    const __hip_bfloat16* Bp = BT + (size_t)(n0 + lr) * 192 + kh + wk * 96;
#pragma unroll
    for (int k0 = 0; k0 < 96; k0 += 32) {
        bf16x8 af = *reinterpret_cast<const bf16x8*>(Ap + k0);
#pragma unroll
        for (int j = 0; j < 3; ++j) {
            bf16x8 bv = *reinterpret_cast<const bf16x8*>(Bp + (size_t)j * 16 * 192 + k0);
            acc[j] = __builtin_amdgcn_mfma_f32_16x16x32_bf16(af, bv, acc[j], 0, 0, 0);
        }
    }
    __shared__ float ct[2][16][100];
    __shared__ float pt[2][16][100];
    int cr = (lane >> 4) << 2;
    if (wk == 1) {
#pragma unroll
        for (int j = 0; j < 3; ++j)
#pragma unroll
            for (int q = 0; q < 4; ++q)
                pt[wb][cr + q][n0 + j * 16 + lr] = acc[j][q];
    }
    __syncthreads();
    if (wk == 0) {
#pragma unroll
        for (int j = 0; j < 3; ++j)
#pragma unroll
            for (int q = 0; q < 4; ++q)
                ct[wb][cr + q][n0 + j * 16 + lr] = acc[j][q] + pt[wb][cr + q][n0 + j * 16 + lr];
    }
    __syncthreads();
#pragma unroll
    for (int rr = 0; rr < 2; ++rr) {
        int row = wid * 2 + rr;
        float a0 = ct[0][row][lane];
        float a1 = (lane < 32) ? ct[0][row][64 + lane] : 0.f;
        float c0 = ct[1][row][lane];
        float c1 = (lane < 32) ? ct[1][row][64 + lane] : 0.f;
        float s0 = a0 + a1, q0 = a0 * a0 + a1 * a1;
        float s1 = c0 + c1, q1 = c0 * c0 + c1 * c1;
#pragma unroll
        for (int o = 32; o >= 1; o >>= 1) {
            s0 += __shfl_xor(s0, o); q0 += __shfl_xor(q0, o);
            s1 += __shfl_xor(s1, o); q1 += __shfl_xor(q1, o);
        }
        float mu0 = s0 * (1.f / 96.f), w0 = rsqrtf(q0 * (1.f / 96.f) - mu0 * mu0 + 1e-5f);
        float mu1 = s1 * (1.f / 96.f), w1 = rsqrtf(q1 * (1.f / 96.f) - mu1 * mu1 + 1e-5f);
        float f1a = (a0 - mu0) * w0 * g0[lane] + b0[lane];
        float f2a = (c0 - mu1) * w1 * g1[lane] + b1[lane];
        float f1b = 0.f, f2b = 0.f;
        if (lane < 32) {
            f1b = (a1 - mu0) * w0 * g0[64 + lane] + b0[64 + lane];
            f2b = (c1 - mu1) * w1 * g1[64 + lane] + b1[64 + lane];
        }
        float s11 = f1a * f1a + f1b * f1b;
        float s22 = f2a * f2a + f2b * f2b;
        float s12 = f1a * f2a + f1b * f2b;
#pragma unroll
        for (int o = 32; o >= 1; o >>= 1) {
            s11 += __shfl_xor(s11, o);
            s22 += __shfl_xor(s22, o);
            s12 += __shfl_xor(s12, o);
        }
        float nr1 = fmaxf(sqrtf(s11), 1e-12f);
        float nr2 = fmaxf(sqrtf(s22), 1e-12f);
        float sim = s12 / (nr1 * nr2);
        size_t grow = (size_t)blockIdx.x * 16 + row;
        __hip_bfloat16* q = cat + grow * 192;
        q[lane] = __float2bfloat16(f1a);
        q[96 + lane] = __float2bfloat16(sim * f1a + (1.f - sim) * f2a);
        if (lane < 32) {
            q[64 + lane] = __float2bfloat16(f1b);
            q[96 + 64 + lane] = __float2bfloat16(sim * f1b + (1.f - sim) * f2b);
        }
    }
}

// ---------------- 3x3 SAME conv: 16-row tiles, balanced 4-way K-split (8 waves) ----------------
__global__ __launch_bounds__(512) void conv3x3_direct(const __hip_bfloat16* __restrict__ cat,
                                                      const __hip_bfloat16* __restrict__ WfT,
                                                      const float* __restrict__ bfv,
                                                      __hip_bfloat16* __restrict__ out) {
    __shared__ float part[3][16][100];
    int tid = threadIdx.x;
    int lane = tid & 63, wid = tid >> 6;   // 8 waves: wn(2) x wk(4)
    int wn = wid & 1, wk = wid >> 1;
    int m0 = blockIdx.x * 16;
    int n0 = wn * 48;
    int lr = lane & 15, kh = (lane >> 4) * 8;
    int m = m0 + lr;
    int bb = m >> 12, l = m & 4095, yy = l >> 6, xx = l & 63;
    f32x4 acc[3] = {};
    const __hip_bfloat16* Bp = WfT + (size_t)(n0 + lr) * 1728 + kh;
    for (int u = wk; u < 54; u += 4) {
        int tap = u / 6;
        int kc = (u - tap * 6) * 32;
        int ky = tap / 3, kx = tap - ky * 3;
        int iy = yy + ky - 1, ix = xx + kx - 1;
        bool ok = ((unsigned)iy < 64u) && ((unsigned)ix < 64u);
        bf16x8 af = {};
        if (ok)
            af = *reinterpret_cast<const bf16x8*>(
                cat + ((size_t)bb * 4096 + (size_t)(iy * 64 + ix)) * 192 + kh + kc);
        int kbase = tap * 192 + kc;
#pragma unroll
        for (int j = 0; j < 3; ++j) {
            bf16x8 bfr = *reinterpret_cast<const bf16x8*>(Bp + (size_t)j * 16 * 1728 + kbase);
            acc[j] = __builtin_amdgcn_mfma_f32_16x16x32_bf16(af, bfr, acc[j], 0, 0, 0);
        }
    }
    int cr = (lane >> 4) << 2;
    if (wk != 0) {
#pragma unroll
        for (int j = 0; j < 3; ++j)
#pragma unroll
            for (int q = 0; q < 4; ++q)
                part[wk - 1][cr + q][n0 + j * 16 + lr] = acc[j][q];
    }
    __syncthreads();
    if (wk != 0) return;
#pragma unroll
    for (int j = 0; j < 3; ++j) {
        int ccol = n0 + j * 16 + lr;
#pragma unroll
        for (int q = 0; q < 4; ++q) {
            float v = acc[j][q] + part[0][cr + q][ccol] + part[1][cr + q][ccol] +
                      part[2][cr + q][ccol];
            v = gelu_exact(v + bfv[ccol]);
            out[(size_t)(m0 + cr + q) * 96 + ccol] = __float2bfloat16(v);
        }
    }
}

// ---------------- scan pass1 (fused conv+sigmoid), 256 thr, 3-chain forward ----------------
__global__ __launch_bounds__(256) void scan_pass1f(
    const __hip_bfloat16* __restrict__ xpw,
    const float* __restrict__ cw0, const float* __restrict__ cw1,
    const float* __restrict__ cb0, const float* __restrict__ cb1,
    const float* __restrict__ A0, const float* __restrict__ A1,
    float* __restrict__ Pc, float* __restrict__ Hf, float* __restrict__ Gb) {
    __shared__ unsigned short rawxu[67][16];
    __shared__ float2 sdx[CHLEN][16];
    __shared__ float sb[CHLEN][16];
    __shared__ float asumv[16];
    int bid = (blockIdx.x & 7) * (SCAN_GRID / 8) + (blockIdx.x >> 3);  // XCD swizzle
    int dg = bid % 12;
    int c = (bid / 12) % NCHUNK;
    int b = (bid / (12 * NCHUNK)) & 1;
    int p = bid / (12 * NCHUNK * 2);
    const float* cw = p ? cw1 : cw0;
    const float* cbp = p ? cb1 : cb0;
    const float* Am = p ? A1 : A0;
    int tid = threadIdx.x;
    if (tid < 16) {
        const float4* Ap4 = (const float4*)(Am + tid * 16);
        float4 a0 = Ap4[0], a1 = Ap4[1], a2 = Ap4[2], a3 = Ap4[3];
        float s = (a0.x + a0.y + a0.z + a0.w) + (a1.x + a1.y + a1.z + a1.w) +
                  (a2.x + a2.y + a2.z + a2.w) + (a3.x + a3.y + a3.z + a3.w);
        asumv[tid] = s * 1.44269504f;
    }
    const unsigned short* xu = (const unsigned short*)xpw;
    int xb = p * 480;
    int t0 = c * CHLEN;
    int r = tid >> 2, q = (tid & 3) * 4;
    size_t grow = (size_t)b * L_SEQ + t0 + r;
    const unsigned short* rowp = xu + grow * XPW2 + xb;
    *(u16x4*)&rawxu[r + 3][q] = *(const u16x4*)(rowp + dg * 16 + q);
    u16x4 dvu = *(const u16x4*)(rowp + 192 + dg * 16 + q);
    u16x4 bvu = *(const u16x4*)(rowp + 384 + q);
    float4 bf4 = {b2f(bvu.x), b2f(bvu.y), b2f(bvu.z), b2f(bvu.w)};
    *(float4*)&sb[r][q] = bf4;
    if (tid < 12) {
        int rr = tid >> 2, qq = (tid & 3) * 4;
        int src = t0 - 3 + rr;
        u16x4 v = {0, 0, 0, 0};
        if (src >= 0)
            v = *(const u16x4*)(xu + ((size_t)b * L_SEQ + src) * XPW2 + xb + dg * 16 + qq);
        *(u16x4*)&rawxu[rr][qq] = v;
    }
    __syncthreads();
    float dd[4] = {b2f(dvu.x), b2f(dvu.y), b2f(dvu.z), b2f(dvu.w)};
#pragma unroll
    for (int i = 0; i < 4; ++i) {
        int d = dg * 16 + q + i;
        float4 w = *(const float4*)(cw + (size_t)d * 4);
        float xc = cbp[d] + w.w * b2f(rawxu[r + 3][q + i]) + w.z * b2f(rawxu[r + 2][q + i]) +
                   w.y * b2f(rawxu[r + 1][q + i]) + w.x * b2f(rawxu[r][q + i]);
        float ds = 1.f / (1.f + __expf(-dd[i]));
        sdx[r][q + i] = make_float2(ds, ds * xc);
    }
    __syncthreads();
    int n = tid & 15, drow = tid >> 4;
    float asum2 = asumv[n];
    float h = 0.f, gb = 0.f, Q = 1.f;
#pragma unroll 4
    for (int t = 0; t < CHLEN; ++t) {
        float2 dx = sdx[t][drow];
        float bm = sb[t][n];
        float a = fast_exp2(dx.x * asum2);
        float bu = dx.y * bm;
        h = a * h + bu;
        gb += Q * bu;
        Q *= a;
    }
    size_t cidx = ((((size_t)p * 2 + b) * NST + n) * DIN + dg * 16 + drow) * NCHUNK + c;
    Pc[cidx] = Q;
    Hf[cidx] = h;
    Gb[cidx] = gb;
}

// ---------------- scan pass2: combine chunk carries (contiguous float4 loads) ----------------
__global__ __launch_bounds__(256) void scan_pass2(const float* __restrict__ Pc,
                                                  const float* __restrict__ Hf,
                                                  const float* __restrict__ Gb,
                                                  float* __restrict__ Hinf,
                                                  float* __restrict__ Hinb) {
    int t = blockIdx.x * 256 + threadIdx.x;
    if (t >= 2 * 2 * NST * DIN) return;
    size_t base = (size_t)t * NCHUNK;
    {
        float4 P4[16], H4[16];
        const float4* Pp = (const float4*)(Pc + base);
        const float4* Hp = (const float4*)(Hf + base);
#pragma unroll
        for (int i = 0; i < 16; ++i) { P4[i] = Pp[i]; H4[i] = Hp[i]; }
        float hin = 0.f;
        float4* Op = (float4*)(Hinf + base);
#pragma unroll
        for (int i = 0; i < 16; ++i) {
            float4 o;
            o.x = hin; hin = H4[i].x + P4[i].x * hin;
            o.y = hin; hin = H4[i].y + P4[i].y * hin;
            o.z = hin; hin = H4[i].z + P4[i].z * hin;
            o.w = hin; hin = H4[i].w + P4[i].w * hin;
            Op[i] = o;
        }
    }
    {
        float4 P4[16], G4[16];
        const float4* Pp = (const float4*)(Pc + base);
        const float4* Gp = (const float4*)(Gb + base);
#pragma unroll
        for (int i = 0; i < 16; ++i) { P4[i] = Pp[i]; G4[i] = Gp[i]; }
        float gin = 0.f;
        float4* Op = (float4*)(Hinb + base);
#pragma unroll
        for (int i = 15; i >= 0; --i) {
            float4 o;
            o.w = gin; gin = G4[i].w + P4[i].w * gin;
            o.z = gin; gin = G4[i].z + P4[i].z * gin;
            o.y = gin; gin = G4[i].y + P4[i].y * gin;
            o.x = gin; gin = G4[i].x + P4[i].x * gin;
            Op[i] = o;
        }
    }
}

// ---------------- scan pass3 (fused conv): direction-split waves (4 fwd + 4 bwd) ----------------
__global__ __launch_bounds__(512) void scan_pass3f(
    const __hip_bfloat16* __restrict__ xpw,
    const float* __restrict__ cw0, const float* __restrict__ cw1,
    const float* __restrict__ cb0, const float* __restrict__ cb1,
    const float* __restrict__ A0, const float* __restrict__ A1,
    const float* __restrict__ Hinf, const float* __restrict__ Hinb,
    const float* __restrict__ Dp0, const float* __restrict__ Dp1,
    __hip_bfloat16* __restrict__ y) {
    __shared__ unsigned short rawxu[67][16];
    __shared__ float2 sdx[CHLEN][16];        // (ds, ds*xc)
    __shared__ float2 sbc[CHLEN][16];        // (Bm, Cm)
    __shared__ unsigned short sxcu[CHLEN][16];  // xc as bf16 (epilogue Dp*xc)
    __shared__ float ysf[CHLEN][16], ysb[CHLEN][16];
    __shared__ float asumv[16];
    int bid = (blockIdx.x & 7) * (SCAN_GRID / 8) + (blockIdx.x >> 3);  // XCD swizzle
    int dg = bid % 12;
    int c = (bid / 12) % NCHUNK;
    int b = (bid / (12 * NCHUNK)) & 1;
    int p = bid / (12 * NCHUNK * 2);
    const float* cw = p ? cw1 : cw0;
    const float* cbp = p ? cb1 : cb0;
    const float* Am = p ? A1 : A0;
    const float* Dp = p ? Dp1 : Dp0;
    int tid = threadIdx.x;
    if (tid < 16) {
        const float4* Ap4 = (const float4*)(Am + tid * 16);
        float4 a0 = Ap4[0], a1 = Ap4[1], a2 = Ap4[2], a3 = Ap4[3];
        float s = (a0.x + a0.y + a0.z + a0.w) + (a1.x + a1.y + a1.z + a1.w) +
                  (a2.x + a2.y + a2.z + a2.w) + (a3.x + a3.y + a3.z + a3.w);
        asumv[tid] = s * 1.44269504f;
    }
    const unsigned short* xu = (const unsigned short*)xpw;
    int xb = p * 480;
    int t0 = c * CHLEN;
    int r = tid >> 2, q = (tid & 3) * 4;
    u16x4 dvu = {0, 0, 0, 0};
    if (tid < 256) {
        size_t grow = (size_t)b * L_SEQ + t0 + r;
        const unsigned short* rowp = xu + grow * XPW2 + xb;
        *(u16x4*)&rawxu[r + 3][q] = *(const u16x4*)(rowp + dg * 16 + q);
        dvu = *(const u16x4*)(rowp + 192 + dg * 16 + q);
        u16x4 bvu = *(const u16x4*)(rowp + 384 + q);
        u16x4 cvu = *(const u16x4*)(rowp + 400 + q);
        sbc[r][q + 0] = make_float2(b2f(bvu.x), b2f(cvu.x));
        sbc[r][q + 1] = make_float2(b2f(bvu.y), b2f(cvu.y));
        sbc[r][q + 2] = make_float2(b2f(bvu.z), b2f(cvu.z));
        sbc[r][q + 3] = make_float2(b2f(bvu.w), b2f(cvu.w));
        if (tid < 12) {
            int rr = tid >> 2, qq = (tid & 3) * 4;
            int src = t0 - 3 + rr;
            u16x4 v = {0, 0, 0, 0};
            if (src >= 0)
                v = *(const u16x4*)(xu + ((size_t)b * L_SEQ + src) * XPW2 + xb + dg * 16 + qq);
            *(u16x4*)&rawxu[rr][qq] = v;
        }
    }
    __syncthreads();
    if (tid < 256) {
        float dd[4] = {b2f(dvu.x), b2f(dvu.y), b2f(dvu.z), b2f(dvu.w)};
#pragma unroll
        for (int i = 0; i < 4; ++i) {
            int d = dg * 16 + q + i;
            float4 w = *(const float4*)(cw + (size_t)d * 4);
            float xc = cbp[d] + w.w * b2f(rawxu[r + 3][q + i]) + w.z * b2f(rawxu[r + 2][q + i]) +
                       w.y * b2f(rawxu[r + 1][q + i]) + w.x * b2f(rawxu[r][q + i]);
            float ds = 1.f / (1.f + __expf(-dd[i]));
            sdx[r][q + i] = make_float2(ds, ds * xc);
            sxcu[r][q + i] = f2bf_bits(xc);
        }
    }
    __syncthreads();
    int lane = tid & 63, wave = tid >> 6;   // 8 waves
    int dir = wave >> 2;                    // 0 = fwd (waves 0-3), 1 = bwd (waves 4-7)
    int wl = wave & 3;
    int n = lane & 15;
    int dloc = wl * 4 + (lane >> 4);
    int d = dg * 16 + dloc;
    float asum2 = asumv[n];
    size_t cidx = ((((size_t)p * 2 + b) * NST + n) * DIN + d) * NCHUNK + c;
    if (dir == 0) {
        float h = Hinf[cidx];
#pragma unroll 4
        for (int t = 0; t < CHLEN; ++t) {
            float2 dx = sdx[t][dloc];
            float2 bc = sbc[t][n];
            float a = fast_exp2(dx.x * asum2);
            h = a * h + dx.y * bc.x;
            float pf = rowsum16(bc.y * h);
            if (n == 0) ysf[t][dloc] = pf;
        }
    } else {
        float gv = Hinb[cidx];
#pragma unroll 4
        for (int t = CHLEN - 1; t >= 0; --t) {
            float2 dx = sdx[t][dloc];
            float2 bc = sbc[t][n];
            float a = fast_exp2(dx.x * asum2);
            gv = a * gv + dx.y * bc.x;
            float pb = rowsum16(bc.y * gv);
            if (n == 0) ysb[t][dloc] = pb;
        }
    }
    __syncthreads();
    if (tid < 256) {
        int tl = tid >> 2, qq = (tid & 3) * 4;
        int d2 = dg * 16 + qq;
        float4 Dv = *(const float4*)(Dp + d2);
        float vs[4];
#pragma unroll
        for (int i = 0; i < 4; ++i)
            vs[i] = ysf[tl][qq + i] + ysb[tl][qq + i] +
                    ((const float*)&Dv)[i] * b2f(sxcu[tl][qq + i]);
        s16x4 pk = {(short)f2bf_bits(vs[0]), (short)f2bf_bits(vs[1]),
                    (short)f2bf_bits(vs[2]), (short)f2bf_bits(vs[3])};
        size_t row = (size_t)b * L_SEQ + t0 + tl;
        *(s16x4*)((unsigned short*)y + ((size_t)p * MROWS + row) * DIN + d2) = pk;
    }
}

extern "C" void kernel_launch(void* const* d_in, const int* in_sizes, int n_in,
                              void* d_out, int out_size, void* d_ws, size_t ws_size,
                              hipStream_t stream) {
    const float* x = (const float*)d_in[0];
    const float* norm_g = (const float*)d_in[1];
    const float* norm_b = (const float*)d_in[2];
    const float* Wp[2] = {(const float*)d_in[3], (const float*)d_in[11]};
    const float* cw[2] = {(const float*)d_in[4], (const float*)d_in[12]};
    const float* cb[2] = {(const float*)d_in[5], (const float*)d_in[13]};
    const float* Ab[2] = {(const float*)d_in[6], (const float*)d_in[14]};
    const float* Dpb[2] = {(const float*)d_in[7], (const float*)d_in[15]};
    const float* Wo[2] = {(const float*)d_in[8], (const float*)d_in[16]};
    const float* lng[2] = {(const float*)d_in[9], (const float*)d_in[17]};
    const float* lnb[2] = {(const float*)d_in[10], (const float*)d_in[18]};
    const float* Wf = (const float*)d_in[19];
    const float* bfv = (const float*)d_in[20];
    const float* W1 = (const float*)d_in[21];
    const float* b1 = (const float*)d_in[22];
    const float* W2 = (const float*)d_in[23];
    const float* b2 = (const float*)d_in[24];
    float* out = (float*)d_out;

    char* base = (char*)d_ws;
    size_t off = 0;
    auto alloc = [&](size_t bytes) { void* p = base + off; off += (bytes + 255) & ~(size_t)255; return p; };
    __hip_bfloat16* xpw = (__hip_bfloat16*)alloc((size_t)MROWS * XPW2 * 2);
    const size_t csz = (size_t)2 * 2 * NST * DIN * NCHUNK;
    float* Pc = (float*)alloc(csz * 4);
    float* Hfc = (float*)alloc(csz * 4);
    float* Gbc = (float*)alloc(csz * 4);
    float* Hinf = (float*)alloc(csz * 4);
    float* Hinb = (float*)alloc(csz * 4);
    __hip_bfloat16* xn_bf = (__hip_bfloat16*)alloc((size_t)MROWS * 96 * 2);
    __hip_bfloat16* yb_bf = (__hip_bfloat16*)alloc((size_t)2 * MROWS * DIN * 2);
    __hip_bfloat16* cat_bf = (__hip_bfloat16*)alloc((size_t)MROWS * DIN * 2);
    __hip_bfloat16* fc_bf = (__hip_bfloat16*)alloc((size_t)MROWS * 96 * 2);
    __hip_bfloat16* h1_bf = (__hip_bfloat16*)alloc((size_t)MROWS * 384 * 2);
    __hip_bfloat16* wpT = (__hip_bfloat16*)alloc((size_t)XPW2 * 96 * 2);
    __hip_bfloat16* woT[2] = {(__hip_bfloat16*)alloc(96 * 192 * 2),
                              (__hip_bfloat16*)alloc(96 * 192 * 2)};
    __hip_bfloat16* wfT = (__hip_bfloat16*)alloc(96 * 1728 * 2);
    __hip_bfloat16* w1T = (__hip_bfloat16*)alloc(384 * 96 * 2);
    __hip_bfloat16* w2T = (__hip_bfloat16*)alloc(96 * 384 * 2);
    (void)ws_size; (void)in_sizes; (void)n_in; (void)out_size;

    // 1. tiled weight transposes + input LN (one launch)
    prep_kernel<<<dim3(TP_BLOCKS + 2048), dim3(256), 0, stream>>>(
        Wp[0], Wp[1], Wo[0], Wo[1], Wf, W1, W2,
        wpT, woT[0], woT[1], wfT, w1T, w2T, x, norm_g, norm_b, xn_bf);
    // 2. xp(both branches, bf16) = xn @ [Wp1|Wp2]
    gemm_direct<2, 3, 2, 2, 96, 1, 0, __hip_bfloat16><<<dim3(10, 128), dim3(256), 0, stream>>>(
        xn_bf, 96, wpT, xpw, XPW2, XPW2, nullptr, nullptr);
    // 3-5. bidirectional selective scan, both branches
    scan_pass1f<<<dim3(SCAN_GRID), dim3(256), 0, stream>>>(
        xpw, cw[0], cw[1], cb[0], cb[1], Ab[0], Ab[1], Pc, Hfc, Gbc);
    scan_pass2<<<dim3(48), dim3(256), 0, stream>>>(Pc, Hfc, Gbc, Hinf, Hinb);
    scan_pass3f<<<dim3(SCAN_GRID), dim3(512), 0, stream>>>(
        xpw, cw[0], cw[1], cb[0], cb[1], Ab[0], Ab[1], Hinf, Hinb, Dpb[0], Dpb[1], yb_bf);
    // 6. f1/f2 = LN(y@Wo), cosine fuse -> cat (16-row tiles, K-split, 8 waves)
    gemm_wo_ln_fuse<<<dim3(512), dim3(512), 0, stream>>>(
        yb_bf, woT[0], woT[1], lng[0], lnb[0], lng[1], lnb[1], cat_bf);
    // 7. fc = gelu(conv3x3(cat) + bf)  (16-row tiles, 512 blocks, 8 waves)
    conv3x3_direct<<<dim3(512), dim3(512), 0, stream>>>(cat_bf, wfT, bfv, fc_bf);
    // 8. h1 = gelu(fc @ W1 + b1)  (MI=1: 1024 blocks, 4 waves)
    gemm_direct<1, 3, 2, 2, 96, 1, 1, __hip_bfloat16><<<dim3(4, 256), dim3(256), 0, stream>>>(
        fc_bf, 96, w1T, h1_bf, 384, 384, b1, nullptr);
    // 9. out = h1 @ W2 + b2 + res  (KS=4: 512 blocks, 8 waves)
    gemm_direct<1, 3, 1, 2, 384, 4, 2, float><<<dim3(1, 512), dim3(512), 0, stream>>>(
        h1_bf, 384, w2T, out, 96, 96, b2, x);
}

// Round 16
// 143.829 us; speedup vs baseline: 1.0953x; 1.0315x over previous
//
#include <hip/hip_runtime.h>
#include <hip/hip_bf16.h>
#include <math.h>

#define L_SEQ 4096
#define CDIM 96
#define DIN 192
#define NST 16
#define NCHUNK 64
#define CHLEN 64
#define MROWS 8192
#define XPW2 960   // combined xp width: 2 branches x 480 (416 used + pad)
#define SCAN_GRID 3072

typedef __attribute__((ext_vector_type(8))) short bf16x8;
typedef __attribute__((ext_vector_type(4))) float f32x4;
typedef __attribute__((ext_vector_type(4))) short s16x4;
typedef __attribute__((ext_vector_type(4))) unsigned short u16x4;

__device__ __forceinline__ float gelu_exact(float x) {
    return 0.5f * x * (1.0f + erff(x * 0.70710678118654752f));
}

__device__ __forceinline__ float fast_exp2(float x) {
#if __has_builtin(__builtin_amdgcn_exp2f)
    return __builtin_amdgcn_exp2f(x);
#else
    return exp2f(x);
#endif
}

__device__ __forceinline__ float b2f(unsigned short u) {
    return __uint_as_float((unsigned int)u << 16);
}

// 16-lane DPP row reduction via explicit v_add_f32_dpp; leaves the row sum in all 16 lanes.
__device__ __forceinline__ float rowsum16(float s) {
    asm("v_add_f32_dpp %0, %0, %0 row_ror:8 row_mask:0xf bank_mask:0xf" : "+v"(s));
    asm("v_add_f32_dpp %0, %0, %0 row_ror:4 row_mask:0xf bank_mask:0xf" : "+v"(s));
    asm("v_add_f32_dpp %0, %0, %0 row_ror:2 row_mask:0xf bank_mask:0xf" : "+v"(s));
    asm("v_add_f32_dpp %0, %0, %0 row_ror:1 row_mask:0xf bank_mask:0xf" : "+v"(s));
    return s;
}

__device__ __forceinline__ unsigned short f2bf_bits(float f) {
    __hip_bfloat16 h = __float2bfloat16(f);
    return *reinterpret_cast<unsigned short*>(&h);
}

// ---------------- prep: tiled weight transposes (coalesced) + input LayerNorm ----------------
#define TP_BLOCKS 360
__global__ __launch_bounds__(256) void prep_kernel(
    const float* __restrict__ Wp0, const float* __restrict__ Wp1,
    const float* __restrict__ Wo0, const float* __restrict__ Wo1,
    const float* __restrict__ Wf, const float* __restrict__ W1, const float* __restrict__ W2,
    __hip_bfloat16* __restrict__ wpT, __hip_bfloat16* __restrict__ wo0T,
    __hip_bfloat16* __restrict__ wo1T, __hip_bfloat16* __restrict__ wfT,
    __hip_bfloat16* __restrict__ w1T, __hip_bfloat16* __restrict__ w2T,
    const float* __restrict__ x, const float* __restrict__ g, const float* __restrict__ b,
    __hip_bfloat16* __restrict__ xn) {
    int tid = threadIdx.x;
    if (blockIdx.x < TP_BLOCKS) {
        int t = blockIdx.x;
        const float* S;
        __hip_bfloat16* D;
        int ldS, Cv, Rs;
        if (t < 45) { S = Wp0; D = wpT; ldS = 576; Cv = 416; Rs = 96; }
        else if (t < 90) { t -= 45; S = Wp1; D = wpT + 480 * 96; ldS = 576; Cv = 416; Rs = 96; }
        else if (t < 108) { t -= 90; S = Wo0; D = wo0T; ldS = 96; Cv = 96; Rs = 192; }
        else if (t < 126) { t -= 108; S = Wo1; D = wo1T; ldS = 96; Cv = 96; Rs = 192; }
        else if (t < 288) { t -= 126; S = Wf; D = wfT; ldS = 96; Cv = 96; Rs = 1728; }
        else if (t < 324) { t -= 288; S = W1; D = w1T; ldS = 384; Cv = 384; Rs = 96; }
        else { t -= 324; S = W2; D = w2T; ldS = 96; Cv = 96; Rs = 384; }
        int tilesJ = Rs >> 5;
        int ti = t / tilesJ, tj = t - ti * tilesJ;
        int c0 = ti * 32, r0 = tj * 32;
        __shared__ __hip_bfloat16 lt[32][33];
        int cl = tid & 31, rl = tid >> 5;
#pragma unroll
        for (int e = 0; e < 4; ++e) {
            int row = r0 + rl + e * 8;
            int col = c0 + cl;
            float v = (col < Cv) ? S[(size_t)row * ldS + col] : 0.f;
            lt[cl][rl + e * 8] = __float2bfloat16(v);
        }
        __syncthreads();
#pragma unroll
        for (int e = 0; e < 4; ++e) {
            int drow = c0 + rl + e * 8;
            int dcol = r0 + cl;
            D[(size_t)drow * Rs + dcol] = lt[rl + e * 8][cl];
        }
        return;
    }
    int wave = tid >> 6;
    int lane = tid & 63;
    int row = (blockIdx.x - TP_BLOCKS) * 4 + wave;
    if (row >= MROWS) return;
    const float* p = x + (size_t)row * CDIM;
    float x0 = p[lane];
    float x1 = (lane < 32) ? p[64 + lane] : 0.f;
    float s = x0 + x1, sq = x0 * x0 + x1 * x1;
#pragma unroll
    for (int o = 32; o >= 1; o >>= 1) { s += __shfl_xor(s, o); sq += __shfl_xor(sq, o); }
    float mean = s * (1.f / 96.f);
    float var = sq * (1.f / 96.f) - mean * mean;
    float w = rsqrtf(var + 1e-5f);
    __hip_bfloat16* q = xn + (size_t)row * CDIM;
    q[lane] = __float2bfloat16((x0 - mean) * w * g[lane] + b[lane]);
    if (lane < 32) q[64 + lane] = __float2bfloat16((x1 - mean) * w * g[64 + lane] + b[64 + lane]);
}

// ---------------- LDS-free direct-fragment MFMA GEMM ----------------
template <int MI, int NI, int WR, int WC, int K, int EPI, typename CT>
__global__ __launch_bounds__(WR * WC * 64) void gemm_direct(
    const __hip_bfloat16* __restrict__ A, int lda,
    const __hip_bfloat16* __restrict__ BT,
    CT* __restrict__ C, int ldc, int N,
    const float* __restrict__ bias, const float* __restrict__ res) {
    int tid = threadIdx.x;
    int lane = tid & 63, wid = tid >> 6;
    int wm = wid % WR, wn = wid / WR;
    int m0 = blockIdx.y * (WR * MI * 16) + wm * MI * 16;
    int n0 = blockIdx.x * (WC * NI * 16) + wn * NI * 16;
    int lr = lane & 15, kh = (lane >> 4) * 8;
    f32x4 acc[MI][NI] = {};
    const __hip_bfloat16* Ap = A + (size_t)(m0 + lr) * lda + kh;
    const __hip_bfloat16* Bp = BT + (size_t)(n0 + lr) * K + kh;
#pragma unroll
    for (int k0 = 0; k0 < K; k0 += 32) {
        bf16x8 af[MI], bf[NI];
#pragma unroll
        for (int i = 0; i < MI; ++i)
            af[i] = *reinterpret_cast<const bf16x8*>(Ap + (size_t)i * 16 * lda + k0);
#pragma unroll
        for (int j = 0; j < NI; ++j)
            bf[j] = *reinterpret_cast<const bf16x8*>(Bp + (size_t)j * 16 * K + k0);
#pragma unroll
        for (int i = 0; i < MI; ++i)
#pragma unroll
            for (int j = 0; j < NI; ++j)
                acc[i][j] = __builtin_amdgcn_mfma_f32_16x16x32_bf16(af[i], bf[j], acc[i][j], 0, 0, 0);
    }
    int cr = (lane >> 4) << 2;
#pragma unroll
    for (int i = 0; i < MI; ++i) {
        int row = m0 + i * 16 + cr;
#pragma unroll
        for (int j = 0; j < NI; ++j) {
            int col = n0 + j * 16 + lr;
            if (col < N) {
#pragma unroll
                for (int q = 0; q < 4; ++q) {
                    float v = acc[i][j][q];
                    if (EPI == 1) v = gelu_exact(v + bias[col]);
                    else if (EPI == 2) v = v + bias[col] + res[(size_t)(row + q) * ldc + col];
                    C[(size_t)(row + q) * ldc + col] = (CT)v;
                }
            }
        }
    }
}

// ---------------- fused MLP: out = gelu(fc@W1+b1) @ W2 + b2 + res (16-row tiles, 8 waves) ----
__global__ __launch_bounds__(512) void mlp_fused(
    const __hip_bfloat16* __restrict__ fc,   // [8192][96]
    const __hip_bfloat16* __restrict__ w1T,  // [384][96]
    const float* __restrict__ b1,
    const __hip_bfloat16* __restrict__ w2T,  // [96][384]
    const float* __restrict__ b2,
    const float* __restrict__ resx,          // [8192][96] f32
    float* __restrict__ out) {
    __shared__ unsigned short hl[16][392];   // h1 tile bf16, padded (784B row stride)
    __shared__ float part[3][16][100];
    int tid = threadIdx.x;
    int lane = tid & 63, wid = tid >> 6;     // 8 waves
    int lr = lane & 15, kh = (lane >> 4) * 8;
    int cr = (lane >> 4) << 2;
    int m0 = blockIdx.x * 16;
    // stage 1: h1 = gelu(fc @ W1 + b1); wave wid owns cols [wid*48, wid*48+48)
    {
        int n0 = wid * 48;
        f32x4 acc[3] = {};
        const __hip_bfloat16* Ap = fc + (size_t)(m0 + lr) * 96 + kh;
        const __hip_bfloat16* Bp = w1T + (size_t)(n0 + lr) * 96 + kh;
#pragma unroll
        for (int k0 = 0; k0 < 96; k0 += 32) {
            bf16x8 af = *reinterpret_cast<const bf16x8*>(Ap + k0);
#pragma unroll
            for (int j = 0; j < 3; ++j) {
                bf16x8 bv = *reinterpret_cast<const bf16x8*>(Bp + (size_t)j * 16 * 96 + k0);
                acc[j] = __builtin_amdgcn_mfma_f32_16x16x32_bf16(af, bv, acc[j], 0, 0, 0);
            }
        }
#pragma unroll
        for (int j = 0; j < 3; ++j) {
            int col = n0 + j * 16 + lr;
#pragma unroll
            for (int q = 0; q < 4; ++q)
                hl[cr + q][col] = f2bf_bits(gelu_exact(acc[j][q] + b1[col]));
        }
    }
    __syncthreads();
    // stage 2: out = h1 @ W2 + b2 + res; waves: wn(2 col-halves) x wk(4-way K split)
    {
        int wn = wid & 1, wk = wid >> 1;
        int n0 = wn * 48;
        int kb = wk * 96;
        f32x4 acc[3] = {};
        const __hip_bfloat16* Bp = w2T + (size_t)(n0 + lr) * 384 + kb + kh;
#pragma unroll
        for (int k0 = 0; k0 < 96; k0 += 32) {
            bf16x8 af = *reinterpret_cast<const bf16x8*>(
                (const unsigned short*)&hl[lr][kb + kh + k0]);
#pragma unroll
            for (int j = 0; j < 3; ++j) {
                bf16x8 bv = *reinterpret_cast<const bf16x8*>(Bp + (size_t)j * 16 * 384 + k0);
                acc[j] = __builtin_amdgcn_mfma_f32_16x16x32_bf16(af, bv, acc[j], 0, 0, 0);
            }
        }
        if (wk != 0) {
#pragma unroll
            for (int j = 0; j < 3; ++j)
#pragma unroll
                for (int q = 0; q < 4; ++q)
                    part[wk - 1][cr + q][n0 + j * 16 + lr] = acc[j][q];
        }
        __syncthreads();
        if (wk != 0) return;
#pragma unroll
        for (int j = 0; j < 3; ++j) {
            int col = n0 + j * 16 + lr;
#pragma unroll
            for (int q = 0; q < 4; ++q) {
                int row = m0 + cr + q;
                float v = acc[j][q] + part[0][cr + q][col] + part[1][cr + q][col] +
                          part[2][cr + q][col];
                out[(size_t)row * 96 + col] = v + b2[col] + resx[(size_t)row * 96 + col];
            }
        }
    }
}

// ---------------- Wo GEMM both branches + LN + cosine fuse (16-row tiles, K-split, 8 waves) ----
__global__ __launch_bounds__(512) void gemm_wo_ln_fuse(
    const __hip_bfloat16* __restrict__ A,      // yb [2*8192][192]
    const __hip_bfloat16* __restrict__ BT0, const __hip_bfloat16* __restrict__ BT1,
    const float* __restrict__ g0, const float* __restrict__ b0,
    const float* __restrict__ g1, const float* __restrict__ b1,
    __hip_bfloat16* __restrict__ cat) {        // [8192][192]
    int tid = threadIdx.x;
    int lane = tid & 63, wid = tid >> 6;       // 8 waves: wk x wn x branch
    int wk = wid & 1, wn = (wid >> 1) & 1, wb = wid >> 2;
    int m0 = blockIdx.x * 16;
    int n0 = wn * 48;
    int lr = lane & 15, kh = (lane >> 4) * 8;
    f32x4 acc[3] = {};
    const __hip_bfloat16* Ap = A + (size_t)((wb ? MROWS : 0) + m0 + lr) * 192 + kh + wk * 96;
    const __hip_bfloat16* BT = wb ? BT1 : BT0;
    const __hip_bfloat16* Bp = BT + (size_t)(n0 + lr) * 192 + kh + wk * 96;
#pragma unroll
    for (int k0 = 0; k0 < 96; k0 += 32) {
        bf16x8 af = *reinterpret_cast<const bf16x8*>(Ap + k0);
#pragma unroll
        for (int j = 0; j < 3; ++j) {
            bf16x8 bv = *reinterpret_cast<const bf16x8*>(Bp + (size_t)j * 16 * 192 + k0);
            acc[j] = __builtin_amdgcn_mfma_f32_16x16x32_bf16(af, bv, acc[j], 0, 0, 0);
        }
    }
    __shared__ float ct[2][16][100];
    __shared__ float pt[2][16][100];
    int cr = (lane >> 4) << 2;
    if (wk == 1) {
#pragma unroll
        for (int j = 0; j < 3; ++j)
#pragma unroll
            for (int q = 0; q < 4; ++q)
                pt[wb][cr + q][n0 + j * 16 + lr] = acc[j][q];
    }
    __syncthreads();
    if (wk == 0) {
#pragma unroll
        for (int j = 0; j < 3; ++j)
#pragma unroll
            for (int q = 0; q < 4; ++q)
                ct[wb][cr + q][n0 + j * 16 + lr] = acc[j][q] + pt[wb][cr + q][n0 + j * 16 + lr];
    }
    __syncthreads();
#pragma unroll
    for (int rr = 0; rr < 2; ++rr) {
        int row = wid * 2 + rr;
        float a0 = ct[0][row][lane];
        float a1 = (lane < 32) ? ct[0][row][64 + lane] : 0.f;
        float c0 = ct[1][row][lane];
        float c1 = (lane < 32) ? ct[1][row][64 + lane] : 0.f;
        float s0 = a0 + a1, q0 = a0 * a0 + a1 * a1;
        float s1 = c0 + c1, q1 = c0 * c0 + c1 * c1;
#pragma unroll
        for (int o = 32; o >= 1; o >>= 1) {
            s0 += __shfl_xor(s0, o); q0 += __shfl_xor(q0, o);
            s1 += __shfl_xor(s1, o); q1 += __shfl_xor(q1, o);
        }
        float mu0 = s0 * (1.f / 96.f), w0 = rsqrtf(q0 * (1.f / 96.f) - mu0 * mu0 + 1e-5f);
        float mu1 = s1 * (1.f / 96.f), w1 = rsqrtf(q1 * (1.f / 96.f) - mu1 * mu1 + 1e-5f);
        float f1a = (a0 - mu0) * w0 * g0[lane] + b0[lane];
        float f2a = (c0 - mu1) * w1 * g1[lane] + b1[lane];
        float f1b = 0.f, f2b = 0.f;
        if (lane < 32) {
            f1b = (a1 - mu0) * w0 * g0[64 + lane] + b0[64 + lane];
            f2b = (c1 - mu1) * w1 * g1[64 + lane] + b1[64 + lane];
        }
        float s11 = f1a * f1a + f1b * f1b;
        float s22 = f2a * f2a + f2b * f2b;
        float s12 = f1a * f2a + f1b * f2b;
#pragma unroll
        for (int o = 32; o >= 1; o >>= 1) {
            s11 += __shfl_xor(s11, o);
            s22 += __shfl_xor(s22, o);
            s12 += __shfl_xor(s12, o);
        }
        float nr1 = fmaxf(sqrtf(s11), 1e-12f);
        float nr2 = fmaxf(sqrtf(s22), 1e-12f);
        float sim = s12 / (nr1 * nr2);
        size_t grow = (size_t)blockIdx.x * 16 + row;
        __hip_bfloat16* q = cat + grow * 192;
        q[lane] = __float2bfloat16(f1a);
        q[96 + lane] = __float2bfloat16(sim * f1a + (1.f - sim) * f2a);
        if (lane < 32) {
            q[64 + lane] = __float2bfloat16(f1b);
            q[96 + 64 + lane] = __float2bfloat16(sim * f1b + (1.f - sim) * f2b);
        }
    }
}

// ---------------- 3x3 SAME conv: 16-row tiles, balanced 4-way K-split (8 waves) ----------------
__global__ __launch_bounds__(512) void conv3x3_direct(const __hip_bfloat16* __restrict__ cat,
                                                      const __hip_bfloat16* __restrict__ WfT,
                                                      const float* __restrict__ bfv,
                                                      __hip_bfloat16* __restrict__ out) {
    __shared__ float part[3][16][100];
    int tid = threadIdx.x;
    int lane = tid & 63, wid = tid >> 6;   // 8 waves: wn(2) x wk(4)
    int wn = wid & 1, wk = wid >> 1;
    int m0 = blockIdx.x * 16;
    int n0 = wn * 48;
    int lr = lane & 15, kh = (lane >> 4) * 8;
    int m = m0 + lr;
    int bb = m >> 12, l = m & 4095, yy = l >> 6, xx = l & 63;
    f32x4 acc[3] = {};
    const __hip_bfloat16* Bp = WfT + (size_t)(n0 + lr) * 1728 + kh;
    for (int u = wk; u < 54; u += 4) {
        int tap = u / 6;
        int kc = (u - tap * 6) * 32;
        int ky = tap / 3, kx = tap - ky * 3;
        int iy = yy + ky - 1, ix = xx + kx - 1;
        bool ok = ((unsigned)iy < 64u) && ((unsigned)ix < 64u);
        bf16x8 af = {};
        if (ok)
            af = *reinterpret_cast<const bf16x8*>(
                cat + ((size_t)bb * 4096 + (size_t)(iy * 64 + ix)) * 192 + kh + kc);
        int kbase = tap * 192 + kc;
#pragma unroll
        for (int j = 0; j < 3; ++j) {
            bf16x8 bfr = *reinterpret_cast<const bf16x8*>(Bp + (size_t)j * 16 * 1728 + kbase);
            acc[j] = __builtin_amdgcn_mfma_f32_16x16x32_bf16(af, bfr, acc[j], 0, 0, 0);
        }
    }
    int cr = (lane >> 4) << 2;
    if (wk != 0) {
#pragma unroll
        for (int j = 0; j < 3; ++j)
#pragma unroll
            for (int q = 0; q < 4; ++q)
                part[wk - 1][cr + q][n0 + j * 16 + lr] = acc[j][q];
    }
    __syncthreads();
    if (wk != 0) return;
#pragma unroll
    for (int j = 0; j < 3; ++j) {
        int ccol = n0 + j * 16 + lr;
#pragma unroll
        for (int q = 0; q < 4; ++q) {
            float v = acc[j][q] + part[0][cr + q][ccol] + part[1][cr + q][ccol] +
                      part[2][cr + q][ccol];
            v = gelu_exact(v + bfv[ccol]);
            out[(size_t)(m0 + cr + q) * 96 + ccol] = __float2bfloat16(v);
        }
    }
}

// ---------------- scan pass1 (fused conv+sigmoid), 256 thr, 3-chain forward ----------------
__global__ __launch_bounds__(256) void scan_pass1f(
    const __hip_bfloat16* __restrict__ xpw,
    const float* __restrict__ cw0, const float* __restrict__ cw1,
    const float* __restrict__ cb0, const float* __restrict__ cb1,
    const float* __restrict__ A0, const float* __restrict__ A1,
    float* __restrict__ Pc, float* __restrict__ Hf, float* __restrict__ Gb) {
    __shared__ unsigned short rawxu[67][16];
    __shared__ float2 sdx[CHLEN][16];
    __shared__ float sb[CHLEN][16];
    __shared__ float asumv[16];
    int bid = (blockIdx.x & 7) * (SCAN_GRID / 8) + (blockIdx.x >> 3);  // XCD swizzle
    int dg = bid % 12;
    int c = (bid / 12) % NCHUNK;
    int b = (bid / (12 * NCHUNK)) & 1;
    int p = bid / (12 * NCHUNK * 2);
    const float* cw = p ? cw1 : cw0;
    const float* cbp = p ? cb1 : cb0;
    const float* Am = p ? A1 : A0;
    int tid = threadIdx.x;
    if (tid < 16) {
        const float4* Ap4 = (const float4*)(Am + tid * 16);
        float4 a0 = Ap4[0], a1 = Ap4[1], a2 = Ap4[2], a3 = Ap4[3];
        float s = (a0.x + a0.y + a0.z + a0.w) + (a1.x + a1.y + a1.z + a1.w) +
                  (a2.x + a2.y + a2.z + a2.w) + (a3.x + a3.y + a3.z + a3.w);
        asumv[tid] = s * 1.44269504f;
    }
    const unsigned short* xu = (const unsigned short*)xpw;
    int xb = p * 480;
    int t0 = c * CHLEN;
    int r = tid >> 2, q = (tid & 3) * 4;
    size_t grow = (size_t)b * L_SEQ + t0 + r;
    const unsigned short* rowp = xu + grow * XPW2 + xb;
    *(u16x4*)&rawxu[r + 3][q] = *(const u16x4*)(rowp + dg * 16 + q);
    u16x4 dvu = *(const u16x4*)(rowp + 192 + dg * 16 + q);
    u16x4 bvu = *(const u16x4*)(rowp + 384 + q);
    float4 bf4 = {b2f(bvu.x), b2f(bvu.y), b2f(bvu.z), b2f(bvu.w)};
    *(float4*)&sb[r][q] = bf4;
    if (tid < 12) {
        int rr = tid >> 2, qq = (tid & 3) * 4;
        int src = t0 - 3 + rr;
        u16x4 v = {0, 0, 0, 0};
        if (src >= 0)
            v = *(const u16x4*)(xu + ((size_t)b * L_SEQ + src) * XPW2 + xb + dg * 16 + qq);
        *(u16x4*)&rawxu[rr][qq] = v;
    }
    __syncthreads();
    float dd[4] = {b2f(dvu.x), b2f(dvu.y), b2f(dvu.z), b2f(dvu.w)};
#pragma unroll
    for (int i = 0; i < 4; ++i) {
        int d = dg * 16 + q + i;
        float4 w = *(const float4*)(cw + (size_t)d * 4);
        float xc = cbp[d] + w.w * b2f(rawxu[r + 3][q + i]) + w.z * b2f(rawxu[r + 2][q + i]) +
                   w.y * b2f(rawxu[r + 1][q + i]) + w.x * b2f(rawxu[r][q + i]);
        float ds = 1.f / (1.f + __expf(-dd[i]));
        sdx[r][q + i] = make_float2(ds, ds * xc);
    }
    __syncthreads();
    int n = tid & 15, drow = tid >> 4;
    float asum2 = asumv[n];
    float h = 0.f, gb = 0.f, Q = 1.f;
#pragma unroll 4
    for (int t = 0; t < CHLEN; ++t) {
        float2 dx = sdx[t][drow];
        float bm = sb[t][n];
        float a = fast_exp2(dx.x * asum2);
        float bu = dx.y * bm;
        h = a * h + bu;
        gb += Q * bu;
        Q *= a;
    }
    size_t cidx = ((((size_t)p * 2 + b) * NST + n) * DIN + dg * 16 + drow) * NCHUNK + c;
    Pc[cidx] = Q;
    Hf[cidx] = h;
    Gb[cidx] = gb;
}

// ---------------- scan pass2: combine chunk carries (contiguous float4 loads) ----------------
__global__ __launch_bounds__(256) void scan_pass2(const float* __restrict__ Pc,
                                                  const float* __restrict__ Hf,
                                                  const float* __restrict__ Gb,
                                                  float* __restrict__ Hinf,
                                                  float* __restrict__ Hinb) {
    int t = blockIdx.x * 256 + threadIdx.x;
    if (t >= 2 * 2 * NST * DIN) return;
    size_t base = (size_t)t * NCHUNK;
    {
        float4 P4[16], H4[16];
        const float4* Pp = (const float4*)(Pc + base);
        const float4* Hp = (const float4*)(Hf + base);
#pragma unroll
        for (int i = 0; i < 16; ++i) { P4[i] = Pp[i]; H4[i] = Hp[i]; }
        float hin = 0.f;
        float4* Op = (float4*)(Hinf + base);
#pragma unroll
        for (int i = 0; i < 16; ++i) {
            float4 o;
            o.x = hin; hin = H4[i].x + P4[i].x * hin;
            o.y = hin; hin = H4[i].y + P4[i].y * hin;
            o.z = hin; hin = H4[i].z + P4[i].z * hin;
            o.w = hin; hin = H4[i].w + P4[i].w * hin;
            Op[i] = o;
        }
    }
    {
        float4 P4[16], G4[16];
        const float4* Pp = (const float4*)(Pc + base);
        const float4* Gp = (const float4*)(Gb + base);
#pragma unroll
        for (int i = 0; i < 16; ++i) { P4[i] = Pp[i]; G4[i] = Gp[i]; }
        float gin = 0.f;
        float4* Op = (float4*)(Hinb + base);
#pragma unroll
        for (int i = 15; i >= 0; --i) {
            float4 o;
            o.w = gin; gin = G4[i].w + P4[i].w * gin;
            o.z = gin; gin = G4[i].z + P4[i].z * gin;
            o.y = gin; gin = G4[i].y + P4[i].y * gin;
            o.x = gin; gin = G4[i].x + P4[i].x * gin;
            Op[i] = o;
        }
    }
}

// ---------------- scan pass3 (fused conv): direction-split waves (4 fwd + 4 bwd) ----------------
__global__ __launch_bounds__(512) void scan_pass3f(
    const __hip_bfloat16* __restrict__ xpw,
    const float* __restrict__ cw0, const float* __restrict__ cw1,
    const float* __restrict__ cb0, const float* __restrict__ cb1,
    const float* __restrict__ A0, const float* __restrict__ A1,
    const float* __restrict__ Hinf, const float* __restrict__ Hinb,
    const float* __restrict__ Dp0, const float* __restrict__ Dp1,
    __hip_bfloat16* __restrict__ y) {
    __shared__ unsigned short rawxu[67][16];
    __shared__ float2 sdx[CHLEN][16];        // (ds, ds*xc)
    __shared__ float2 sbc[CHLEN][16];        // (Bm, Cm)
    __shared__ unsigned short sxcu[CHLEN][16];  // xc as bf16 (epilogue Dp*xc)
    __shared__ float ysf[CHLEN][16], ysb[CHLEN][16];
    __shared__ float asumv[16];
    int bid = (blockIdx.x & 7) * (SCAN_GRID / 8) + (blockIdx.x >> 3);  // XCD swizzle
    int dg = bid % 12;
    int c = (bid / 12) % NCHUNK;
    int b = (bid / (12 * NCHUNK)) & 1;
    int p = bid / (12 * NCHUNK * 2);
    const float* cw = p ? cw1 : cw0;
    const float* cbp = p ? cb1 : cb0;
    const float* Am = p ? A1 : A0;
    const float* Dp = p ? Dp1 : Dp0;
    int tid = threadIdx.x;
    if (tid < 16) {
        const float4* Ap4 = (const float4*)(Am + tid * 16);
        float4 a0 = Ap4[0], a1 = Ap4[1], a2 = Ap4[2], a3 = Ap4[3];
        float s = (a0.x + a0.y + a0.z + a0.w) + (a1.x + a1.y + a1.z + a1.w) +
                  (a2.x + a2.y + a2.z + a2.w) + (a3.x + a3.y + a3.z + a3.w);
        asumv[tid] = s * 1.44269504f;
    }
    const unsigned short* xu = (const unsigned short*)xpw;
    int xb = p * 480;
    int t0 = c * CHLEN;
    int r = tid >> 2, q = (tid & 3) * 4;
    u16x4 dvu = {0, 0, 0, 0};
    if (tid < 256) {
        size_t grow = (size_t)b * L_SEQ + t0 + r;
        const unsigned short* rowp = xu + grow * XPW2 + xb;
        *(u16x4*)&rawxu[r + 3][q] = *(const u16x4*)(rowp + dg * 16 + q);
        dvu = *(const u16x4*)(rowp + 192 + dg * 16 + q);
        u16x4 bvu = *(const u16x4*)(rowp + 384 + q);
        u16x4 cvu = *(const u16x4*)(rowp + 400 + q);
        sbc[r][q + 0] = make_float2(b2f(bvu.x), b2f(cvu.x));
        sbc[r][q + 1] = make_float2(b2f(bvu.y), b2f(cvu.y));
        sbc[r][q + 2] = make_float2(b2f(bvu.z), b2f(cvu.z));
        sbc[r][q + 3] = make_float2(b2f(bvu.w), b2f(cvu.w));
        if (tid < 12) {
            int rr = tid >> 2, qq = (tid & 3) * 4;
            int src = t0 - 3 + rr;
            u16x4 v = {0, 0, 0, 0};
            if (src >= 0)
                v = *(const u16x4*)(xu + ((size_t)b * L_SEQ + src) * XPW2 + xb + dg * 16 + qq);
            *(u16x4*)&rawxu[rr][qq] = v;
        }
    }
    __syncthreads();
    if (tid < 256) {
        float dd[4] = {b2f(dvu.x), b2f(dvu.y), b2f(dvu.z), b2f(dvu.w)};
#pragma unroll
        for (int i = 0; i < 4; ++i) {
            int d = dg * 16 + q + i;
            float4 w = *(const float4*)(cw + (size_t)d * 4);
            float xc = cbp[d] + w.w * b2f(rawxu[r + 3][q + i]) + w.z * b2f(rawxu[r + 2][q + i]) +
                       w.y * b2f(rawxu[r + 1][q + i]) + w.x * b2f(rawxu[r][q + i]);
            float ds = 1.f / (1.f + __expf(-dd[i]));
            sdx[r][q + i] = make_float2(ds, ds * xc);
            sxcu[r][q + i] = f2bf_bits(xc);
        }
    }
    __syncthreads();
    int lane = tid & 63, wave = tid >> 6;   // 8 waves
    int dir = wave >> 2;                    // 0 = fwd (waves 0-3), 1 = bwd (waves 4-7)
    int wl = wave & 3;
    int n = lane & 15;
    int dloc = wl * 4 + (lane >> 4);
    int d = dg * 16 + dloc;
    float asum2 = asumv[n];
    size_t cidx = ((((size_t)p * 2 + b) * NST + n) * DIN + d) * NCHUNK + c;
    if (dir == 0) {
        float h = Hinf[cidx];
#pragma unroll 4
        for (int t = 0; t < CHLEN; ++t) {
            float2 dx = sdx[t][dloc];
            float2 bc = sbc[t][n];
            float a = fast_exp2(dx.x * asum2);
            h = a * h + dx.y * bc.x;
            float pf = rowsum16(bc.y * h);
            if (n == 0) ysf[t][dloc] = pf;
        }
    } else {
        float gv = Hinb[cidx];
#pragma unroll 4
        for (int t = CHLEN - 1; t >= 0; --t) {
            float2 dx = sdx[t][dloc];
            float2 bc = sbc[t][n];
            float a = fast_exp2(dx.x * asum2);
            gv = a * gv + dx.y * bc.x;
            float pb = rowsum16(bc.y * gv);
            if (n == 0) ysb[t][dloc] = pb;
        }
    }
    __syncthreads();
    if (tid < 256) {
        int tl = tid >> 2, qq = (tid & 3) * 4;
        int d2 = dg * 16 + qq;
        float4 Dv = *(const float4*)(Dp + d2);
        float vs[4];
#pragma unroll
        for (int i = 0; i < 4; ++i)
            vs[i] = ysf[tl][qq + i] + ysb[tl][qq + i] +
                    ((const float*)&Dv)[i] * b2f(sxcu[tl][qq + i]);
        s16x4 pk = {(short)f2bf_bits(vs[0]), (short)f2bf_bits(vs[1]),
                    (short)f2bf_bits(vs[2]), (short)f2bf_bits(vs[3])};
        size_t row = (size_t)b * L_SEQ + t0 + tl;
        *(s16x4*)((unsigned short*)y + ((size_t)p * MROWS + row) * DIN + d2) = pk;
    }
}

extern "C" void kernel_launch(void* const* d_in, const int* in_sizes, int n_in,
                              void* d_out, int out_size, void* d_ws, size_t ws_size,
                              hipStream_t stream) {
    const float* x = (const float*)d_in[0];
    const float* norm_g = (const float*)d_in[1];
    const float* norm_b = (const float*)d_in[2];
    const float* Wp[2] = {(const float*)d_in[3], (const float*)d_in[11]};
    const float* cw[2] = {(const float*)d_in[4], (const float*)d_in[12]};
    const float* cb[2] = {(const float*)d_in[5], (const float*)d_in[13]};
    const float* Ab[2] = {(const float*)d_in[6], (const float*)d_in[14]};
    const float* Dpb[2] = {(const float*)d_in[7], (const float*)d_in[15]};
    const float* Wo[2] = {(const float*)d_in[8], (const float*)d_in[16]};
    const float* lng[2] = {(const float*)d_in[9], (const float*)d_in[17]};
    const float* lnb[2] = {(const float*)d_in[10], (const float*)d_in[18]};
    const float* Wf = (const float*)d_in[19];
    const float* bfv = (const float*)d_in[20];
    const float* W1 = (const float*)d_in[21];
    const float* b1 = (const float*)d_in[22];
    const float* W2 = (const float*)d_in[23];
    const float* b2 = (const float*)d_in[24];
    float* out = (float*)d_out;

    char* base = (char*)d_ws;
    size_t off = 0;
    auto alloc = [&](size_t bytes) { void* p = base + off; off += (bytes + 255) & ~(size_t)255; return p; };
    __hip_bfloat16* xpw = (__hip_bfloat16*)alloc((size_t)MROWS * XPW2 * 2);
    const size_t csz = (size_t)2 * 2 * NST * DIN * NCHUNK;
    float* Pc = (float*)alloc(csz * 4);
    float* Hfc = (float*)alloc(csz * 4);
    float* Gbc = (float*)alloc(csz * 4);
    float* Hinf = (float*)alloc(csz * 4);
    float* Hinb = (float*)alloc(csz * 4);
    __hip_bfloat16* xn_bf = (__hip_bfloat16*)alloc((size_t)MROWS * 96 * 2);
    __hip_bfloat16* yb_bf = (__hip_bfloat16*)alloc((size_t)2 * MROWS * DIN * 2);
    __hip_bfloat16* cat_bf = (__hip_bfloat16*)alloc((size_t)MROWS * DIN * 2);
    __hip_bfloat16* fc_bf = (__hip_bfloat16*)alloc((size_t)MROWS * 96 * 2);
    __hip_bfloat16* wpT = (__hip_bfloat16*)alloc((size_t)XPW2 * 96 * 2);
    __hip_bfloat16* woT[2] = {(__hip_bfloat16*)alloc(96 * 192 * 2),
                              (__hip_bfloat16*)alloc(96 * 192 * 2)};
    __hip_bfloat16* wfT = (__hip_bfloat16*)alloc(96 * 1728 * 2);
    __hip_bfloat16* w1T = (__hip_bfloat16*)alloc(384 * 96 * 2);
    __hip_bfloat16* w2T = (__hip_bfloat16*)alloc(96 * 384 * 2);
    (void)ws_size; (void)in_sizes; (void)n_in; (void)out_size;

    // 1. tiled weight transposes + input LN (one launch)
    prep_kernel<<<dim3(TP_BLOCKS + 2048), dim3(256), 0, stream>>>(
        Wp[0], Wp[1], Wo[0], Wo[1], Wf, W1, W2,
        wpT, woT[0], woT[1], wfT, w1T, w2T, x, norm_g, norm_b, xn_bf);
    // 2. xp(both branches, bf16) = xn @ [Wp1|Wp2]
    gemm_direct<2, 3, 2, 2, 96, 0, __hip_bfloat16><<<dim3(10, 128), dim3(256), 0, stream>>>(
        xn_bf, 96, wpT, xpw, XPW2, XPW2, nullptr, nullptr);
    // 3-5. bidirectional selective scan, both branches
    scan_pass1f<<<dim3(SCAN_GRID), dim3(256), 0, stream>>>(
        xpw, cw[0], cw[1], cb[0], cb[1], Ab[0], Ab[1], Pc, Hfc, Gbc);
    scan_pass2<<<dim3(48), dim3(256), 0, stream>>>(Pc, Hfc, Gbc, Hinf, Hinb);
    scan_pass3f<<<dim3(SCAN_GRID), dim3(512), 0, stream>>>(
        xpw, cw[0], cw[1], cb[0], cb[1], Ab[0], Ab[1], Hinf, Hinb, Dpb[0], Dpb[1], yb_bf);
    // 6. f1/f2 = LN(y@Wo), cosine fuse -> cat (16-row tiles, K-split, 8 waves)
    gemm_wo_ln_fuse<<<dim3(512), dim3(512), 0, stream>>>(
        yb_bf, woT[0], woT[1], lng[0], lnb[0], lng[1], lnb[1], cat_bf);
    // 7. fc = gelu(conv3x3(cat) + bf)  (16-row tiles, 512 blocks, 8 waves)
    conv3x3_direct<<<dim3(512), dim3(512), 0, stream>>>(cat_bf, wfT, bfv, fc_bf);
    // 8. out = gelu(fc@W1+b1) @ W2 + b2 + res  (fused MLP, one launch)
    mlp_fused<<<dim3(512), dim3(512), 0, stream>>>(fc_bf, w1T, b1, w2T, b2, x, out);
}

// Round 17
// 140.605 us; speedup vs baseline: 1.1204x; 1.0229x over previous
//
#include <hip/hip_runtime.h>
#include <hip/hip_bf16.h>
#include <math.h>

#define L_SEQ 4096
#define CDIM 96
#define DIN 192
#define NST 16
#define NCHUNK 64
#define CHLEN 64
#define MROWS 8192
#define XPW2 960   // combined xp width: 2 branches x 480 (416 used + pad)
#define SCAN_GRID 3072

typedef __attribute__((ext_vector_type(8))) short bf16x8;
typedef __attribute__((ext_vector_type(4))) float f32x4;
typedef __attribute__((ext_vector_type(4))) short s16x4;
typedef __attribute__((ext_vector_type(4))) unsigned short u16x4;

__device__ __forceinline__ float gelu_exact(float x) {
    return 0.5f * x * (1.0f + erff(x * 0.70710678118654752f));
}

__device__ __forceinline__ float fast_exp2(float x) {
#if __has_builtin(__builtin_amdgcn_exp2f)
    return __builtin_amdgcn_exp2f(x);
#else
    return exp2f(x);
#endif
}

__device__ __forceinline__ float b2f(unsigned short u) {
    return __uint_as_float((unsigned int)u << 16);
}

// 16-lane DPP row reduction via explicit v_add_f32_dpp; leaves the row sum in all 16 lanes.
__device__ __forceinline__ float rowsum16(float s) {
    asm("v_add_f32_dpp %0, %0, %0 row_ror:8 row_mask:0xf bank_mask:0xf" : "+v"(s));
    asm("v_add_f32_dpp %0, %0, %0 row_ror:4 row_mask:0xf bank_mask:0xf" : "+v"(s));
    asm("v_add_f32_dpp %0, %0, %0 row_ror:2 row_mask:0xf bank_mask:0xf" : "+v"(s));
    asm("v_add_f32_dpp %0, %0, %0 row_ror:1 row_mask:0xf bank_mask:0xf" : "+v"(s));
    return s;
}

__device__ __forceinline__ unsigned short f2bf_bits(float f) {
    __hip_bfloat16 h = __float2bfloat16(f);
    return *reinterpret_cast<unsigned short*>(&h);
}

// ---------------- prep: tiled weight transposes (coalesced) + input LayerNorm ----------------
#define TP_BLOCKS 360
__global__ __launch_bounds__(256) void prep_kernel(
    const float* __restrict__ Wp0, const float* __restrict__ Wp1,
    const float* __restrict__ Wo0, const float* __restrict__ Wo1,
    const float* __restrict__ Wf, const float* __restrict__ W1, const float* __restrict__ W2,
    __hip_bfloat16* __restrict__ wpT, __hip_bfloat16* __restrict__ wo0T,
    __hip_bfloat16* __restrict__ wo1T, __hip_bfloat16* __restrict__ wfT,
    __hip_bfloat16* __restrict__ w1T, __hip_bfloat16* __restrict__ w2T,
    const float* __restrict__ x, const float* __restrict__ g, const float* __restrict__ b,
    __hip_bfloat16* __restrict__ xn) {
    int tid = threadIdx.x;
    if (blockIdx.x < TP_BLOCKS) {
        int t = blockIdx.x;
        const float* S;
        __hip_bfloat16* D;
        int ldS, Cv, Rs;
        if (t < 45) { S = Wp0; D = wpT; ldS = 576; Cv = 416; Rs = 96; }
        else if (t < 90) { t -= 45; S = Wp1; D = wpT + 480 * 96; ldS = 576; Cv = 416; Rs = 96; }
        else if (t < 108) { t -= 90; S = Wo0; D = wo0T; ldS = 96; Cv = 96; Rs = 192; }
        else if (t < 126) { t -= 108; S = Wo1; D = wo1T; ldS = 96; Cv = 96; Rs = 192; }
        else if (t < 288) { t -= 126; S = Wf; D = wfT; ldS = 96; Cv = 96; Rs = 1728; }
        else if (t < 324) { t -= 288; S = W1; D = w1T; ldS = 384; Cv = 384; Rs = 96; }
        else { t -= 324; S = W2; D = w2T; ldS = 96; Cv = 96; Rs = 384; }
        int tilesJ = Rs >> 5;
        int ti = t / tilesJ, tj = t - ti * tilesJ;
        int c0 = ti * 32, r0 = tj * 32;
        __shared__ __hip_bfloat16 lt[32][33];
        int cl = tid & 31, rl = tid >> 5;
#pragma unroll
        for (int e = 0; e < 4; ++e) {
            int row = r0 + rl + e * 8;
            int col = c0 + cl;
            float v = (col < Cv) ? S[(size_t)row * ldS + col] : 0.f;
            lt[cl][rl + e * 8] = __float2bfloat16(v);
        }
        __syncthreads();
#pragma unroll
        for (int e = 0; e < 4; ++e) {
            int drow = c0 + rl + e * 8;
            int dcol = r0 + cl;
            D[(size_t)drow * Rs + dcol] = lt[rl + e * 8][cl];
        }
        return;
    }
    int wave = tid >> 6;
    int lane = tid & 63;
    int row = (blockIdx.x - TP_BLOCKS) * 4 + wave;
    if (row >= MROWS) return;
    const float* p = x + (size_t)row * CDIM;
    float x0 = p[lane];
    float x1 = (lane < 32) ? p[64 + lane] : 0.f;
    float s = x0 + x1, sq = x0 * x0 + x1 * x1;
#pragma unroll
    for (int o = 32; o >= 1; o >>= 1) { s += __shfl_xor(s, o); sq += __shfl_xor(sq, o); }
    float mean = s * (1.f / 96.f);
    float var = sq * (1.f / 96.f) - mean * mean;
    float w = rsqrtf(var + 1e-5f);
    __hip_bfloat16* q = xn + (size_t)row * CDIM;
    q[lane] = __float2bfloat16((x0 - mean) * w * g[lane] + b[lane]);
    if (lane < 32) q[64 + lane] = __float2bfloat16((x1 - mean) * w * g[64 + lane] + b[64 + lane]);
}

// ---------------- LDS-free direct-fragment MFMA GEMM ----------------
template <int MI, int NI, int WR, int WC, int K, int EPI, typename CT>
__global__ __launch_bounds__(WR * WC * 64) void gemm_direct(
    const __hip_bfloat16* __restrict__ A, int lda,
    const __hip_bfloat16* __restrict__ BT,
    CT* __restrict__ C, int ldc, int N,
    const float* __restrict__ bias, const float* __restrict__ res) {
    int tid = threadIdx.x;
    int lane = tid & 63, wid = tid >> 6;
    int wm = wid % WR, wn = wid / WR;
    int m0 = blockIdx.y * (WR * MI * 16) + wm * MI * 16;
    int n0 = blockIdx.x * (WC * NI * 16) + wn * NI * 16;
    int lr = lane & 15, kh = (lane >> 4) * 8;
    f32x4 acc[MI][NI] = {};
    const __hip_bfloat16* Ap = A + (size_t)(m0 + lr) * lda + kh;
    const __hip_bfloat16* Bp = BT + (size_t)(n0 + lr) * K + kh;
#pragma unroll
    for (int k0 = 0; k0 < K; k0 += 32) {
        bf16x8 af[MI], bf[NI];
#pragma unroll
        for (int i = 0; i < MI; ++i)
            af[i] = *reinterpret_cast<const bf16x8*>(Ap + (size_t)i * 16 * lda + k0);
#pragma unroll
        for (int j = 0; j < NI; ++j)
            bf[j] = *reinterpret_cast<const bf16x8*>(Bp + (size_t)j * 16 * K + k0);
#pragma unroll
        for (int i = 0; i < MI; ++i)
#pragma unroll
            for (int j = 0; j < NI; ++j)
                acc[i][j] = __builtin_amdgcn_mfma_f32_16x16x32_bf16(af[i], bf[j], acc[i][j], 0, 0, 0);
    }
    int cr = (lane >> 4) << 2;
#pragma unroll
    for (int i = 0; i < MI; ++i) {
        int row = m0 + i * 16 + cr;
#pragma unroll
        for (int j = 0; j < NI; ++j) {
            int col = n0 + j * 16 + lr;
            if (col < N) {
#pragma unroll
                for (int q = 0; q < 4; ++q) {
                    float v = acc[i][j][q];
                    if (EPI == 1) v = gelu_exact(v + bias[col]);
                    else if (EPI == 2) v = v + bias[col] + res[(size_t)(row + q) * ldc + col];
                    C[(size_t)(row + q) * ldc + col] = (CT)v;
                }
            }
        }
    }
}

// ---------- fused conv3x3 + MLP: out = gelu(conv(cat)+bf) @W1 gelu @W2 + b2 + res ----------
__global__ __launch_bounds__(512) void conv_mlp_fused(
    const __hip_bfloat16* __restrict__ cat,  // [8192][192]
    const __hip_bfloat16* __restrict__ WfT,  // [96][1728]
    const float* __restrict__ bfv,
    const __hip_bfloat16* __restrict__ w1T,  // [384][96]
    const float* __restrict__ b1,
    const __hip_bfloat16* __restrict__ w2T,  // [96][384]
    const float* __restrict__ b2,
    const float* __restrict__ resx,          // [8192][96] f32
    float* __restrict__ out) {
    __shared__ float part[3][16][100];
    __shared__ unsigned short fcl[16][104];  // conv output tile bf16 (208B stride)
    __shared__ unsigned short hl[16][392];   // h1 tile bf16 (784B stride)
    int tid = threadIdx.x;
    int lane = tid & 63, wid = tid >> 6;     // 8 waves
    int lr = lane & 15, kh = (lane >> 4) * 8;
    int cr = (lane >> 4) << 2;
    int m0 = blockIdx.x * 16;
    // ---- stage A: conv3x3 (wn(2) x wk(4) wave split) -> fcl ----
    {
        int wn = wid & 1, wk = wid >> 1;
        int n0 = wn * 48;
        int m = m0 + lr;
        int bb = m >> 12, l = m & 4095, yy = l >> 6, xx = l & 63;
        f32x4 acc[3] = {};
        const __hip_bfloat16* Bp = WfT + (size_t)(n0 + lr) * 1728 + kh;
        for (int u = wk; u < 54; u += 4) {
            int tap = u / 6;
            int kc = (u - tap * 6) * 32;
            int ky = tap / 3, kx = tap - ky * 3;
            int iy = yy + ky - 1, ix = xx + kx - 1;
            bool ok = ((unsigned)iy < 64u) && ((unsigned)ix < 64u);
            bf16x8 af = {};
            if (ok)
                af = *reinterpret_cast<const bf16x8*>(
                    cat + ((size_t)bb * 4096 + (size_t)(iy * 64 + ix)) * 192 + kh + kc);
            int kbase = tap * 192 + kc;
#pragma unroll
            for (int j = 0; j < 3; ++j) {
                bf16x8 bfr = *reinterpret_cast<const bf16x8*>(Bp + (size_t)j * 16 * 1728 + kbase);
                acc[j] = __builtin_amdgcn_mfma_f32_16x16x32_bf16(af, bfr, acc[j], 0, 0, 0);
            }
        }
        if (wk != 0) {
#pragma unroll
            for (int j = 0; j < 3; ++j)
#pragma unroll
                for (int q = 0; q < 4; ++q)
                    part[wk - 1][cr + q][n0 + j * 16 + lr] = acc[j][q];
        }
        __syncthreads();
        if (wk == 0) {
#pragma unroll
            for (int j = 0; j < 3; ++j) {
                int ccol = n0 + j * 16 + lr;
#pragma unroll
                for (int q = 0; q < 4; ++q) {
                    float v = acc[j][q] + part[0][cr + q][ccol] + part[1][cr + q][ccol] +
                              part[2][cr + q][ccol];
                    fcl[cr + q][ccol] = f2bf_bits(gelu_exact(v + bfv[ccol]));
                }
            }
        }
        __syncthreads();
    }
    // ---- stage B: h1 = gelu(fc @ W1 + b1); wave wid owns cols [wid*48, wid*48+48) ----
    {
        int n0 = wid * 48;
        f32x4 acc[3] = {};
        const __hip_bfloat16* Bp = w1T + (size_t)(n0 + lr) * 96 + kh;
#pragma unroll
        for (int k0 = 0; k0 < 96; k0 += 32) {
            bf16x8 af = *reinterpret_cast<const bf16x8*>((const unsigned short*)&fcl[lr][kh + k0]);
#pragma unroll
            for (int j = 0; j < 3; ++j) {
                bf16x8 bv = *reinterpret_cast<const bf16x8*>(Bp + (size_t)j * 16 * 96 + k0);
                acc[j] = __builtin_amdgcn_mfma_f32_16x16x32_bf16(af, bv, acc[j], 0, 0, 0);
            }
        }
#pragma unroll
        for (int j = 0; j < 3; ++j) {
            int col = n0 + j * 16 + lr;
#pragma unroll
            for (int q = 0; q < 4; ++q)
                hl[cr + q][col] = f2bf_bits(gelu_exact(acc[j][q] + b1[col]));
        }
    }
    __syncthreads();
    // ---- stage C: out = h1 @ W2 + b2 + res; wn(2) x wk(4-way K split) ----
    {
        int wn = wid & 1, wk = wid >> 1;
        int n0 = wn * 48;
        int kb = wk * 96;
        f32x4 acc[3] = {};
        const __hip_bfloat16* Bp = w2T + (size_t)(n0 + lr) * 384 + kb + kh;
#pragma unroll
        for (int k0 = 0; k0 < 96; k0 += 32) {
            bf16x8 af = *reinterpret_cast<const bf16x8*>(
                (const unsigned short*)&hl[lr][kb + kh + k0]);
#pragma unroll
            for (int j = 0; j < 3; ++j) {
                bf16x8 bv = *reinterpret_cast<const bf16x8*>(Bp + (size_t)j * 16 * 384 + k0);
                acc[j] = __builtin_amdgcn_mfma_f32_16x16x32_bf16(af, bv, acc[j], 0, 0, 0);
            }
        }
        if (wk != 0) {
#pragma unroll
            for (int j = 0; j < 3; ++j)
#pragma unroll
                for (int q = 0; q < 4; ++q)
                    part[wk - 1][cr + q][n0 + j * 16 + lr] = acc[j][q];
        }
        __syncthreads();
        if (wk != 0) return;
#pragma unroll
        for (int j = 0; j < 3; ++j) {
            int col = n0 + j * 16 + lr;
#pragma unroll
            for (int q = 0; q < 4; ++q) {
                int row = m0 + cr + q;
                float v = acc[j][q] + part[0][cr + q][col] + part[1][cr + q][col] +
                          part[2][cr + q][col];
                out[(size_t)row * 96 + col] = v + b2[col] + resx[(size_t)row * 96 + col];
            }
        }
    }
}

// ---------------- Wo GEMM both branches + LN + cosine fuse (16-row tiles, K-split, 8 waves) ----
__global__ __launch_bounds__(512) void gemm_wo_ln_fuse(
    const __hip_bfloat16* __restrict__ A,      // yb [2*8192][192]
    const __hip_bfloat16* __restrict__ BT0, const __hip_bfloat16* __restrict__ BT1,
    const float* __restrict__ g0, const float* __restrict__ b0,
    const float* __restrict__ g1, const float* __restrict__ b1,
    __hip_bfloat16* __restrict__ cat) {        // [8192][192]
    int tid = threadIdx.x;
    int lane = tid & 63, wid = tid >> 6;       // 8 waves: wk x wn x branch
    int wk = wid & 1, wn = (wid >> 1) & 1, wb = wid >> 2;
    int m0 = blockIdx.x * 16;
    int n0 = wn * 48;
    int lr = lane & 15, kh = (lane >> 4) * 8;
    f32x4 acc[3] = {};
    const __hip_bfloat16* Ap = A + (size_t)((wb ? MROWS : 0) + m0 + lr) * 192 + kh + wk * 96;
    const __hip_bfloat16* BT = wb ? BT1 : BT0;
    const __hip_bfloat16* Bp = BT + (size_t)(n0 + lr) * 192 + kh + wk * 96;
#pragma unroll
    for (int k0 = 0; k0 < 96; k0 += 32) {
        bf16x8 af = *reinterpret_cast<const bf16x8*>(Ap + k0);
#pragma unroll
        for (int j = 0; j < 3; ++j) {
            bf16x8 bv = *reinterpret_cast<const bf16x8*>(Bp + (size_t)j * 16 * 192 + k0);
            acc[j] = __builtin_amdgcn_mfma_f32_16x16x32_bf16(af, bv, acc[j], 0, 0, 0);
        }
    }
    __shared__ float ct[2][16][100];
    __shared__ float pt[2][16][100];
    int cr = (lane >> 4) << 2;
    if (wk == 1) {
#pragma unroll
        for (int j = 0; j < 3; ++j)
#pragma unroll
            for (int q = 0; q < 4; ++q)
                pt[wb][cr + q][n0 + j * 16 + lr] = acc[j][q];
    }
    __syncthreads();
    if (wk == 0) {
#pragma unroll
        for (int j = 0; j < 3; ++j)
#pragma unroll
            for (int q = 0; q < 4; ++q)
                ct[wb][cr + q][n0 + j * 16 + lr] = acc[j][q] + pt[wb][cr + q][n0 + j * 16 + lr];
    }
    __syncthreads();
#pragma unroll
    for (int rr = 0; rr < 2; ++rr) {
        int row = wid * 2 + rr;
        float a0 = ct[0][row][lane];
        float a1 = (lane < 32) ? ct[0][row][64 + lane] : 0.f;
        float c0 = ct[1][row][lane];
        float c1 = (lane < 32) ? ct[1][row][64 + lane] : 0.f;
        float s0 = a0 + a1, q0 = a0 * a0 + a1 * a1;
        float s1 = c0 + c1, q1 = c0 * c0 + c1 * c1;
#pragma unroll
        for (int o = 32; o >= 1; o >>= 1) {
            s0 += __shfl_xor(s0, o); q0 += __shfl_xor(q0, o);
            s1 += __shfl_xor(s1, o); q1 += __shfl_xor(q1, o);
        }
        float mu0 = s0 * (1.f / 96.f), w0 = rsqrtf(q0 * (1.f / 96.f) - mu0 * mu0 + 1e-5f);
        float mu1 = s1 * (1.f / 96.f), w1 = rsqrtf(q1 * (1.f / 96.f) - mu1 * mu1 + 1e-5f);
        float f1a = (a0 - mu0) * w0 * g0[lane] + b0[lane];
        float f2a = (c0 - mu1) * w1 * g1[lane] + b1[lane];
        float f1b = 0.f, f2b = 0.f;
        if (lane < 32) {
            f1b = (a1 - mu0) * w0 * g0[64 + lane] + b0[64 + lane];
            f2b = (c1 - mu1) * w1 * g1[64 + lane] + b1[64 + lane];
        }
        float s11 = f1a * f1a + f1b * f1b;
        float s22 = f2a * f2a + f2b * f2b;
        float s12 = f1a * f2a + f1b * f2b;
#pragma unroll
        for (int o = 32; o >= 1; o >>= 1) {
            s11 += __shfl_xor(s11, o);
            s22 += __shfl_xor(s22, o);
            s12 += __shfl_xor(s12, o);
        }
        float nr1 = fmaxf(sqrtf(s11), 1e-12f);
        float nr2 = fmaxf(sqrtf(s22), 1e-12f);
        float sim = s12 / (nr1 * nr2);
        size_t grow = (size_t)blockIdx.x * 16 + row;
        __hip_bfloat16* q = cat + grow * 192;
        q[lane] = __float2bfloat16(f1a);
        q[96 + lane] = __float2bfloat16(sim * f1a + (1.f - sim) * f2a);
        if (lane < 32) {
            q[64 + lane] = __float2bfloat16(f1b);
            q[96 + 64 + lane] = __float2bfloat16(sim * f1b + (1.f - sim) * f2b);
        }
    }
}

// ---------------- scan pass1 (fused conv+sigmoid), 256 thr, 3-chain forward ----------------
__global__ __launch_bounds__(256) void scan_pass1f(
    const __hip_bfloat16* __restrict__ xpw,
    const float* __restrict__ cw0, const float* __restrict__ cw1,
    const float* __restrict__ cb0, const float* __restrict__ cb1,
    const float* __restrict__ A0, const float* __restrict__ A1,
    float* __restrict__ Pc, float* __restrict__ Hf, float* __restrict__ Gb) {
    __shared__ unsigned short rawxu[67][16];
    __shared__ float2 sdx[CHLEN][16];
    __shared__ float sb[CHLEN][16];
    __shared__ float asumv[16];
    int bid = (blockIdx.x & 7) * (SCAN_GRID / 8) + (blockIdx.x >> 3);  // XCD swizzle
    int dg = bid % 12;
    int c = (bid / 12) % NCHUNK;
    int b = (bid / (12 * NCHUNK)) & 1;
    int p = bid / (12 * NCHUNK * 2);
    const float* cw = p ? cw1 : cw0;
    const float* cbp = p ? cb1 : cb0;
    const float* Am = p ? A1 : A0;
    int tid = threadIdx.x;
    if (tid < 16) {
        const float4* Ap4 = (const float4*)(Am + tid * 16);
        float4 a0 = Ap4[0], a1 = Ap4[1], a2 = Ap4[2], a3 = Ap4[3];
        float s = (a0.x + a0.y + a0.z + a0.w) + (a1.x + a1.y + a1.z + a1.w) +
                  (a2.x + a2.y + a2.z + a2.w) + (a3.x + a3.y + a3.z + a3.w);
        asumv[tid] = s * 1.44269504f;
    }
    const unsigned short* xu = (const unsigned short*)xpw;
    int xb = p * 480;
    int t0 = c * CHLEN;
    int r = tid >> 2, q = (tid & 3) * 4;
    size_t grow = (size_t)b * L_SEQ + t0 + r;
    const unsigned short* rowp = xu + grow * XPW2 + xb;
    *(u16x4*)&rawxu[r + 3][q] = *(const u16x4*)(rowp + dg * 16 + q);
    u16x4 dvu = *(const u16x4*)(rowp + 192 + dg * 16 + q);
    u16x4 bvu = *(const u16x4*)(rowp + 384 + q);
    float4 bf4 = {b2f(bvu.x), b2f(bvu.y), b2f(bvu.z), b2f(bvu.w)};
    *(float4*)&sb[r][q] = bf4;
    if (tid < 12) {
        int rr = tid >> 2, qq = (tid & 3) * 4;
        int src = t0 - 3 + rr;
        u16x4 v = {0, 0, 0, 0};
        if (src >= 0)
            v = *(const u16x4*)(xu + ((size_t)b * L_SEQ + src) * XPW2 + xb + dg * 16 + qq);
        *(u16x4*)&rawxu[rr][qq] = v;
    }
    __syncthreads();
    float dd[4] = {b2f(dvu.x), b2f(dvu.y), b2f(dvu.z), b2f(dvu.w)};
#pragma unroll
    for (int i = 0; i < 4; ++i) {
        int d = dg * 16 + q + i;
        float4 w = *(const float4*)(cw + (size_t)d * 4);
        float xc = cbp[d] + w.w * b2f(rawxu[r + 3][q + i]) + w.z * b2f(rawxu[r + 2][q + i]) +
                   w.y * b2f(rawxu[r + 1][q + i]) + w.x * b2f(rawxu[r][q + i]);
        float ds = 1.f / (1.f + __expf(-dd[i]));
        sdx[r][q + i] = make_float2(ds, ds * xc);
    }
    __syncthreads();
    int n = tid & 15, drow = tid >> 4;
    float asum2 = asumv[n];
    float h = 0.f, gb = 0.f, Q = 1.f;
#pragma unroll 4
    for (int t = 0; t < CHLEN; ++t) {
        float2 dx = sdx[t][drow];
        float bm = sb[t][n];
        float a = fast_exp2(dx.x * asum2);
        float bu = dx.y * bm;
        h = a * h + bu;
        gb += Q * bu;
        Q *= a;
    }
    size_t cidx = ((((size_t)p * 2 + b) * NST + n) * DIN + dg * 16 + drow) * NCHUNK + c;
    Pc[cidx] = Q;
    Hf[cidx] = h;
    Gb[cidx] = gb;
}

// ---------------- scan pass2: combine chunk carries (contiguous float4 loads) ----------------
__global__ __launch_bounds__(256) void scan_pass2(const float* __restrict__ Pc,
                                                  const float* __restrict__ Hf,
                                                  const float* __restrict__ Gb,
                                                  float* __restrict__ Hinf,
                                                  float* __restrict__ Hinb) {
    int t = blockIdx.x * 256 + threadIdx.x;
    if (t >= 2 * 2 * NST * DIN) return;
    size_t base = (size_t)t * NCHUNK;
    {
        float4 P4[16], H4[16];
        const float4* Pp = (const float4*)(Pc + base);
        const float4* Hp = (const float4*)(Hf + base);
#pragma unroll
        for (int i = 0; i < 16; ++i) { P4[i] = Pp[i]; H4[i] = Hp[i]; }
        float hin = 0.f;
        float4* Op = (float4*)(Hinf + base);
#pragma unroll
        for (int i = 0; i < 16; ++i) {
            float4 o;
            o.x = hin; hin = H4[i].x + P4[i].x * hin;
            o.y = hin; hin = H4[i].y + P4[i].y * hin;
            o.z = hin; hin = H4[i].z + P4[i].z * hin;
            o.w = hin; hin = H4[i].w + P4[i].w * hin;
            Op[i] = o;
        }
    }
    {
        float4 P4[16], G4[16];
        const float4* Pp = (const float4*)(Pc + base);
        const float4* Gp = (const float4*)(Gb + base);
#pragma unroll
        for (int i = 0; i < 16; ++i) { P4[i] = Pp[i]; G4[i] = Gp[i]; }
        float gin = 0.f;
        float4* Op = (float4*)(Hinb + base);
#pragma unroll
        for (int i = 15; i >= 0; --i) {
            float4 o;
            o.w = gin; gin = G4[i].w + P4[i].w * gin;
            o.z = gin; gin = G4[i].z + P4[i].z * gin;
            o.y = gin; gin = G4[i].y + P4[i].y * gin;
            o.x = gin; gin = G4[i].x + P4[i].x * gin;
            Op[i] = o;
        }
    }
}

// ---------------- scan pass3 (fused conv): direction-split waves (4 fwd + 4 bwd) ----------------
__global__ __launch_bounds__(512) void scan_pass3f(
    const __hip_bfloat16* __restrict__ xpw,
    const float* __restrict__ cw0, const float* __restrict__ cw1,
    const float* __restrict__ cb0, const float* __restrict__ cb1,
    const float* __restrict__ A0, const float* __restrict__ A1,
    const float* __restrict__ Hinf, const float* __restrict__ Hinb,
    const float* __restrict__ Dp0, const float* __restrict__ Dp1,
    __hip_bfloat16* __restrict__ y) {
    __shared__ unsigned short rawxu[67][16];
    __shared__ float2 sdx[CHLEN][16];        // (ds, ds*xc)
    __shared__ float2 sbc[CHLEN][16];        // (Bm, Cm)
    __shared__ unsigned short sxcu[CHLEN][16];  // xc as bf16 (epilogue Dp*xc)
    __shared__ float ysf[CHLEN][16], ysb[CHLEN][16];
    __shared__ float asumv[16];
    int bid = (blockIdx.x & 7) * (SCAN_GRID / 8) + (blockIdx.x >> 3);  // XCD swizzle
    int dg = bid % 12;
    int c = (bid / 12) % NCHUNK;
    int b = (bid / (12 * NCHUNK)) & 1;
    int p = bid / (12 * NCHUNK * 2);
    const float* cw = p ? cw1 : cw0;
    const float* cbp = p ? cb1 : cb0;
    const float* Am = p ? A1 : A0;
    const float* Dp = p ? Dp1 : Dp0;
    int tid = threadIdx.x;
    if (tid < 16) {
        const float4* Ap4 = (const float4*)(Am + tid * 16);
        float4 a0 = Ap4[0], a1 = Ap4[1], a2 = Ap4[2], a3 = Ap4[3];
        float s = (a0.x + a0.y + a0.z + a0.w) + (a1.x + a1.y + a1.z + a1.w) +
                  (a2.x + a2.y + a2.z + a2.w) + (a3.x + a3.y + a3.z + a3.w);
        asumv[tid] = s * 1.44269504f;
    }
    const unsigned short* xu = (const unsigned short*)xpw;
    int xb = p * 480;
    int t0 = c * CHLEN;
    int r = tid >> 2, q = (tid & 3) * 4;
    u16x4 dvu = {0, 0, 0, 0};
    if (tid < 256) {
        size_t grow = (size_t)b * L_SEQ + t0 + r;
        const unsigned short* rowp = xu + grow * XPW2 + xb;
        *(u16x4*)&rawxu[r + 3][q] = *(const u16x4*)(rowp + dg * 16 + q);
        dvu = *(const u16x4*)(rowp + 192 + dg * 16 + q);
        u16x4 bvu = *(const u16x4*)(rowp + 384 + q);
        u16x4 cvu = *(const u16x4*)(rowp + 400 + q);
        sbc[r][q + 0] = make_float2(b2f(bvu.x), b2f(cvu.x));
        sbc[r][q + 1] = make_float2(b2f(bvu.y), b2f(cvu.y));
        sbc[r][q + 2] = make_float2(b2f(bvu.z), b2f(cvu.z));
        sbc[r][q + 3] = make_float2(b2f(bvu.w), b2f(cvu.w));
        if (tid < 12) {
            int rr = tid >> 2, qq = (tid & 3) * 4;
            int src = t0 - 3 + rr;
            u16x4 v = {0, 0, 0, 0};
            if (src >= 0)
                v = *(const u16x4*)(xu + ((size_t)b * L_SEQ + src) * XPW2 + xb + dg * 16 + qq);
            *(u16x4*)&rawxu[rr][qq] = v;
        }
    }
    __syncthreads();
    if (tid < 256) {
        float dd[4] = {b2f(dvu.x), b2f(dvu.y), b2f(dvu.z), b2f(dvu.w)};
#pragma unroll
        for (int i = 0; i < 4; ++i) {
            int d = dg * 16 + q + i;
            float4 w = *(const float4*)(cw + (size_t)d * 4);
            float xc = cbp[d] + w.w * b2f(rawxu[r + 3][q + i]) + w.z * b2f(rawxu[r + 2][q + i]) +
                       w.y * b2f(rawxu[r + 1][q + i]) + w.x * b2f(rawxu[r][q + i]);
            float ds = 1.f / (1.f + __expf(-dd[i]));
            sdx[r][q + i] = make_float2(ds, ds * xc);
            sxcu[r][q + i] = f2bf_bits(xc);
        }
    }
    __syncthreads();
    int lane = tid & 63, wave = tid >> 6;   // 8 waves
    int dir = wave >> 2;                    // 0 = fwd (waves 0-3), 1 = bwd (waves 4-7)
    int wl = wave & 3;
    int n = lane & 15;
    int dloc = wl * 4 + (lane >> 4);
    int d = dg * 16 + dloc;
    float asum2 = asumv[n];
    size_t cidx = ((((size_t)p * 2 + b) * NST + n) * DIN + d) * NCHUNK + c;
    if (dir == 0) {
        float h = Hinf[cidx];
#pragma unroll 4
        for (int t = 0; t < CHLEN; ++t) {
            float2 dx = sdx[t][dloc];
            float2 bc = sbc[t][n];
            float a = fast_exp2(dx.x * asum2);
            h = a * h + dx.y * bc.x;
            float pf = rowsum16(bc.y * h);
            if (n == 0) ysf[t][dloc] = pf;
        }
    } else {
        float gv = Hinb[cidx];
#pragma unroll 4
        for (int t = CHLEN - 1; t >= 0; --t) {
            float2 dx = sdx[t][dloc];
            float2 bc = sbc[t][n];
            float a = fast_exp2(dx.x * asum2);
            gv = a * gv + dx.y * bc.x;
            float pb = rowsum16(bc.y * gv);
            if (n == 0) ysb[t][dloc] = pb;
        }
    }
    __syncthreads();
    if (tid < 256) {
        int tl = tid >> 2, qq = (tid & 3) * 4;
        int d2 = dg * 16 + qq;
        float4 Dv = *(const float4*)(Dp + d2);
        float vs[4];
#pragma unroll
        for (int i = 0; i < 4; ++i)
            vs[i] = ysf[tl][qq + i] + ysb[tl][qq + i] +
                    ((const float*)&Dv)[i] * b2f(sxcu[tl][qq + i]);
        s16x4 pk = {(short)f2bf_bits(vs[0]), (short)f2bf_bits(vs[1]),
                    (short)f2bf_bits(vs[2]), (short)f2bf_bits(vs[3])};
        size_t row = (size_t)b * L_SEQ + t0 + tl;
        *(s16x4*)((unsigned short*)y + ((size_t)p * MROWS + row) * DIN + d2) = pk;
    }
}

extern "C" void kernel_launch(void* const* d_in, const int* in_sizes, int n_in,
                              void* d_out, int out_size, void* d_ws, size_t ws_size,
                              hipStream_t stream) {
    const float* x = (const float*)d_in[0];
    const float* norm_g = (const float*)d_in[1];
    const float* norm_b = (const float*)d_in[2];
    const float* Wp[2] = {(const float*)d_in[3], (const float*)d_in[11]};
    const float* cw[2] = {(const float*)d_in[4], (const float*)d_in[12]};
    const float* cb[2] = {(const float*)d_in[5], (const float*)d_in[13]};
    const float* Ab[2] = {(const float*)d_in[6], (const float*)d_in[14]};
    const float* Dpb[2] = {(const float*)d_in[7], (const float*)d_in[15]};
    const float* Wo[2] = {(const float*)d_in[8], (const float*)d_in[16]};
    const float* lng[2] = {(const float*)d_in[9], (const float*)d_in[17]};
    const float* lnb[2] = {(const float*)d_in[10], (const float*)d_in[18]};
    const float* Wf = (const float*)d_in[19];
    const float* bfv = (const float*)d_in[20];
    const float* W1 = (const float*)d_in[21];
    const float* b1 = (const float*)d_in[22];
    const float* W2 = (const float*)d_in[23];
    const float* b2 = (const float*)d_in[24];
    float* out = (float*)d_out;

    char* base = (char*)d_ws;
    size_t off = 0;
    auto alloc = [&](size_t bytes) { void* p = base + off; off += (bytes + 255) & ~(size_t)255; return p; };
    __hip_bfloat16* xpw = (__hip_bfloat16*)alloc((size_t)MROWS * XPW2 * 2);
    const size_t csz = (size_t)2 * 2 * NST * DIN * NCHUNK;
    float* Pc = (float*)alloc(csz * 4);
    float* Hfc = (float*)alloc(csz * 4);
    float* Gbc = (float*)alloc(csz * 4);
    float* Hinf = (float*)alloc(csz * 4);
    float* Hinb = (float*)alloc(csz * 4);
    __hip_bfloat16* xn_bf = (__hip_bfloat16*)alloc((size_t)MROWS * 96 * 2);
    __hip_bfloat16* yb_bf = (__hip_bfloat16*)alloc((size_t)2 * MROWS * DIN * 2);
    __hip_bfloat16* cat_bf = (__hip_bfloat16*)alloc((size_t)MROWS * DIN * 2);
    __hip_bfloat16* wpT = (__hip_bfloat16*)alloc((size_t)XPW2 * 96 * 2);
    __hip_bfloat16* woT[2] = {(__hip_bfloat16*)alloc(96 * 192 * 2),
                              (__hip_bfloat16*)alloc(96 * 192 * 2)};
    __hip_bfloat16* wfT = (__hip_bfloat16*)alloc(96 * 1728 * 2);
    __hip_bfloat16* w1T = (__hip_bfloat16*)alloc(384 * 96 * 2);
    __hip_bfloat16* w2T = (__hip_bfloat16*)alloc(96 * 384 * 2);
    (void)ws_size; (void)in_sizes; (void)n_in; (void)out_size;

    // 1. tiled weight transposes + input LN (one launch)
    prep_kernel<<<dim3(TP_BLOCKS + 2048), dim3(256), 0, stream>>>(
        Wp[0], Wp[1], Wo[0], Wo[1], Wf, W1, W2,
        wpT, woT[0], woT[1], wfT, w1T, w2T, x, norm_g, norm_b, xn_bf);
    // 2. xp(both branches, bf16) = xn @ [Wp1|Wp2]
    gemm_direct<2, 3, 2, 2, 96, 0, __hip_bfloat16><<<dim3(10, 128), dim3(256), 0, stream>>>(
        xn_bf, 96, wpT, xpw, XPW2, XPW2, nullptr, nullptr);
    // 3-5. bidirectional selective scan, both branches
    scan_pass1f<<<dim3(SCAN_GRID), dim3(256), 0, stream>>>(
        xpw, cw[0], cw[1], cb[0], cb[1], Ab[0], Ab[1], Pc, Hfc, Gbc);
    scan_pass2<<<dim3(48), dim3(256), 0, stream>>>(Pc, Hfc, Gbc, Hinf, Hinb);
    scan_pass3f<<<dim3(SCAN_GRID), dim3(512), 0, stream>>>(
        xpw, cw[0], cw[1], cb[0], cb[1], Ab[0], Ab[1], Hinf, Hinb, Dpb[0], Dpb[1], yb_bf);
    // 6. f1/f2 = LN(y@Wo), cosine fuse -> cat (16-row tiles, K-split, 8 waves)
    gemm_wo_ln_fuse<<<dim3(512), dim3(512), 0, stream>>>(
        yb_bf, woT[0], woT[1], lng[0], lnb[0], lng[1], lnb[1], cat_bf);
    // 7. out = mlp(gelu(conv3x3(cat)+bf)) + res  (fused conv+MLP, one launch)
    conv_mlp_fused<<<dim3(512), dim3(512), 0, stream>>>(
        cat_bf, wfT, bfv, w1T, b1, w2T, b2, x, out);
}